// Round 1
// baseline (771.748 us; speedup 1.0000x reference)
//
#include <hip/hip_runtime.h>
#include <math.h>

#define NN 65536
#define NE 1048576

// ---------------- CSR build ----------------
__global__ __launch_bounds__(256) void k_hist(const int* __restrict__ dst, int* __restrict__ deg) {
  int e = blockIdx.x * 256 + threadIdx.x;
  atomicAdd(&deg[dst[e]], 1);
}

__global__ __launch_bounds__(1024) void k_scan(const int* __restrict__ deg, int* __restrict__ off,
                                               int* __restrict__ cur) {
  __shared__ int buf[1024];
  int t = threadIdx.x;
  int base = t * 64;
  int s = 0;
  for (int i = 0; i < 64; ++i) s += deg[base + i];
  buf[t] = s;
  __syncthreads();
  for (int d = 1; d < 1024; d <<= 1) {
    int xv = (t >= d) ? buf[t - d] : 0;
    __syncthreads();
    buf[t] += xv;
    __syncthreads();
  }
  int run = buf[t] - s;  // exclusive prefix of this chunk
  for (int i = 0; i < 64; ++i) {
    int dg = deg[base + i];
    off[base + i] = run;
    cur[base + i] = run;
    run += dg;
  }
  if (t == 1023) off[NN] = run;
}

__global__ __launch_bounds__(256) void k_scatter(const int* __restrict__ src, const int* __restrict__ dst,
                                                 const float* __restrict__ val, int* __restrict__ cur,
                                                 int2* __restrict__ pack) {
  int e = blockIdx.x * 256 + threadIdx.x;
  int d = dst[e];
  int p = atomicAdd(&cur[d], 1);
  pack[p] = make_int2(src[e], __float_as_int(val[e]));
}

// ---------------- GCN layer 1: agg in 3-dim space, then GEMM [N,3]@[3,64] ----------------
__global__ __launch_bounds__(256) void k_aggx(const int* __restrict__ off, const int2* __restrict__ pack,
                                              const float* __restrict__ x, float* __restrict__ aggx) {
  int n = blockIdx.x * 256 + threadIdx.x;
  int i = off[n], e = off[n + 1];
  float a0 = 0.f, a1 = 0.f, a2 = 0.f;
  for (; i < e; ++i) {
    int2 ed = pack[i];
    float v = __int_as_float(ed.y);
    const float* xs = &x[3 * ed.x];
    a0 = fmaf(v, xs[0], a0);
    a1 = fmaf(v, xs[1], a1);
    a2 = fmaf(v, xs[2], a2);
  }
  aggx[n * 3 + 0] = a0;
  aggx[n * 3 + 1] = a1;
  aggx[n * 3 + 2] = a2;
}

__global__ __launch_bounds__(256) void k_gemm1(const float* __restrict__ aggx, const float* __restrict__ w,
                                               const float* __restrict__ b, float* __restrict__ out) {
  __shared__ float sw[256];  // 192 weights + 64 bias
  int t = threadIdx.x;
  sw[t] = (t < 192) ? w[t] : b[t - 192];
  __syncthreads();
  int g = blockIdx.x * 256 + t;
  int n = g >> 6, j = g & 63;
  float a0 = aggx[n * 3], a1 = aggx[n * 3 + 1], a2 = aggx[n * 3 + 2];
  float r = sw[192 + j];
  r = fmaf(a0, sw[j], r);
  r = fmaf(a1, sw[64 + j], r);
  r = fmaf(a2, sw[128 + j], r);
  out[g] = fmaxf(r, 0.f);
}

// ---------------- 64-feature aggregation: wave per node, lane = feature ----------------
__global__ __launch_bounds__(256) void k_agg64(const int* __restrict__ off, const int2* __restrict__ pack,
                                               const float* __restrict__ h, float* __restrict__ out) {
  int lane = threadIdx.x & 63;
  int n = blockIdx.x * 4 + (threadIdx.x >> 6);
  int i = off[n], e = off[n + 1];
  float acc = 0.f;
  for (; i < e; ++i) {
    int2 ed = pack[i];  // broadcast 8B load (all lanes same addr)
    acc = fmaf(__int_as_float(ed.y), h[(size_t)ed.x * 64 + lane], acc);
  }
  out[(size_t)n * 64 + lane] = acc;
}

// ---------------- GCN layer 2 GEMM: [N,64]@[64,64] + relu, W column in regs ----------------
__global__ __launch_bounds__(256) void k_gemm2(const float* __restrict__ agg, const float* __restrict__ w2,
                                               const float* __restrict__ b2, float* __restrict__ out) {
  int lane = threadIdx.x & 63, wv = threadIdx.x >> 6;
  float w[64];
#pragma unroll
  for (int k = 0; k < 64; ++k) w[k] = w2[k * 64 + lane];
  float bb = b2[lane];
  int n0 = blockIdx.x * 32 + wv * 8;
  for (int t = 0; t < 8; ++t) {
    int n = n0 + t;
    const float4* row = (const float4*)&agg[(size_t)n * 64];
    float acc = bb;
#pragma unroll
    for (int kk = 0; kk < 16; ++kk) {
      float4 q = row[kk];  // broadcast 16B load
      acc = fmaf(q.x, w[4 * kk + 0], acc);
      acc = fmaf(q.y, w[4 * kk + 1], acc);
      acc = fmaf(q.z, w[4 * kk + 2], acc);
      acc = fmaf(q.w, w[4 * kk + 3], acc);
    }
    out[(size_t)n * 64 + lane] = fmaxf(acc, 0.f);
  }
}

// ---------------- GCN layer 3 GEMM fused with per-shape max pool ----------------
// grid = 64 shapes * 4 jtiles * 4 pchunks; block 256; thread = one output column j
__global__ __launch_bounds__(256) void k_gemm3max(const float* __restrict__ agg, const float* __restrict__ w3,
                                                  const float* __restrict__ b3, float* __restrict__ gf) {
  int bid = blockIdx.x;
  int shape = bid >> 4;
  int jt = (bid >> 2) & 3;
  int pc = bid & 3;
  int j = jt * 256 + threadIdx.x;
  float w[64];
#pragma unroll
  for (int k = 0; k < 64; ++k) w[k] = w3[k * 1024 + j];
  float bb = b3[j];
  __shared__ float rows[16 * 64];
  float m = 0.f;  // relu floor
  int prow = shape * 1024 + pc * 256;
  for (int pp = 0; pp < 256; pp += 16) {
    const float4* srcp = (const float4*)&agg[(size_t)(prow + pp) * 64];
    ((float4*)rows)[threadIdx.x] = srcp[threadIdx.x];  // 4KB coalesced stage
    __syncthreads();
    for (int r = 0; r < 16; ++r) {
      const float4* rv = (const float4*)&rows[r * 64];
      float acc = bb;
#pragma unroll
      for (int kk = 0; kk < 16; ++kk) {
        float4 q = rv[kk];  // LDS broadcast
        acc = fmaf(q.x, w[4 * kk + 0], acc);
        acc = fmaf(q.y, w[4 * kk + 1], acc);
        acc = fmaf(q.z, w[4 * kk + 2], acc);
        acc = fmaf(q.w, w[4 * kk + 3], acc);
      }
      m = fmaxf(m, acc);
    }
    __syncthreads();
  }
  // m >= 0, so float-bits compare as uint
  atomicMax((unsigned int*)&gf[shape * 1024 + j], __float_as_uint(m));
}

// ---------------- MLP head ----------------
__global__ __launch_bounds__(256) void k_fc(const float* __restrict__ in, const float* __restrict__ w,
                                            const float* __restrict__ bias, float* __restrict__ out,
                                            int K, int J, int jmask, int jshift) {
  int t = blockIdx.x * 256 + threadIdx.x;
  int j = t & jmask, bb = t >> jshift;
  float acc = bias[j];
  const float* row = in + (size_t)bb * K;
  for (int k = 0; k < K; k += 4) {
    float4 q = *(const float4*)&row[k];  // broadcast
    acc = fmaf(q.x, w[(k + 0) * J + j], acc);
    acc = fmaf(q.y, w[(k + 1) * J + j], acc);
    acc = fmaf(q.z, w[(k + 2) * J + j], acc);
    acc = fmaf(q.w, w[(k + 3) * J + j], acc);
  }
  out[t] = acc;
}

__global__ __launch_bounds__(256) void k_bn(const float* __restrict__ z, const float* __restrict__ g,
                                            const float* __restrict__ bt, float* __restrict__ out, int J) {
  int j = blockIdx.x * 256 + threadIdx.x;
  if (j >= J) return;
  float s = 0.f;
  for (int bb = 0; bb < 64; ++bb) s += z[bb * J + j];
  float mean = s * (1.0f / 64.0f);
  float v = 0.f;
  for (int bb = 0; bb < 64; ++bb) {
    float d = z[bb * J + j] - mean;
    v = fmaf(d, d, v);
  }
  float inv = 1.0f / sqrtf(v * (1.0f / 64.0f) + 1e-5f);
  float gg = g[j] * inv, beta = bt[j];
  for (int bb = 0; bb < 64; ++bb)
    out[bb * J + j] = fmaxf(fmaf(z[bb * J + j] - mean, gg, beta), 0.f);
}

__global__ __launch_bounds__(64) void k_head(const float* __restrict__ z, const float* __restrict__ w,
                                             const float* __restrict__ b, float* __restrict__ out) {
  int bb = blockIdx.x, j = threadIdx.x;
  float acc = -INFINITY;
  if (j < 40) {
    acc = b[j];
    const float* row = z + bb * 256;
    for (int k = 0; k < 256; ++k) acc = fmaf(row[k], w[k * 40 + j], acc);
  }
  float m = acc;
  for (int d = 32; d > 0; d >>= 1) m = fmaxf(m, __shfl_xor(m, d));
  float e = (j < 40) ? expf(acc - m) : 0.f;
  for (int d = 32; d > 0; d >>= 1) e += __shfl_xor(e, d);
  if (j < 40) out[bb * 40 + j] = acc - m - logf(e);
}

extern "C" void kernel_launch(void* const* d_in, const int* in_sizes, int n_in,
                              void* d_out, int out_size, void* d_ws, size_t ws_size,
                              hipStream_t stream) {
  (void)in_sizes; (void)n_in; (void)out_size; (void)ws_size;
  const float* x    = (const float*)d_in[0];
  const int*   esrc = (const int*)d_in[1];
  const int*   edst = (const int*)d_in[2];
  const float* ev   = (const float*)d_in[3];
  // d_in[4] = num_pts (1024, fixed by problem)
  const float* gc1w = (const float*)d_in[5];
  const float* gc1b = (const float*)d_in[6];
  const float* gc2w = (const float*)d_in[7];
  const float* gc2b = (const float*)d_in[8];
  const float* gc3w = (const float*)d_in[9];
  const float* gc3b = (const float*)d_in[10];
  const float* fc1w = (const float*)d_in[11];
  const float* fc1b = (const float*)d_in[12];
  const float* bn1g = (const float*)d_in[13];
  const float* bn1b = (const float*)d_in[14];
  const float* fc2w = (const float*)d_in[15];
  const float* fc2b = (const float*)d_in[16];
  const float* bn2g = (const float*)d_in[17];
  const float* bn2b = (const float*)d_in[18];
  const float* fc3w = (const float*)d_in[19];
  const float* fc3b = (const float*)d_in[20];

  char* ws = (char*)d_ws;
  size_t o = 0;
  auto alloc = [&](size_t bytes) -> void* {
    void* p = ws + o;
    o += (bytes + 255) & ~(size_t)255;
    return p;
  };
  int*   deg  = (int*)alloc((size_t)NN * 4);
  int*   off  = (int*)alloc((size_t)(NN + 1) * 4);
  int*   cur  = (int*)alloc((size_t)NN * 4);
  int2*  pack = (int2*)alloc((size_t)NE * 8);
  float* aggx = (float*)alloc((size_t)NN * 3 * 4);
  float* bufA = (float*)alloc((size_t)NN * 64 * 4);  // h1, then h2
  float* bufB = (float*)alloc((size_t)NN * 64 * 4);  // agg2, then agg3
  float* gf   = (float*)alloc(64 * 1024 * 4);
  float* z1   = (float*)alloc(64 * 512 * 4);
  float* z1n  = (float*)alloc(64 * 512 * 4);
  float* z2   = (float*)alloc(64 * 256 * 4);
  float* z2n  = (float*)alloc(64 * 256 * 4);

  hipMemsetAsync(deg, 0, (size_t)NN * 4, stream);
  hipMemsetAsync(gf, 0, 64 * 1024 * 4, stream);

  k_hist<<<NE / 256, 256, 0, stream>>>(edst, deg);
  k_scan<<<1, 1024, 0, stream>>>(deg, off, cur);
  k_scatter<<<NE / 256, 256, 0, stream>>>(esrc, edst, ev, cur, pack);

  // layer 1: agg(x) -> @W1 + b1, relu
  k_aggx<<<NN / 256, 256, 0, stream>>>(off, pack, x, aggx);
  k_gemm1<<<(NN * 64) / 256, 256, 0, stream>>>(aggx, gc1w, gc1b, bufA);

  // layer 2: agg(h1) -> @W2 + b2, relu
  k_agg64<<<NN / 4, 256, 0, stream>>>(off, pack, bufA, bufB);
  k_gemm2<<<NN / 32, 256, 0, stream>>>(bufB, gc2w, gc2b, bufA);

  // layer 3: agg(h2) -> @W3 + b3, relu, fused per-shape max pool
  k_agg64<<<NN / 4, 256, 0, stream>>>(off, pack, bufA, bufB);
  k_gemm3max<<<64 * 16, 256, 0, stream>>>(bufB, gc3w, gc3b, gf);

  // MLP head
  k_fc<<<(64 * 512) / 256, 256, 0, stream>>>(gf, fc1w, fc1b, z1, 1024, 512, 511, 9);
  k_bn<<<2, 256, 0, stream>>>(z1, bn1g, bn1b, z1n, 512);
  k_fc<<<(64 * 256) / 256, 256, 0, stream>>>(z1n, fc2w, fc2b, z2, 512, 256, 255, 8);
  k_bn<<<1, 256, 0, stream>>>(z2, bn2g, bn2b, z2n, 256);
  k_head<<<64, 64, 0, stream>>>(z2n, fc3w, fc3b, (float*)d_out);
}

// Round 2
// 698.158 us; speedup vs baseline: 1.1054x; 1.1054x over previous
//
#include <hip/hip_runtime.h>
#include <math.h>

#define NN 65536
#define NE 1048576

typedef __attribute__((ext_vector_type(8))) short short8;
typedef __attribute__((ext_vector_type(4))) float f32x4;

__device__ inline unsigned short f2bf(float f) {
  unsigned u = __float_as_uint(f);
  unsigned r = u + 0x7fff + ((u >> 16) & 1);  // RNE
  return (unsigned short)(r >> 16);
}
__device__ inline float bf2f(unsigned short h) { return __uint_as_float(((unsigned)h) << 16); }

// ---------------- CSR build ----------------
__global__ __launch_bounds__(256) void k_hist(const int* __restrict__ dst, int* __restrict__ deg) {
  int e = blockIdx.x * 256 + threadIdx.x;
  atomicAdd(&deg[dst[e]], 1);
}

__global__ __launch_bounds__(1024) void k_scan(const int* __restrict__ deg, int* __restrict__ off,
                                               int* __restrict__ cur) {
  __shared__ int buf[1024];
  int t = threadIdx.x;
  int base = t * 64;
  int s = 0;
  for (int i = 0; i < 64; ++i) s += deg[base + i];
  buf[t] = s;
  __syncthreads();
  for (int d = 1; d < 1024; d <<= 1) {
    int xv = (t >= d) ? buf[t - d] : 0;
    __syncthreads();
    buf[t] += xv;
    __syncthreads();
  }
  int run = buf[t] - s;
  for (int i = 0; i < 64; ++i) {
    int dg = deg[base + i];
    off[base + i] = run;
    cur[base + i] = run;
    run += dg;
  }
  if (t == 1023) off[NN] = run;
}

__global__ __launch_bounds__(256) void k_scatter(const int* __restrict__ src, const int* __restrict__ dst,
                                                 const float* __restrict__ val, int* __restrict__ cur,
                                                 int2* __restrict__ pack) {
  int e = blockIdx.x * 256 + threadIdx.x;
  int d = dst[e];
  int p = atomicAdd(&cur[d], 1);
  pack[p] = make_int2(src[e], __float_as_int(val[e]));
}

// ---------------- GCN layer 1 ----------------
__global__ __launch_bounds__(256) void k_aggx(const int* __restrict__ off, const int2* __restrict__ pack,
                                              const float* __restrict__ x, float* __restrict__ aggx) {
  int n = blockIdx.x * 256 + threadIdx.x;
  int i = off[n], e = off[n + 1];
  float a0 = 0.f, a1 = 0.f, a2 = 0.f;
  for (; i < e; ++i) {
    int2 ed = pack[i];
    float v = __int_as_float(ed.y);
    const float* xs = &x[3 * ed.x];
    a0 = fmaf(v, xs[0], a0);
    a1 = fmaf(v, xs[1], a1);
    a2 = fmaf(v, xs[2], a2);
  }
  aggx[n * 3 + 0] = a0;
  aggx[n * 3 + 1] = a1;
  aggx[n * 3 + 2] = a2;
}

__global__ __launch_bounds__(256) void k_gemm1(const float* __restrict__ aggx, const float* __restrict__ w,
                                               const float* __restrict__ b, float* __restrict__ out) {
  __shared__ float sw[256];
  int t = threadIdx.x;
  sw[t] = (t < 192) ? w[t] : b[t - 192];
  __syncthreads();
  int g = blockIdx.x * 256 + t;
  int n = g >> 6, j = g & 63;
  float a0 = aggx[n * 3], a1 = aggx[n * 3 + 1], a2 = aggx[n * 3 + 2];
  float r = sw[192 + j];
  r = fmaf(a0, sw[j], r);
  r = fmaf(a1, sw[64 + j], r);
  r = fmaf(a2, sw[128 + j], r);
  out[g] = fmaxf(r, 0.f);
}

// ---------------- 64-feature aggregation: wave per node, lane = feature ----------------
__global__ __launch_bounds__(256) void k_agg64(const int* __restrict__ off, const int2* __restrict__ pack,
                                               const float* __restrict__ h, float* __restrict__ out) {
  int lane = threadIdx.x & 63;
  int n = blockIdx.x * 4 + (threadIdx.x >> 6);
  int i = off[n], e = off[n + 1];
  float acc = 0.f;
  for (; i < e; ++i) {
    int2 ed = pack[i];
    acc = fmaf(__int_as_float(ed.y), h[(size_t)ed.x * 64 + lane], acc);
  }
  out[(size_t)n * 64 + lane] = acc;
}

// same aggregation, but emit split-bf16 planes (hi, lo) for the MFMA GEMM
__global__ __launch_bounds__(256) void k_agg64_split(const int* __restrict__ off, const int2* __restrict__ pack,
                                                     const float* __restrict__ h,
                                                     unsigned short* __restrict__ hi,
                                                     unsigned short* __restrict__ lo) {
  int lane = threadIdx.x & 63;
  int n = blockIdx.x * 4 + (threadIdx.x >> 6);
  int i = off[n], e = off[n + 1];
  float acc = 0.f;
  for (; i < e; ++i) {
    int2 ed = pack[i];
    acc = fmaf(__int_as_float(ed.y), h[(size_t)ed.x * 64 + lane], acc);
  }
  unsigned short h16 = f2bf(acc);
  unsigned short l16 = f2bf(acc - bf2f(h16));
  size_t idx = (size_t)n * 64 + lane;
  hi[idx] = h16;
  lo[idx] = l16;
}

// ---------------- GCN layer 2 GEMM (fp32 VALU, unchanged) ----------------
__global__ __launch_bounds__(256) void k_gemm2(const float* __restrict__ agg, const float* __restrict__ w2,
                                               const float* __restrict__ b2, float* __restrict__ out) {
  int lane = threadIdx.x & 63, wv = threadIdx.x >> 6;
  float w[64];
#pragma unroll
  for (int k = 0; k < 64; ++k) w[k] = w2[k * 64 + lane];
  float bb = b2[lane];
  int n0 = blockIdx.x * 32 + wv * 8;
  for (int t = 0; t < 8; ++t) {
    int n = n0 + t;
    const float4* row = (const float4*)&agg[(size_t)n * 64];
    float acc = bb;
#pragma unroll
    for (int kk = 0; kk < 16; ++kk) {
      float4 q = row[kk];
      acc = fmaf(q.x, w[4 * kk + 0], acc);
      acc = fmaf(q.y, w[4 * kk + 1], acc);
      acc = fmaf(q.z, w[4 * kk + 2], acc);
      acc = fmaf(q.w, w[4 * kk + 3], acc);
    }
    out[(size_t)n * 64 + lane] = fmaxf(acc, 0.f);
  }
}

// ---------------- W3 prep: split-bf16, MFMA-fragment order ----------------
// Bfrag layout: [q][col][g][e]  (q: 0,1 = Whi k0-31/k32-63; 2,3 = Wlo k0-31/k32-63)
__global__ __launch_bounds__(256) void k_prepw(const float* __restrict__ w3, unsigned short* __restrict__ bfrag) {
  int t = blockIdx.x * 256 + threadIdx.x;  // 131072 total
  int e = t & 7, g = (t >> 3) & 3, col = (t >> 5) & 1023, q = t >> 15;
  int k = (q & 1) * 32 + g * 8 + e;
  float v = w3[k * 1024 + col];
  unsigned short hv = f2bf(v);
  bfrag[t] = (q < 2) ? hv : f2bf(v - bf2f(hv));
}

// ---------------- GCN layer 3 GEMM + maxpool via MFMA (split-bf16) ----------------
// C = A_hi@W_hi + A_hi@W_lo + A_lo@W_hi ; out[shape][j] = relu(max_p C[p][j] + b[j])
// grid: bid = (jt*2 + pc)*64 + shape  (keeps all blocks of one shape on one XCD)
// block 256 = 4 waves; wave tile = 32 rows x 16 cols per iter; 16 iters (512 rows).
__global__ __launch_bounds__(256) void k_gemm3max(const unsigned short* __restrict__ Ahi,
                                                  const unsigned short* __restrict__ Alo,
                                                  const unsigned short* __restrict__ Bfrag,
                                                  const float* __restrict__ b3,
                                                  unsigned* __restrict__ gf) {
  int bid = blockIdx.x;
  int shape = bid & 63;
  int jp = bid >> 6;          // 0..31
  int jt = jp >> 1, pc = jp & 1;
  int tid = threadIdx.x;
  int wv = tid >> 6, l = tid & 63;
  int col = jt * 64 + wv * 16 + (l & 15);
  int g = l >> 4;  // 0..3

  const short8* bf = (const short8*)Bfrag;
  short8 B0 = bf[(0 * 1024 + col) * 4 + g];
  short8 B1 = bf[(1 * 1024 + col) * 4 + g];
  short8 B2 = bf[(2 * 1024 + col) * 4 + g];
  short8 B3 = bf[(3 * 1024 + col) * 4 + g];

  size_t base = (size_t)(shape * 1024 + pc * 512 + (l & 15)) * 64 + g * 8;
  const unsigned short* ah = Ahi + base;
  const unsigned short* al = Alo + base;

  float mcol = -1e30f;
  for (int it = 0; it < 16; ++it) {
    size_t r0 = (size_t)it * 32 * 64;
#pragma unroll
    for (int msub = 0; msub < 2; ++msub) {
      size_t o = r0 + (size_t)msub * 16 * 64;
      short8 ah0 = *(const short8*)(ah + o);
      short8 ah1 = *(const short8*)(ah + o + 32);
      short8 al0 = *(const short8*)(al + o);
      short8 al1 = *(const short8*)(al + o + 32);
      f32x4 acc = {0.f, 0.f, 0.f, 0.f};
      acc = __builtin_amdgcn_mfma_f32_16x16x32_bf16(ah0, B0, acc, 0, 0, 0);
      acc = __builtin_amdgcn_mfma_f32_16x16x32_bf16(ah1, B1, acc, 0, 0, 0);
      acc = __builtin_amdgcn_mfma_f32_16x16x32_bf16(ah0, B2, acc, 0, 0, 0);
      acc = __builtin_amdgcn_mfma_f32_16x16x32_bf16(ah1, B3, acc, 0, 0, 0);
      acc = __builtin_amdgcn_mfma_f32_16x16x32_bf16(al0, B0, acc, 0, 0, 0);
      acc = __builtin_amdgcn_mfma_f32_16x16x32_bf16(al1, B1, acc, 0, 0, 0);
      mcol = fmaxf(mcol, acc[0]);
      mcol = fmaxf(mcol, acc[1]);
      mcol = fmaxf(mcol, acc[2]);
      mcol = fmaxf(mcol, acc[3]);
    }
  }
  // lanes l, l^16, l^32, l^48 hold the same col (different row subsets)
  mcol = fmaxf(mcol, __shfl_xor(mcol, 16));
  mcol = fmaxf(mcol, __shfl_xor(mcol, 32));
  if (g == 0) {
    float v = fmaxf(mcol + b3[col], 0.f);
    atomicMax(&gf[shape * 1024 + col], __float_as_uint(v));
  }
}

// ---------------- MLP head ----------------
__global__ __launch_bounds__(256) void k_fc(const float* __restrict__ in, const float* __restrict__ w,
                                            const float* __restrict__ bias, float* __restrict__ out,
                                            int K, int J, int jmask, int jshift) {
  int t = blockIdx.x * 256 + threadIdx.x;
  int j = t & jmask, bb = t >> jshift;
  float acc = bias[j];
  const float* row = in + (size_t)bb * K;
  for (int k = 0; k < K; k += 4) {
    float4 q = *(const float4*)&row[k];
    acc = fmaf(q.x, w[(k + 0) * J + j], acc);
    acc = fmaf(q.y, w[(k + 1) * J + j], acc);
    acc = fmaf(q.z, w[(k + 2) * J + j], acc);
    acc = fmaf(q.w, w[(k + 3) * J + j], acc);
  }
  out[t] = acc;
}

__global__ __launch_bounds__(256) void k_bn(const float* __restrict__ z, const float* __restrict__ g,
                                            const float* __restrict__ bt, float* __restrict__ out, int J) {
  int j = blockIdx.x * 256 + threadIdx.x;
  if (j >= J) return;
  float s = 0.f;
  for (int bb = 0; bb < 64; ++bb) s += z[bb * J + j];
  float mean = s * (1.0f / 64.0f);
  float v = 0.f;
  for (int bb = 0; bb < 64; ++bb) {
    float d = z[bb * J + j] - mean;
    v = fmaf(d, d, v);
  }
  float inv = 1.0f / sqrtf(v * (1.0f / 64.0f) + 1e-5f);
  float gg = g[j] * inv, beta = bt[j];
  for (int bb = 0; bb < 64; ++bb)
    out[bb * J + j] = fmaxf(fmaf(z[bb * J + j] - mean, gg, beta), 0.f);
}

__global__ __launch_bounds__(64) void k_head(const float* __restrict__ z, const float* __restrict__ w,
                                             const float* __restrict__ b, float* __restrict__ out) {
  int bb = blockIdx.x, j = threadIdx.x;
  float acc = -INFINITY;
  if (j < 40) {
    acc = b[j];
    const float* row = z + bb * 256;
    for (int k = 0; k < 256; ++k) acc = fmaf(row[k], w[k * 40 + j], acc);
  }
  float m = acc;
  for (int d = 32; d > 0; d >>= 1) m = fmaxf(m, __shfl_xor(m, d));
  float e = (j < 40) ? expf(acc - m) : 0.f;
  for (int d = 32; d > 0; d >>= 1) e += __shfl_xor(e, d);
  if (j < 40) out[bb * 40 + j] = acc - m - logf(e);
}

extern "C" void kernel_launch(void* const* d_in, const int* in_sizes, int n_in,
                              void* d_out, int out_size, void* d_ws, size_t ws_size,
                              hipStream_t stream) {
  (void)in_sizes; (void)n_in; (void)out_size; (void)ws_size;
  const float* x    = (const float*)d_in[0];
  const int*   esrc = (const int*)d_in[1];
  const int*   edst = (const int*)d_in[2];
  const float* ev   = (const float*)d_in[3];
  const float* gc1w = (const float*)d_in[5];
  const float* gc1b = (const float*)d_in[6];
  const float* gc2w = (const float*)d_in[7];
  const float* gc2b = (const float*)d_in[8];
  const float* gc3w = (const float*)d_in[9];
  const float* gc3b = (const float*)d_in[10];
  const float* fc1w = (const float*)d_in[11];
  const float* fc1b = (const float*)d_in[12];
  const float* bn1g = (const float*)d_in[13];
  const float* bn1b = (const float*)d_in[14];
  const float* fc2w = (const float*)d_in[15];
  const float* fc2b = (const float*)d_in[16];
  const float* bn2g = (const float*)d_in[17];
  const float* bn2b = (const float*)d_in[18];
  const float* fc3w = (const float*)d_in[19];
  const float* fc3b = (const float*)d_in[20];

  char* ws = (char*)d_ws;
  size_t o = 0;
  auto alloc = [&](size_t bytes) -> void* {
    void* p = ws + o;
    o += (bytes + 255) & ~(size_t)255;
    return p;
  };
  int*   deg  = (int*)alloc((size_t)NN * 4);
  int*   off  = (int*)alloc((size_t)(NN + 1) * 4);
  int*   cur  = (int*)alloc((size_t)NN * 4);
  int2*  pack = (int2*)alloc((size_t)NE * 8);
  float* aggx = (float*)alloc((size_t)NN * 3 * 4);
  float* bufA = (float*)alloc((size_t)NN * 64 * 4);  // h1, then h2
  float* bufB = (float*)alloc((size_t)NN * 64 * 4);  // agg2; then reused as Ahi/Alo planes
  unsigned short* Ahi = (unsigned short*)bufB;              // 8 MB
  unsigned short* Alo = (unsigned short*)(bufB + NN * 32);  // 8 MB
  unsigned short* Bfrag = (unsigned short*)alloc(4 * 1024 * 32 * 2);  // 256 KB
  float* gf   = (float*)alloc(64 * 1024 * 4);
  float* z1   = (float*)alloc(64 * 512 * 4);
  float* z1n  = (float*)alloc(64 * 512 * 4);
  float* z2   = (float*)alloc(64 * 256 * 4);
  float* z2n  = (float*)alloc(64 * 256 * 4);

  hipMemsetAsync(deg, 0, (size_t)NN * 4, stream);
  hipMemsetAsync(gf, 0, 64 * 1024 * 4, stream);

  k_hist<<<NE / 256, 256, 0, stream>>>(edst, deg);
  k_scan<<<1, 1024, 0, stream>>>(deg, off, cur);
  k_scatter<<<NE / 256, 256, 0, stream>>>(esrc, edst, ev, cur, pack);
  k_prepw<<<512, 256, 0, stream>>>(gc3w, Bfrag);

  // layer 1
  k_aggx<<<NN / 256, 256, 0, stream>>>(off, pack, x, aggx);
  k_gemm1<<<(NN * 64) / 256, 256, 0, stream>>>(aggx, gc1w, gc1b, bufA);

  // layer 2
  k_agg64<<<NN / 4, 256, 0, stream>>>(off, pack, bufA, bufB);
  k_gemm2<<<NN / 32, 256, 0, stream>>>(bufB, gc2w, gc2b, bufA);

  // layer 3: aggregate h2 -> split-bf16 planes, then MFMA GEMM + maxpool
  k_agg64_split<<<NN / 4, 256, 0, stream>>>(off, pack, bufA, Ahi, Alo);
  k_gemm3max<<<64 * 32, 256, 0, stream>>>(Ahi, Alo, Bfrag, gc3b, (unsigned*)gf);

  // MLP head
  k_fc<<<(64 * 512) / 256, 256, 0, stream>>>(gf, fc1w, fc1b, z1, 1024, 512, 511, 9);
  k_bn<<<2, 256, 0, stream>>>(z1, bn1g, bn1b, z1n, 512);
  k_fc<<<(64 * 256) / 256, 256, 0, stream>>>(z1n, fc2w, fc2b, z2, 512, 256, 255, 8);
  k_bn<<<1, 256, 0, stream>>>(z2, bn2g, bn2b, z2n, 256);
  k_head<<<64, 64, 0, stream>>>(z2n, fc3w, fc3b, (float*)d_out);
}

// Round 3
// 490.573 us; speedup vs baseline: 1.5732x; 1.4231x over previous
//
#include <hip/hip_runtime.h>
#include <math.h>

#define NN 65536
#define NE 1048576

typedef __attribute__((ext_vector_type(8))) short short8;
typedef __attribute__((ext_vector_type(4))) float f32x4;

__device__ inline unsigned short f2bf(float f) {
  unsigned u = __float_as_uint(f);
  unsigned r = u + 0x7fff + ((u >> 16) & 1);  // RNE
  return (unsigned short)(r >> 16);
}
__device__ inline float bf2f(unsigned short h) { return __uint_as_float(((unsigned)h) << 16); }

// ---------------- CSR build ----------------
__global__ __launch_bounds__(256) void k_hist(const int* __restrict__ dst, int* __restrict__ deg) {
  int e = blockIdx.x * 256 + threadIdx.x;
  atomicAdd(&deg[dst[e]], 1);
}

__global__ __launch_bounds__(1024) void k_scan(const int* __restrict__ deg, int* __restrict__ off,
                                               int* __restrict__ cur) {
  __shared__ int buf[1024];
  int t = threadIdx.x;
  int base = t * 64;
  int s = 0;
  for (int i = 0; i < 64; ++i) s += deg[base + i];
  buf[t] = s;
  __syncthreads();
  for (int d = 1; d < 1024; d <<= 1) {
    int xv = (t >= d) ? buf[t - d] : 0;
    __syncthreads();
    buf[t] += xv;
    __syncthreads();
  }
  int run = buf[t] - s;
  for (int i = 0; i < 64; ++i) {
    int dg = deg[base + i];
    off[base + i] = run;
    cur[base + i] = run;
    run += dg;
  }
  if (t == 1023) off[NN] = run;
}

__global__ __launch_bounds__(256) void k_scatter(const int* __restrict__ src, const int* __restrict__ dst,
                                                 const float* __restrict__ val, int* __restrict__ cur,
                                                 int2* __restrict__ pack) {
  int e = blockIdx.x * 256 + threadIdx.x;
  int d = dst[e];
  int p = atomicAdd(&cur[d], 1);
  pack[p] = make_int2(src[e], __float_as_int(val[e]));
}

// ---------------- GCN layer 1 ----------------
__global__ __launch_bounds__(256) void k_aggx(const int* __restrict__ off, const int2* __restrict__ pack,
                                              const float* __restrict__ x, float* __restrict__ aggx) {
  int n = blockIdx.x * 256 + threadIdx.x;
  int i = off[n], e = off[n + 1];
  float a0 = 0.f, a1 = 0.f, a2 = 0.f;
  float b0 = 0.f, b1 = 0.f, b2 = 0.f;
  for (; i + 2 <= e; i += 2) {
    int2 e0 = pack[i], e1 = pack[i + 1];
    float v0 = __int_as_float(e0.y), v1 = __int_as_float(e1.y);
    const float* x0 = &x[3 * e0.x];
    const float* x1 = &x[3 * e1.x];
    a0 = fmaf(v0, x0[0], a0);
    a1 = fmaf(v0, x0[1], a1);
    a2 = fmaf(v0, x0[2], a2);
    b0 = fmaf(v1, x1[0], b0);
    b1 = fmaf(v1, x1[1], b1);
    b2 = fmaf(v1, x1[2], b2);
  }
  if (i < e) {
    int2 e0 = pack[i];
    float v0 = __int_as_float(e0.y);
    const float* x0 = &x[3 * e0.x];
    a0 = fmaf(v0, x0[0], a0);
    a1 = fmaf(v0, x0[1], a1);
    a2 = fmaf(v0, x0[2], a2);
  }
  aggx[n * 3 + 0] = a0 + b0;
  aggx[n * 3 + 1] = a1 + b1;
  aggx[n * 3 + 2] = a2 + b2;
}

__global__ __launch_bounds__(256) void k_gemm1(const float* __restrict__ aggx, const float* __restrict__ w,
                                               const float* __restrict__ b, float* __restrict__ out) {
  __shared__ float sw[256];
  int t = threadIdx.x;
  sw[t] = (t < 192) ? w[t] : b[t - 192];
  __syncthreads();
  int g = blockIdx.x * 256 + t;
  int n = g >> 6, j = g & 63;
  float a0 = aggx[n * 3], a1 = aggx[n * 3 + 1], a2 = aggx[n * 3 + 2];
  float r = sw[192 + j];
  r = fmaf(a0, sw[j], r);
  r = fmaf(a1, sw[64 + j], r);
  r = fmaf(a2, sw[128 + j], r);
  out[g] = fmaxf(r, 0.f);
}

// ---------------- 64-feature aggregation: wave per node, lane = feature, 4-way edge ILP ----
__global__ __launch_bounds__(256) void k_agg64(const int* __restrict__ off, const int2* __restrict__ pack,
                                               const float* __restrict__ h, float* __restrict__ out) {
  int lane = threadIdx.x & 63;
  int n = blockIdx.x * 4 + (threadIdx.x >> 6);
  int i = off[n], e = off[n + 1];
  float a0 = 0.f, a1 = 0.f, a2 = 0.f, a3 = 0.f;
  for (; i + 4 <= e; i += 4) {
    int2 e0 = pack[i], e1 = pack[i + 1], e2 = pack[i + 2], e3 = pack[i + 3];
    a0 = fmaf(__int_as_float(e0.y), h[(size_t)e0.x * 64 + lane], a0);
    a1 = fmaf(__int_as_float(e1.y), h[(size_t)e1.x * 64 + lane], a1);
    a2 = fmaf(__int_as_float(e2.y), h[(size_t)e2.x * 64 + lane], a2);
    a3 = fmaf(__int_as_float(e3.y), h[(size_t)e3.x * 64 + lane], a3);
  }
  for (; i < e; ++i) {
    int2 ed = pack[i];
    a0 = fmaf(__int_as_float(ed.y), h[(size_t)ed.x * 64 + lane], a0);
  }
  out[(size_t)n * 64 + lane] = (a0 + a1) + (a2 + a3);
}

// same aggregation, but emit split-bf16 planes (hi, lo) for the MFMA GEMM
__global__ __launch_bounds__(256) void k_agg64_split(const int* __restrict__ off, const int2* __restrict__ pack,
                                                     const float* __restrict__ h,
                                                     unsigned short* __restrict__ hi,
                                                     unsigned short* __restrict__ lo) {
  int lane = threadIdx.x & 63;
  int n = blockIdx.x * 4 + (threadIdx.x >> 6);
  int i = off[n], e = off[n + 1];
  float a0 = 0.f, a1 = 0.f, a2 = 0.f, a3 = 0.f;
  for (; i + 4 <= e; i += 4) {
    int2 e0 = pack[i], e1 = pack[i + 1], e2 = pack[i + 2], e3 = pack[i + 3];
    a0 = fmaf(__int_as_float(e0.y), h[(size_t)e0.x * 64 + lane], a0);
    a1 = fmaf(__int_as_float(e1.y), h[(size_t)e1.x * 64 + lane], a1);
    a2 = fmaf(__int_as_float(e2.y), h[(size_t)e2.x * 64 + lane], a2);
    a3 = fmaf(__int_as_float(e3.y), h[(size_t)e3.x * 64 + lane], a3);
  }
  for (; i < e; ++i) {
    int2 ed = pack[i];
    a0 = fmaf(__int_as_float(ed.y), h[(size_t)ed.x * 64 + lane], a0);
  }
  float acc = (a0 + a1) + (a2 + a3);
  unsigned short h16 = f2bf(acc);
  unsigned short l16 = f2bf(acc - bf2f(h16));
  size_t idx = (size_t)n * 64 + lane;
  hi[idx] = h16;
  lo[idx] = l16;
}

// ---------------- GCN layer 2 GEMM (fp32 VALU, unchanged) ----------------
__global__ __launch_bounds__(256) void k_gemm2(const float* __restrict__ agg, const float* __restrict__ w2,
                                               const float* __restrict__ b2, float* __restrict__ out) {
  int lane = threadIdx.x & 63, wv = threadIdx.x >> 6;
  float w[64];
#pragma unroll
  for (int k = 0; k < 64; ++k) w[k] = w2[k * 64 + lane];
  float bb = b2[lane];
  int n0 = blockIdx.x * 32 + wv * 8;
  for (int t = 0; t < 8; ++t) {
    int n = n0 + t;
    const float4* row = (const float4*)&agg[(size_t)n * 64];
    float acc = bb;
#pragma unroll
    for (int kk = 0; kk < 16; ++kk) {
      float4 q = row[kk];
      acc = fmaf(q.x, w[4 * kk + 0], acc);
      acc = fmaf(q.y, w[4 * kk + 1], acc);
      acc = fmaf(q.z, w[4 * kk + 2], acc);
      acc = fmaf(q.w, w[4 * kk + 3], acc);
    }
    out[(size_t)n * 64 + lane] = fmaxf(acc, 0.f);
  }
}

// ---------------- W3 prep: split-bf16, MFMA-fragment order ----------------
// Bfrag layout: [q][col][g][e]  (q: 0,1 = Whi k0-31/k32-63; 2,3 = Wlo k0-31/k32-63)
__global__ __launch_bounds__(256) void k_prepw(const float* __restrict__ w3, unsigned short* __restrict__ bfrag) {
  int t = blockIdx.x * 256 + threadIdx.x;  // 131072 total
  int e = t & 7, g = (t >> 3) & 3, col = (t >> 5) & 1023, q = t >> 15;
  int k = (q & 1) * 32 + g * 8 + e;
  float v = w3[k * 1024 + col];
  unsigned short hv = f2bf(v);
  bfrag[t] = (q < 2) ? hv : f2bf(v - bf2f(hv));
}

// ---------------- GCN layer 3 GEMM + maxpool via MFMA (split-bf16) ----------------
// Re-tiled: grid 512 = 256 rowchunks x 2 colhalves; block 512 = 8 waves.
// Each wave: 4 col-tiles of B resident in 64 VGPRs, streams 16 A-tiles (256 rows).
// Per 4 A-loads -> 24 MFMAs.
__global__ __launch_bounds__(512) void k_gemm3max(const unsigned short* __restrict__ Ahi,
                                                  const unsigned short* __restrict__ Alo,
                                                  const unsigned short* __restrict__ Bfrag,
                                                  const float* __restrict__ b3,
                                                  unsigned* __restrict__ gf) {
  int b = blockIdx.x;
  int colhalf = b & 1, rowchunk = b >> 1;  // rowchunk 0..255 (256 rows each)
  int shape = rowchunk >> 2;
  int tid = threadIdx.x;
  int wv = tid >> 6, l = tid & 63;
  int g = l >> 4, lr = l & 15;

  const short8* bf = (const short8*)Bfrag;
  int c0 = colhalf * 512 + wv * 64 + lr;
  short8 B0[4], B1[4], B2[4], B3[4];
#pragma unroll
  for (int ct = 0; ct < 4; ++ct) {
    int col = c0 + ct * 16;
    B0[ct] = bf[(0 * 1024 + col) * 4 + g];
    B1[ct] = bf[(1 * 1024 + col) * 4 + g];
    B2[ct] = bf[(2 * 1024 + col) * 4 + g];
    B3[ct] = bf[(3 * 1024 + col) * 4 + g];
  }

  float m[4] = {-1e30f, -1e30f, -1e30f, -1e30f};
  size_t abase = ((size_t)rowchunk * 256 + lr) * 64 + g * 8;
  for (int t = 0; t < 16; ++t) {
    size_t o = abase + (size_t)t * 16 * 64;
    short8 ah0 = *(const short8*)(Ahi + o);
    short8 ah1 = *(const short8*)(Ahi + o + 32);
    short8 al0 = *(const short8*)(Alo + o);
    short8 al1 = *(const short8*)(Alo + o + 32);
#pragma unroll
    for (int ct = 0; ct < 4; ++ct) {
      f32x4 acc = {0.f, 0.f, 0.f, 0.f};
      acc = __builtin_amdgcn_mfma_f32_16x16x32_bf16(ah0, B0[ct], acc, 0, 0, 0);
      acc = __builtin_amdgcn_mfma_f32_16x16x32_bf16(ah1, B1[ct], acc, 0, 0, 0);
      acc = __builtin_amdgcn_mfma_f32_16x16x32_bf16(ah0, B2[ct], acc, 0, 0, 0);
      acc = __builtin_amdgcn_mfma_f32_16x16x32_bf16(ah1, B3[ct], acc, 0, 0, 0);
      acc = __builtin_amdgcn_mfma_f32_16x16x32_bf16(al0, B0[ct], acc, 0, 0, 0);
      acc = __builtin_amdgcn_mfma_f32_16x16x32_bf16(al1, B1[ct], acc, 0, 0, 0);
      m[ct] = fmaxf(m[ct], fmaxf(fmaxf(acc[0], acc[1]), fmaxf(acc[2], acc[3])));
    }
  }
#pragma unroll
  for (int ct = 0; ct < 4; ++ct) {
    float mm = m[ct];
    mm = fmaxf(mm, __shfl_xor(mm, 16));
    mm = fmaxf(mm, __shfl_xor(mm, 32));
    if (g == 0) {
      int col = c0 + ct * 16;
      float v = fmaxf(mm + b3[col], 0.f);
      atomicMax(&gf[shape * 1024 + col], __float_as_uint(v));
    }
  }
}

// ---------------- MLP head ----------------
__global__ __launch_bounds__(256) void k_fc(const float* __restrict__ in, const float* __restrict__ w,
                                            const float* __restrict__ bias, float* __restrict__ out,
                                            int K, int J, int jmask, int jshift) {
  int t = blockIdx.x * 256 + threadIdx.x;
  int j = t & jmask, bb = t >> jshift;
  float acc = bias[j];
  const float* row = in + (size_t)bb * K;
  for (int k = 0; k < K; k += 4) {
    float4 q = *(const float4*)&row[k];
    acc = fmaf(q.x, w[(k + 0) * J + j], acc);
    acc = fmaf(q.y, w[(k + 1) * J + j], acc);
    acc = fmaf(q.z, w[(k + 2) * J + j], acc);
    acc = fmaf(q.w, w[(k + 3) * J + j], acc);
  }
  out[t] = acc;
}

__global__ __launch_bounds__(256) void k_bn(const float* __restrict__ z, const float* __restrict__ g,
                                            const float* __restrict__ bt, float* __restrict__ out, int J) {
  int j = blockIdx.x * 256 + threadIdx.x;
  if (j >= J) return;
  float s = 0.f;
  for (int bb = 0; bb < 64; ++bb) s += z[bb * J + j];
  float mean = s * (1.0f / 64.0f);
  float v = 0.f;
  for (int bb = 0; bb < 64; ++bb) {
    float d = z[bb * J + j] - mean;
    v = fmaf(d, d, v);
  }
  float inv = 1.0f / sqrtf(v * (1.0f / 64.0f) + 1e-5f);
  float gg = g[j] * inv, beta = bt[j];
  for (int bb = 0; bb < 64; ++bb)
    out[bb * J + j] = fmaxf(fmaf(z[bb * J + j] - mean, gg, beta), 0.f);
}

__global__ __launch_bounds__(64) void k_head(const float* __restrict__ z, const float* __restrict__ w,
                                             const float* __restrict__ b, float* __restrict__ out) {
  int bb = blockIdx.x, j = threadIdx.x;
  float acc = -INFINITY;
  if (j < 40) {
    acc = b[j];
    const float* row = z + bb * 256;
    for (int k = 0; k < 256; ++k) acc = fmaf(row[k], w[k * 40 + j], acc);
  }
  float m = acc;
  for (int d = 32; d > 0; d >>= 1) m = fmaxf(m, __shfl_xor(m, d));
  float e = (j < 40) ? expf(acc - m) : 0.f;
  for (int d = 32; d > 0; d >>= 1) e += __shfl_xor(e, d);
  if (j < 40) out[bb * 40 + j] = acc - m - logf(e);
}

extern "C" void kernel_launch(void* const* d_in, const int* in_sizes, int n_in,
                              void* d_out, int out_size, void* d_ws, size_t ws_size,
                              hipStream_t stream) {
  (void)in_sizes; (void)n_in; (void)out_size; (void)ws_size;
  const float* x    = (const float*)d_in[0];
  const int*   esrc = (const int*)d_in[1];
  const int*   edst = (const int*)d_in[2];
  const float* ev   = (const float*)d_in[3];
  const float* gc1w = (const float*)d_in[5];
  const float* gc1b = (const float*)d_in[6];
  const float* gc2w = (const float*)d_in[7];
  const float* gc2b = (const float*)d_in[8];
  const float* gc3w = (const float*)d_in[9];
  const float* gc3b = (const float*)d_in[10];
  const float* fc1w = (const float*)d_in[11];
  const float* fc1b = (const float*)d_in[12];
  const float* bn1g = (const float*)d_in[13];
  const float* bn1b = (const float*)d_in[14];
  const float* fc2w = (const float*)d_in[15];
  const float* fc2b = (const float*)d_in[16];
  const float* bn2g = (const float*)d_in[17];
  const float* bn2b = (const float*)d_in[18];
  const float* fc3w = (const float*)d_in[19];
  const float* fc3b = (const float*)d_in[20];

  char* ws = (char*)d_ws;
  size_t o = 0;
  auto alloc = [&](size_t bytes) -> void* {
    void* p = ws + o;
    o += (bytes + 255) & ~(size_t)255;
    return p;
  };
  int*   deg  = (int*)alloc((size_t)NN * 4);
  int*   off  = (int*)alloc((size_t)(NN + 1) * 4);
  int*   cur  = (int*)alloc((size_t)NN * 4);
  int2*  pack = (int2*)alloc((size_t)NE * 8);
  float* aggx = (float*)alloc((size_t)NN * 3 * 4);
  float* bufA = (float*)alloc((size_t)NN * 64 * 4);  // h1, then h2
  float* bufB = (float*)alloc((size_t)NN * 64 * 4);  // agg2; then reused as Ahi/Alo planes
  unsigned short* Ahi = (unsigned short*)bufB;              // 8 MB
  unsigned short* Alo = (unsigned short*)(bufB + NN * 32);  // 8 MB
  unsigned short* Bfrag = (unsigned short*)alloc(4 * 1024 * 32 * 2);  // 256 KB
  float* gf   = (float*)alloc(64 * 1024 * 4);
  float* z1   = (float*)alloc(64 * 512 * 4);
  float* z1n  = (float*)alloc(64 * 512 * 4);
  float* z2   = (float*)alloc(64 * 256 * 4);
  float* z2n  = (float*)alloc(64 * 256 * 4);

  hipMemsetAsync(deg, 0, (size_t)NN * 4, stream);
  hipMemsetAsync(gf, 0, 64 * 1024 * 4, stream);

  k_hist<<<NE / 256, 256, 0, stream>>>(edst, deg);
  k_scan<<<1, 1024, 0, stream>>>(deg, off, cur);
  k_scatter<<<NE / 256, 256, 0, stream>>>(esrc, edst, ev, cur, pack);
  k_prepw<<<512, 256, 0, stream>>>(gc3w, Bfrag);

  // layer 1
  k_aggx<<<NN / 256, 256, 0, stream>>>(off, pack, x, aggx);
  k_gemm1<<<(NN * 64) / 256, 256, 0, stream>>>(aggx, gc1w, gc1b, bufA);

  // layer 2
  k_agg64<<<NN / 4, 256, 0, stream>>>(off, pack, bufA, bufB);
  k_gemm2<<<NN / 32, 256, 0, stream>>>(bufB, gc2w, gc2b, bufA);

  // layer 3: aggregate h2 -> split-bf16 planes, then MFMA GEMM + maxpool
  k_agg64_split<<<NN / 4, 256, 0, stream>>>(off, pack, bufA, Ahi, Alo);
  k_gemm3max<<<512, 512, 0, stream>>>(Ahi, Alo, Bfrag, gc3b, (unsigned*)gf);

  // MLP head
  k_fc<<<(64 * 512) / 256, 256, 0, stream>>>(gf, fc1w, fc1b, z1, 1024, 512, 511, 9);
  k_bn<<<2, 256, 0, stream>>>(z1, bn1g, bn1b, z1n, 512);
  k_fc<<<(64 * 256) / 256, 256, 0, stream>>>(z1n, fc2w, fc2b, z2, 512, 256, 255, 8);
  k_bn<<<1, 256, 0, stream>>>(z2, bn2g, bn2b, z2n, 256);
  k_head<<<64, 64, 0, stream>>>(z2n, fc3w, fc3b, (float*)d_out);
}

// Round 4
// 411.662 us; speedup vs baseline: 1.8747x; 1.1917x over previous
//
#include <hip/hip_runtime.h>
#include <math.h>

#define NN 65536
#define NE 1048576

typedef __attribute__((ext_vector_type(8))) short short8;
typedef __attribute__((ext_vector_type(4))) float f32x4;

__device__ inline unsigned short f2bf(float f) {
  unsigned u = __float_as_uint(f);
  unsigned r = u + 0x7fff + ((u >> 16) & 1);  // RNE
  return (unsigned short)(r >> 16);
}
__device__ inline float bf2f(unsigned short h) { return __uint_as_float(((unsigned)h) << 16); }

// ---------------- CSR build ----------------
__global__ __launch_bounds__(256) void k_hist(const int* __restrict__ dst, int* __restrict__ deg) {
  int e = blockIdx.x * 256 + threadIdx.x;
  atomicAdd(&deg[dst[e]], 1);
}

__global__ __launch_bounds__(1024) void k_scan(const int* __restrict__ deg, int* __restrict__ off,
                                               int* __restrict__ cur) {
  __shared__ int buf[1024];
  int t = threadIdx.x;
  int base = t * 64;
  int s = 0;
  for (int i = 0; i < 64; ++i) s += deg[base + i];
  buf[t] = s;
  __syncthreads();
  for (int d = 1; d < 1024; d <<= 1) {
    int xv = (t >= d) ? buf[t - d] : 0;
    __syncthreads();
    buf[t] += xv;
    __syncthreads();
  }
  int run = buf[t] - s;
  for (int i = 0; i < 64; ++i) {
    int dg = deg[base + i];
    off[base + i] = run;
    cur[base + i] = run;
    run += dg;
  }
  if (t == 1023) off[NN] = run;
}

__global__ __launch_bounds__(256) void k_scatter(const int* __restrict__ src, const int* __restrict__ dst,
                                                 const float* __restrict__ val, int* __restrict__ cur,
                                                 int2* __restrict__ pack) {
  int e = blockIdx.x * 256 + threadIdx.x;
  int d = dst[e];
  int p = atomicAdd(&cur[d], 1);
  pack[p] = make_int2(src[e], __float_as_int(val[e]));
}

// ---------------- GCN layer 1 ----------------
__global__ __launch_bounds__(256) void k_packx(const float* __restrict__ x, float4* __restrict__ x4) {
  int n = blockIdx.x * 256 + threadIdx.x;
  x4[n] = make_float4(x[3 * n], x[3 * n + 1], x[3 * n + 2], 0.f);
}

__global__ __launch_bounds__(256) void k_aggx(const int* __restrict__ off, const int2* __restrict__ pack,
                                              const float4* __restrict__ x4, float* __restrict__ aggx) {
  int n = blockIdx.x * 256 + threadIdx.x;
  int i = off[n], e = off[n + 1];
  float a0 = 0.f, a1 = 0.f, a2 = 0.f;
  float b0 = 0.f, b1 = 0.f, b2 = 0.f;
  for (; i + 2 <= e; i += 2) {
    int2 e0 = pack[i], e1 = pack[i + 1];
    float v0 = __int_as_float(e0.y), v1 = __int_as_float(e1.y);
    float4 q0 = x4[e0.x];
    float4 q1 = x4[e1.x];
    a0 = fmaf(v0, q0.x, a0);
    a1 = fmaf(v0, q0.y, a1);
    a2 = fmaf(v0, q0.z, a2);
    b0 = fmaf(v1, q1.x, b0);
    b1 = fmaf(v1, q1.y, b1);
    b2 = fmaf(v1, q1.z, b2);
  }
  if (i < e) {
    int2 e0 = pack[i];
    float v0 = __int_as_float(e0.y);
    float4 q0 = x4[e0.x];
    a0 = fmaf(v0, q0.x, a0);
    a1 = fmaf(v0, q0.y, a1);
    a2 = fmaf(v0, q0.z, a2);
  }
  aggx[n * 3 + 0] = a0 + b0;
  aggx[n * 3 + 1] = a1 + b1;
  aggx[n * 3 + 2] = a2 + b2;
}

__global__ __launch_bounds__(256) void k_gemm1(const float* __restrict__ aggx, const float* __restrict__ w,
                                               const float* __restrict__ b, float* __restrict__ out) {
  __shared__ float sw[256];
  int t = threadIdx.x;
  sw[t] = (t < 192) ? w[t] : b[t - 192];
  __syncthreads();
  int g = blockIdx.x * 256 + t;
  int n = g >> 6, j = g & 63;
  float a0 = aggx[n * 3], a1 = aggx[n * 3 + 1], a2 = aggx[n * 3 + 2];
  float r = sw[192 + j];
  r = fmaf(a0, sw[j], r);
  r = fmaf(a1, sw[64 + j], r);
  r = fmaf(a2, sw[128 + j], r);
  out[g] = fmaxf(r, 0.f);
}

// ---------------- 64-feature aggregation (fp32 h), 4-way edge ILP ----------------
__global__ __launch_bounds__(256) void k_agg64(const int* __restrict__ off, const int2* __restrict__ pack,
                                               const float* __restrict__ h, float* __restrict__ out) {
  int lane = threadIdx.x & 63;
  int n = blockIdx.x * 4 + (threadIdx.x >> 6);
  int i = off[n], e = off[n + 1];
  float a0 = 0.f, a1 = 0.f, a2 = 0.f, a3 = 0.f;
  for (; i + 4 <= e; i += 4) {
    int2 e0 = pack[i], e1 = pack[i + 1], e2 = pack[i + 2], e3 = pack[i + 3];
    a0 = fmaf(__int_as_float(e0.y), h[(size_t)e0.x * 64 + lane], a0);
    a1 = fmaf(__int_as_float(e1.y), h[(size_t)e1.x * 64 + lane], a1);
    a2 = fmaf(__int_as_float(e2.y), h[(size_t)e2.x * 64 + lane], a2);
    a3 = fmaf(__int_as_float(e3.y), h[(size_t)e3.x * 64 + lane], a3);
  }
  for (; i < e; ++i) {
    int2 ed = pack[i];
    a0 = fmaf(__int_as_float(ed.y), h[(size_t)ed.x * 64 + lane], a0);
  }
  out[(size_t)n * 64 + lane] = (a0 + a1) + (a2 + a3);
}

// 64-feature aggregation from bf16 h, emitting split-bf16 planes for the MFMA GEMM
__global__ __launch_bounds__(256) void k_agg64_split(const int* __restrict__ off, const int2* __restrict__ pack,
                                                     const unsigned short* __restrict__ h,
                                                     unsigned short* __restrict__ hi,
                                                     unsigned short* __restrict__ lo) {
  int lane = threadIdx.x & 63;
  int n = blockIdx.x * 4 + (threadIdx.x >> 6);
  int i = off[n], e = off[n + 1];
  float a0 = 0.f, a1 = 0.f, a2 = 0.f, a3 = 0.f;
  for (; i + 4 <= e; i += 4) {
    int2 e0 = pack[i], e1 = pack[i + 1], e2 = pack[i + 2], e3 = pack[i + 3];
    a0 = fmaf(__int_as_float(e0.y), bf2f(h[(size_t)e0.x * 64 + lane]), a0);
    a1 = fmaf(__int_as_float(e1.y), bf2f(h[(size_t)e1.x * 64 + lane]), a1);
    a2 = fmaf(__int_as_float(e2.y), bf2f(h[(size_t)e2.x * 64 + lane]), a2);
    a3 = fmaf(__int_as_float(e3.y), bf2f(h[(size_t)e3.x * 64 + lane]), a3);
  }
  for (; i < e; ++i) {
    int2 ed = pack[i];
    a0 = fmaf(__int_as_float(ed.y), bf2f(h[(size_t)ed.x * 64 + lane]), a0);
  }
  float acc = (a0 + a1) + (a2 + a3);
  unsigned short h16 = f2bf(acc);
  unsigned short l16 = f2bf(acc - bf2f(h16));
  size_t idx = (size_t)n * 64 + lane;
  hi[idx] = h16;
  lo[idx] = l16;
}

// ---------------- GCN layer 2 GEMM: fp32 in, bf16 out ----------------
__global__ __launch_bounds__(256) void k_gemm2(const float* __restrict__ agg, const float* __restrict__ w2,
                                               const float* __restrict__ b2, unsigned short* __restrict__ out) {
  int lane = threadIdx.x & 63, wv = threadIdx.x >> 6;
  float w[64];
#pragma unroll
  for (int k = 0; k < 64; ++k) w[k] = w2[k * 64 + lane];
  float bb = b2[lane];
  int n0 = blockIdx.x * 32 + wv * 8;
  for (int t = 0; t < 8; ++t) {
    int n = n0 + t;
    const float4* row = (const float4*)&agg[(size_t)n * 64];
    float acc = bb;
#pragma unroll
    for (int kk = 0; kk < 16; ++kk) {
      float4 q = row[kk];
      acc = fmaf(q.x, w[4 * kk + 0], acc);
      acc = fmaf(q.y, w[4 * kk + 1], acc);
      acc = fmaf(q.z, w[4 * kk + 2], acc);
      acc = fmaf(q.w, w[4 * kk + 3], acc);
    }
    out[(size_t)n * 64 + lane] = f2bf(fmaxf(acc, 0.f));
  }
}

// ---------------- W3 prep: split-bf16, MFMA-fragment order ----------------
__global__ __launch_bounds__(256) void k_prepw(const float* __restrict__ w3, unsigned short* __restrict__ bfrag) {
  int t = blockIdx.x * 256 + threadIdx.x;  // 131072 total
  int e = t & 7, g = (t >> 3) & 3, col = (t >> 5) & 1023, q = t >> 15;
  int k = (q & 1) * 32 + g * 8 + e;
  float v = w3[k * 1024 + col];
  unsigned short hv = f2bf(v);
  bfrag[t] = (q < 2) ? hv : f2bf(v - bf2f(hv));
}

// ---------------- GCN layer 3 GEMM + maxpool via MFMA (split-bf16) ----------------
__global__ __launch_bounds__(512) void k_gemm3max(const unsigned short* __restrict__ Ahi,
                                                  const unsigned short* __restrict__ Alo,
                                                  const unsigned short* __restrict__ Bfrag,
                                                  const float* __restrict__ b3,
                                                  unsigned* __restrict__ gf) {
  int b = blockIdx.x;
  int colhalf = b & 1, rowchunk = b >> 1;  // rowchunk 0..255 (256 rows each)
  int shape = rowchunk >> 2;
  int tid = threadIdx.x;
  int wv = tid >> 6, l = tid & 63;
  int g = l >> 4, lr = l & 15;

  const short8* bf = (const short8*)Bfrag;
  int c0 = colhalf * 512 + wv * 64 + lr;
  short8 B0[4], B1[4], B2[4], B3[4];
#pragma unroll
  for (int ct = 0; ct < 4; ++ct) {
    int col = c0 + ct * 16;
    B0[ct] = bf[(0 * 1024 + col) * 4 + g];
    B1[ct] = bf[(1 * 1024 + col) * 4 + g];
    B2[ct] = bf[(2 * 1024 + col) * 4 + g];
    B3[ct] = bf[(3 * 1024 + col) * 4 + g];
  }

  float m[4] = {-1e30f, -1e30f, -1e30f, -1e30f};
  size_t abase = ((size_t)rowchunk * 256 + lr) * 64 + g * 8;
  for (int t = 0; t < 16; ++t) {
    size_t o = abase + (size_t)t * 16 * 64;
    short8 ah0 = *(const short8*)(Ahi + o);
    short8 ah1 = *(const short8*)(Ahi + o + 32);
    short8 al0 = *(const short8*)(Alo + o);
    short8 al1 = *(const short8*)(Alo + o + 32);
#pragma unroll
    for (int ct = 0; ct < 4; ++ct) {
      f32x4 acc = {0.f, 0.f, 0.f, 0.f};
      acc = __builtin_amdgcn_mfma_f32_16x16x32_bf16(ah0, B0[ct], acc, 0, 0, 0);
      acc = __builtin_amdgcn_mfma_f32_16x16x32_bf16(ah1, B1[ct], acc, 0, 0, 0);
      acc = __builtin_amdgcn_mfma_f32_16x16x32_bf16(ah0, B2[ct], acc, 0, 0, 0);
      acc = __builtin_amdgcn_mfma_f32_16x16x32_bf16(ah1, B3[ct], acc, 0, 0, 0);
      acc = __builtin_amdgcn_mfma_f32_16x16x32_bf16(al0, B0[ct], acc, 0, 0, 0);
      acc = __builtin_amdgcn_mfma_f32_16x16x32_bf16(al1, B1[ct], acc, 0, 0, 0);
      m[ct] = fmaxf(m[ct], fmaxf(fmaxf(acc[0], acc[1]), fmaxf(acc[2], acc[3])));
    }
  }
#pragma unroll
  for (int ct = 0; ct < 4; ++ct) {
    float mm = m[ct];
    mm = fmaxf(mm, __shfl_xor(mm, 16));
    mm = fmaxf(mm, __shfl_xor(mm, 32));
    if (g == 0) {
      int col = c0 + ct * 16;
      float v = fmaxf(mm + b3[col], 0.f);
      atomicMax(&gf[shape * 1024 + col], __float_as_uint(v));
    }
  }
}

// ---------------- MLP head ----------------
// grid (J/64, 64): block = 256 thr = 4 waves; wave s covers K/4; lanes = 64 cols.
__global__ __launch_bounds__(256) void k_fc(const float* __restrict__ in, const float* __restrict__ w,
                                            const float* __restrict__ bias, float* __restrict__ out,
                                            int K, int J) {
  __shared__ float sin_[1024];
  __shared__ float part[4][64];
  int jt = blockIdx.x, bb = blockIdx.y;
  int tid = threadIdx.x, s = tid >> 6, lane = tid & 63;
  for (int i = tid; i < K; i += 256) sin_[i] = in[bb * K + i];
  __syncthreads();
  int j = (jt << 6) + lane;
  int Kq = K >> 2;
  int k0 = s * Kq;
  float a0 = 0.f, a1 = 0.f, a2 = 0.f, a3 = 0.f;
  for (int k = 0; k < Kq; k += 4) {
    int kk = k0 + k;
    a0 = fmaf(sin_[kk + 0], w[(kk + 0) * J + j], a0);
    a1 = fmaf(sin_[kk + 1], w[(kk + 1) * J + j], a1);
    a2 = fmaf(sin_[kk + 2], w[(kk + 2) * J + j], a2);
    a3 = fmaf(sin_[kk + 3], w[(kk + 3) * J + j], a3);
  }
  part[s][lane] = (a0 + a1) + (a2 + a3);
  __syncthreads();
  if (tid < 64)
    out[bb * J + (jt << 6) + tid] =
        part[0][tid] + part[1][tid] + part[2][tid] + part[3][tid] + bias[(jt << 6) + tid];
}

// grid J/64: block 256 = 4 waves; 64 cols x 64 rows tile in LDS, two-pass BN + relu.
__global__ __launch_bounds__(256) void k_bn(const float* __restrict__ z, const float* __restrict__ g,
                                            const float* __restrict__ bt, float* __restrict__ out, int J) {
  __shared__ float tile[64][64];
  __shared__ float red[4][64];
  __shared__ float sc[64], sh[64];
  int tid = threadIdx.x, s = tid >> 6, lane = tid & 63;
  int j0 = blockIdx.x << 6;
  float psum = 0.f;
#pragma unroll
  for (int r = 0; r < 16; ++r) {
    int row = s * 16 + r;
    float v = z[row * J + j0 + lane];
    tile[row][lane] = v;
    psum += v;
  }
  red[s][lane] = psum;
  __syncthreads();
  if (tid < 64) sc[tid] = (red[0][tid] + red[1][tid] + red[2][tid] + red[3][tid]) * (1.f / 64.f);
  __syncthreads();
  float mean = sc[lane];
  float pv = 0.f;
#pragma unroll
  for (int r = 0; r < 16; ++r) {
    float d = tile[s * 16 + r][lane] - mean;
    pv = fmaf(d, d, pv);
  }
  red[s][lane] = pv;
  __syncthreads();
  if (tid < 64) {
    float var = (red[0][tid] + red[1][tid] + red[2][tid] + red[3][tid]) * (1.f / 64.f);
    float scale = g[j0 + tid] / sqrtf(var + 1e-5f);
    sh[tid] = bt[j0 + tid] - sc[tid] * scale;
    sc[tid] = scale;
  }
  __syncthreads();
  float scale = sc[lane], shift = sh[lane];
#pragma unroll
  for (int r = 0; r < 16; ++r) {
    int row = s * 16 + r;
    out[row * J + j0 + lane] = fmaxf(fmaf(tile[row][lane], scale, shift), 0.f);
  }
}

// grid 64: block 256 = 4 waves split K=256; wave0 does log_softmax over 40 logits.
__global__ __launch_bounds__(256) void k_head(const float* __restrict__ z, const float* __restrict__ w,
                                              const float* __restrict__ b, float* __restrict__ out) {
  __shared__ float sz[256];
  __shared__ float part[4][64];
  int bb = blockIdx.x, tid = threadIdx.x;
  sz[tid] = z[bb * 256 + tid];
  __syncthreads();
  int s = tid >> 6, j = tid & 63;
  float acc = 0.f;
  if (j < 40) {
#pragma unroll
    for (int k = 0; k < 64; k += 4) {
      int kk = s * 64 + k;
      acc = fmaf(sz[kk + 0], w[(kk + 0) * 40 + j], acc);
      acc = fmaf(sz[kk + 1], w[(kk + 1) * 40 + j], acc);
      acc = fmaf(sz[kk + 2], w[(kk + 2) * 40 + j], acc);
      acc = fmaf(sz[kk + 3], w[(kk + 3) * 40 + j], acc);
    }
  }
  part[s][j] = acc;
  __syncthreads();
  if (tid < 64) {
    float v = (j < 40) ? part[0][j] + part[1][j] + part[2][j] + part[3][j] + b[j] : -INFINITY;
    float m = v;
    for (int d = 32; d > 0; d >>= 1) m = fmaxf(m, __shfl_xor(m, d));
    float e = (j < 40) ? expf(v - m) : 0.f;
    for (int d = 32; d > 0; d >>= 1) e += __shfl_xor(e, d);
    if (j < 40) out[bb * 40 + j] = v - m - logf(e);
  }
}

extern "C" void kernel_launch(void* const* d_in, const int* in_sizes, int n_in,
                              void* d_out, int out_size, void* d_ws, size_t ws_size,
                              hipStream_t stream) {
  (void)in_sizes; (void)n_in; (void)out_size; (void)ws_size;
  const float* x    = (const float*)d_in[0];
  const int*   esrc = (const int*)d_in[1];
  const int*   edst = (const int*)d_in[2];
  const float* ev   = (const float*)d_in[3];
  const float* gc1w = (const float*)d_in[5];
  const float* gc1b = (const float*)d_in[6];
  const float* gc2w = (const float*)d_in[7];
  const float* gc2b = (const float*)d_in[8];
  const float* gc3w = (const float*)d_in[9];
  const float* gc3b = (const float*)d_in[10];
  const float* fc1w = (const float*)d_in[11];
  const float* fc1b = (const float*)d_in[12];
  const float* bn1g = (const float*)d_in[13];
  const float* bn1b = (const float*)d_in[14];
  const float* fc2w = (const float*)d_in[15];
  const float* fc2b = (const float*)d_in[16];
  const float* bn2g = (const float*)d_in[17];
  const float* bn2b = (const float*)d_in[18];
  const float* fc3w = (const float*)d_in[19];
  const float* fc3b = (const float*)d_in[20];

  char* ws = (char*)d_ws;
  size_t o = 0;
  auto alloc = [&](size_t bytes) -> void* {
    void* p = ws + o;
    o += (bytes + 255) & ~(size_t)255;
    return p;
  };
  int*   deg  = (int*)alloc((size_t)NN * 4);
  int*   off  = (int*)alloc((size_t)(NN + 1) * 4);
  int*   cur  = (int*)alloc((size_t)NN * 4);
  int2*  pack = (int2*)alloc((size_t)NE * 8);
  float* aggx = (float*)alloc((size_t)NN * 3 * 4);
  float4* x4  = (float4*)alloc((size_t)NN * 16);
  float* bufA = (float*)alloc((size_t)NN * 64 * 4);  // h1 fp32; then h2 bf16 (first half)
  float* bufB = (float*)alloc((size_t)NN * 64 * 4);  // agg2 fp32; then Ahi/Alo planes
  unsigned short* h2_16 = (unsigned short*)bufA;            // 8 MB (h1 dead by then)
  unsigned short* Ahi = (unsigned short*)bufB;              // 8 MB
  unsigned short* Alo = (unsigned short*)(bufB + NN * 32);  // 8 MB
  unsigned short* Bfrag = (unsigned short*)alloc(4 * 1024 * 32 * 2);  // 256 KB
  float* gf   = (float*)alloc(64 * 1024 * 4);
  float* z1   = (float*)alloc(64 * 512 * 4);
  float* z1n  = (float*)alloc(64 * 512 * 4);
  float* z2   = (float*)alloc(64 * 256 * 4);
  float* z2n  = (float*)alloc(64 * 256 * 4);

  hipMemsetAsync(deg, 0, (size_t)NN * 4, stream);
  hipMemsetAsync(gf, 0, 64 * 1024 * 4, stream);

  k_hist<<<NE / 256, 256, 0, stream>>>(edst, deg);
  k_scan<<<1, 1024, 0, stream>>>(deg, off, cur);
  k_scatter<<<NE / 256, 256, 0, stream>>>(esrc, edst, ev, cur, pack);
  k_prepw<<<512, 256, 0, stream>>>(gc3w, Bfrag);
  k_packx<<<NN / 256, 256, 0, stream>>>(x, x4);

  // layer 1
  k_aggx<<<NN / 256, 256, 0, stream>>>(off, pack, x4, aggx);
  k_gemm1<<<(NN * 64) / 256, 256, 0, stream>>>(aggx, gc1w, gc1b, bufA);

  // layer 2
  k_agg64<<<NN / 4, 256, 0, stream>>>(off, pack, bufA, bufB);
  k_gemm2<<<NN / 32, 256, 0, stream>>>(bufB, gc2w, gc2b, h2_16);

  // layer 3: aggregate bf16 h2 -> split-bf16 planes, then MFMA GEMM + maxpool
  k_agg64_split<<<NN / 4, 256, 0, stream>>>(off, pack, h2_16, Ahi, Alo);
  k_gemm3max<<<512, 512, 0, stream>>>(Ahi, Alo, Bfrag, gc3b, (unsigned*)gf);

  // MLP head
  k_fc<<<dim3(8, 64), 256, 0, stream>>>(gf, fc1w, fc1b, z1, 1024, 512);
  k_bn<<<8, 256, 0, stream>>>(z1, bn1g, bn1b, z1n, 512);
  k_fc<<<dim3(4, 64), 256, 0, stream>>>(z1n, fc2w, fc2b, z2, 512, 256);
  k_bn<<<4, 256, 0, stream>>>(z2, bn2g, bn2b, z2n, 256);
  k_head<<<64, 256, 0, stream>>>(z2n, fc3w, fc3b, (float*)d_out);
}

// Round 5
// 323.642 us; speedup vs baseline: 2.3846x; 1.2720x over previous
//
#include <hip/hip_runtime.h>
#include <math.h>

#define NN 65536
#define NE 1048576
#define CAP 17408  // per-bucket capacity: mean 16384, sd ~127, 8-sigma slack

typedef __attribute__((ext_vector_type(8))) short short8;
typedef __attribute__((ext_vector_type(4))) float f32x4;

__device__ inline unsigned short f2bf(float f) {
  unsigned u = __float_as_uint(f);
  unsigned r = u + 0x7fff + ((u >> 16) & 1);  // RNE
  return (unsigned short)(r >> 16);
}
__device__ inline float bf2f(unsigned short h) { return __uint_as_float(((unsigned)h) << 16); }

// ---------------- CSR build, pass 1: bin edges by shape (dst>>10) ----------------
__global__ __launch_bounds__(256) void k_bin(const int* __restrict__ src, const int* __restrict__ dst,
                                             const float* __restrict__ val, int* __restrict__ gcur,
                                             int4* __restrict__ ebin) {
  __shared__ int cnt[64], base[64];
  int tid = threadIdx.x;
  if (tid < 64) cnt[tid] = 0;
  __syncthreads();
  int e0 = blockIdx.x * 4096;
  int rsrc[16], rdst[16], rrank[16];
  float rval[16];
#pragma unroll
  for (int i = 0; i < 16; ++i) {
    int e = e0 + i * 256 + tid;
    rsrc[i] = src[e];
    rdst[i] = dst[e];
    rval[i] = val[e];
    rrank[i] = atomicAdd(&cnt[rdst[i] >> 10], 1);
  }
  __syncthreads();
  if (tid < 64) base[tid] = atomicAdd(&gcur[tid], cnt[tid]);
  __syncthreads();
#pragma unroll
  for (int i = 0; i < 16; ++i) {
    int b = rdst[i] >> 10;
    ebin[b * CAP + base[b] + rrank[i]] = make_int4(rsrc[i], rdst[i] & 1023, __float_as_int(rval[i]), 0);
  }
}

// ---------------- CSR build, pass 2: per-bucket local CSR (one block per shape) ----------------
__global__ __launch_bounds__(256) void k_csr(const int* __restrict__ gcnt, const int4* __restrict__ ebin,
                                             int* __restrict__ off, int2* __restrict__ pack) {
  __shared__ int lcnt[1024], lcur[1024], part[256];
  int b = blockIdx.x, tid = threadIdx.x;
  int count = gcnt[b];
  int gbase = 0;
  for (int i = 0; i < 64; ++i) gbase += (i < b) ? gcnt[i] : 0;
  for (int i = tid; i < 1024; i += 256) lcnt[i] = 0;
  __syncthreads();
  for (int i = tid; i < count; i += 256) atomicAdd(&lcnt[ebin[b * CAP + i].y], 1);
  __syncthreads();
  int s0 = lcnt[4 * tid], s1 = lcnt[4 * tid + 1], s2 = lcnt[4 * tid + 2], s3 = lcnt[4 * tid + 3];
  int tsum = s0 + s1 + s2 + s3;
  part[tid] = tsum;
  __syncthreads();
  for (int d = 1; d < 256; d <<= 1) {
    int v = (tid >= d) ? part[tid - d] : 0;
    __syncthreads();
    part[tid] += v;
    __syncthreads();
  }
  int tbase = part[tid] - tsum;  // exclusive
  int o0 = tbase, o1 = tbase + s0, o2 = o1 + s1, o3 = o2 + s2;
  lcur[4 * tid] = o0; lcur[4 * tid + 1] = o1; lcur[4 * tid + 2] = o2; lcur[4 * tid + 3] = o3;
  off[b * 1024 + 4 * tid] = gbase + o0;
  off[b * 1024 + 4 * tid + 1] = gbase + o1;
  off[b * 1024 + 4 * tid + 2] = gbase + o2;
  off[b * 1024 + 4 * tid + 3] = gbase + o3;
  if (b == 63 && tid == 255) off[NN] = gbase + count;
  __syncthreads();
  for (int i = tid; i < count; i += 256) {
    int4 e = ebin[b * CAP + i];
    int p = atomicAdd(&lcur[e.y], 1);
    pack[gbase + p] = make_int2(e.x, e.z);
  }
}

// ---------------- GCN layer 1 ----------------
__global__ __launch_bounds__(256) void k_packx(const float* __restrict__ x, float4* __restrict__ x4) {
  int n = blockIdx.x * 256 + threadIdx.x;
  x4[n] = make_float4(x[3 * n], x[3 * n + 1], x[3 * n + 2], 0.f);
}

__global__ __launch_bounds__(256) void k_aggx(const int* __restrict__ off, const int2* __restrict__ pack,
                                              const float4* __restrict__ x4, float* __restrict__ aggx) {
  int n = blockIdx.x * 256 + threadIdx.x;
  int i = off[n], e = off[n + 1];
  float a0 = 0.f, a1 = 0.f, a2 = 0.f;
  float b0 = 0.f, b1 = 0.f, b2 = 0.f;
  for (; i + 2 <= e; i += 2) {
    int2 e0 = pack[i], e1 = pack[i + 1];
    float v0 = __int_as_float(e0.y), v1 = __int_as_float(e1.y);
    float4 q0 = x4[e0.x];
    float4 q1 = x4[e1.x];
    a0 = fmaf(v0, q0.x, a0);
    a1 = fmaf(v0, q0.y, a1);
    a2 = fmaf(v0, q0.z, a2);
    b0 = fmaf(v1, q1.x, b0);
    b1 = fmaf(v1, q1.y, b1);
    b2 = fmaf(v1, q1.z, b2);
  }
  if (i < e) {
    int2 e0 = pack[i];
    float v0 = __int_as_float(e0.y);
    float4 q0 = x4[e0.x];
    a0 = fmaf(v0, q0.x, a0);
    a1 = fmaf(v0, q0.y, a1);
    a2 = fmaf(v0, q0.z, a2);
  }
  aggx[n * 3 + 0] = a0 + b0;
  aggx[n * 3 + 1] = a1 + b1;
  aggx[n * 3 + 2] = a2 + b2;
}

__global__ __launch_bounds__(256) void k_gemm1(const float* __restrict__ aggx, const float* __restrict__ w,
                                               const float* __restrict__ b, unsigned short* __restrict__ out) {
  __shared__ float sw[256];
  int t = threadIdx.x;
  sw[t] = (t < 192) ? w[t] : b[t - 192];
  __syncthreads();
  int g = blockIdx.x * 256 + t;
  int n = g >> 6, j = g & 63;
  float a0 = aggx[n * 3], a1 = aggx[n * 3 + 1], a2 = aggx[n * 3 + 2];
  float r = sw[192 + j];
  r = fmaf(a0, sw[j], r);
  r = fmaf(a1, sw[64 + j], r);
  r = fmaf(a2, sw[128 + j], r);
  out[g] = f2bf(fmaxf(r, 0.f));
}

// ---------------- 64-feature aggregation from bf16 h, fp32 out, 4-way edge ILP ----------------
__global__ __launch_bounds__(256) void k_agg64(const int* __restrict__ off, const int2* __restrict__ pack,
                                               const unsigned short* __restrict__ h, float* __restrict__ out) {
  int lane = threadIdx.x & 63;
  int n = blockIdx.x * 4 + (threadIdx.x >> 6);
  int i = off[n], e = off[n + 1];
  float a0 = 0.f, a1 = 0.f, a2 = 0.f, a3 = 0.f;
  for (; i + 4 <= e; i += 4) {
    int2 e0 = pack[i], e1 = pack[i + 1], e2 = pack[i + 2], e3 = pack[i + 3];
    a0 = fmaf(__int_as_float(e0.y), bf2f(h[(size_t)e0.x * 64 + lane]), a0);
    a1 = fmaf(__int_as_float(e1.y), bf2f(h[(size_t)e1.x * 64 + lane]), a1);
    a2 = fmaf(__int_as_float(e2.y), bf2f(h[(size_t)e2.x * 64 + lane]), a2);
    a3 = fmaf(__int_as_float(e3.y), bf2f(h[(size_t)e3.x * 64 + lane]), a3);
  }
  for (; i < e; ++i) {
    int2 ed = pack[i];
    a0 = fmaf(__int_as_float(ed.y), bf2f(h[(size_t)ed.x * 64 + lane]), a0);
  }
  out[(size_t)n * 64 + lane] = (a0 + a1) + (a2 + a3);
}

// 64-feature aggregation from bf16 h, emitting split-bf16 planes for the MFMA GEMM
__global__ __launch_bounds__(256) void k_agg64_split(const int* __restrict__ off, const int2* __restrict__ pack,
                                                     const unsigned short* __restrict__ h,
                                                     unsigned short* __restrict__ hi,
                                                     unsigned short* __restrict__ lo) {
  int lane = threadIdx.x & 63;
  int n = blockIdx.x * 4 + (threadIdx.x >> 6);
  int i = off[n], e = off[n + 1];
  float a0 = 0.f, a1 = 0.f, a2 = 0.f, a3 = 0.f;
  for (; i + 4 <= e; i += 4) {
    int2 e0 = pack[i], e1 = pack[i + 1], e2 = pack[i + 2], e3 = pack[i + 3];
    a0 = fmaf(__int_as_float(e0.y), bf2f(h[(size_t)e0.x * 64 + lane]), a0);
    a1 = fmaf(__int_as_float(e1.y), bf2f(h[(size_t)e1.x * 64 + lane]), a1);
    a2 = fmaf(__int_as_float(e2.y), bf2f(h[(size_t)e2.x * 64 + lane]), a2);
    a3 = fmaf(__int_as_float(e3.y), bf2f(h[(size_t)e3.x * 64 + lane]), a3);
  }
  for (; i < e; ++i) {
    int2 ed = pack[i];
    a0 = fmaf(__int_as_float(ed.y), bf2f(h[(size_t)ed.x * 64 + lane]), a0);
  }
  float acc = (a0 + a1) + (a2 + a3);
  unsigned short h16 = f2bf(acc);
  unsigned short l16 = f2bf(acc - bf2f(h16));
  size_t idx = (size_t)n * 64 + lane;
  hi[idx] = h16;
  lo[idx] = l16;
}

// ---------------- GCN layer 2 GEMM: fp32 in, bf16 out ----------------
__global__ __launch_bounds__(256) void k_gemm2(const float* __restrict__ agg, const float* __restrict__ w2,
                                               const float* __restrict__ b2, unsigned short* __restrict__ out) {
  int lane = threadIdx.x & 63, wv = threadIdx.x >> 6;
  float w[64];
#pragma unroll
  for (int k = 0; k < 64; ++k) w[k] = w2[k * 64 + lane];
  float bb = b2[lane];
  int n0 = blockIdx.x * 32 + wv * 8;
  for (int t = 0; t < 8; ++t) {
    int n = n0 + t;
    const float4* row = (const float4*)&agg[(size_t)n * 64];
    float acc = bb;
#pragma unroll
    for (int kk = 0; kk < 16; ++kk) {
      float4 q = row[kk];
      acc = fmaf(q.x, w[4 * kk + 0], acc);
      acc = fmaf(q.y, w[4 * kk + 1], acc);
      acc = fmaf(q.z, w[4 * kk + 2], acc);
      acc = fmaf(q.w, w[4 * kk + 3], acc);
    }
    out[(size_t)n * 64 + lane] = f2bf(fmaxf(acc, 0.f));
  }
}

// ---------------- W3 prep: split-bf16, MFMA-fragment order ----------------
__global__ __launch_bounds__(256) void k_prepw(const float* __restrict__ w3, unsigned short* __restrict__ bfrag) {
  int t = blockIdx.x * 256 + threadIdx.x;  // 131072 total
  int e = t & 7, g = (t >> 3) & 3, col = (t >> 5) & 1023, q = t >> 15;
  int k = (q & 1) * 32 + g * 8 + e;
  float v = w3[k * 1024 + col];
  unsigned short hv = f2bf(v);
  bfrag[t] = (q < 2) ? hv : f2bf(v - bf2f(hv));
}

// ---------------- GCN layer 3 GEMM + maxpool via MFMA (split-bf16) ----------------
__global__ __launch_bounds__(512) void k_gemm3max(const unsigned short* __restrict__ Ahi,
                                                  const unsigned short* __restrict__ Alo,
                                                  const unsigned short* __restrict__ Bfrag,
                                                  const float* __restrict__ b3,
                                                  unsigned* __restrict__ gf) {
  int b = blockIdx.x;
  int colhalf = b & 1, rowchunk = b >> 1;  // rowchunk 0..255 (256 rows each)
  int shape = rowchunk >> 2;
  int tid = threadIdx.x;
  int wv = tid >> 6, l = tid & 63;
  int g = l >> 4, lr = l & 15;

  const short8* bf = (const short8*)Bfrag;
  int c0 = colhalf * 512 + wv * 64 + lr;
  short8 B0[4], B1[4], B2[4], B3[4];
#pragma unroll
  for (int ct = 0; ct < 4; ++ct) {
    int col = c0 + ct * 16;
    B0[ct] = bf[(0 * 1024 + col) * 4 + g];
    B1[ct] = bf[(1 * 1024 + col) * 4 + g];
    B2[ct] = bf[(2 * 1024 + col) * 4 + g];
    B3[ct] = bf[(3 * 1024 + col) * 4 + g];
  }

  float m[4] = {-1e30f, -1e30f, -1e30f, -1e30f};
  size_t abase = ((size_t)rowchunk * 256 + lr) * 64 + g * 8;
  for (int t = 0; t < 16; ++t) {
    size_t o = abase + (size_t)t * 16 * 64;
    short8 ah0 = *(const short8*)(Ahi + o);
    short8 ah1 = *(const short8*)(Ahi + o + 32);
    short8 al0 = *(const short8*)(Alo + o);
    short8 al1 = *(const short8*)(Alo + o + 32);
#pragma unroll
    for (int ct = 0; ct < 4; ++ct) {
      f32x4 acc = {0.f, 0.f, 0.f, 0.f};
      acc = __builtin_amdgcn_mfma_f32_16x16x32_bf16(ah0, B0[ct], acc, 0, 0, 0);
      acc = __builtin_amdgcn_mfma_f32_16x16x32_bf16(ah1, B1[ct], acc, 0, 0, 0);
      acc = __builtin_amdgcn_mfma_f32_16x16x32_bf16(ah0, B2[ct], acc, 0, 0, 0);
      acc = __builtin_amdgcn_mfma_f32_16x16x32_bf16(ah1, B3[ct], acc, 0, 0, 0);
      acc = __builtin_amdgcn_mfma_f32_16x16x32_bf16(al0, B0[ct], acc, 0, 0, 0);
      acc = __builtin_amdgcn_mfma_f32_16x16x32_bf16(al1, B1[ct], acc, 0, 0, 0);
      m[ct] = fmaxf(m[ct], fmaxf(fmaxf(acc[0], acc[1]), fmaxf(acc[2], acc[3])));
    }
  }
#pragma unroll
  for (int ct = 0; ct < 4; ++ct) {
    float mm = m[ct];
    mm = fmaxf(mm, __shfl_xor(mm, 16));
    mm = fmaxf(mm, __shfl_xor(mm, 32));
    if (g == 0) {
      int col = c0 + ct * 16;
      float v = fmaxf(mm + b3[col], 0.f);
      atomicMax(&gf[shape * 1024 + col], __float_as_uint(v));
    }
  }
}

// ---------------- MLP head ----------------
__global__ __launch_bounds__(256) void k_fc(const float* __restrict__ in, const float* __restrict__ w,
                                            const float* __restrict__ bias, float* __restrict__ out,
                                            int K, int J) {
  __shared__ float sin_[1024];
  __shared__ float part[4][64];
  int jt = blockIdx.x, bb = blockIdx.y;
  int tid = threadIdx.x, s = tid >> 6, lane = tid & 63;
  for (int i = tid; i < K; i += 256) sin_[i] = in[bb * K + i];
  __syncthreads();
  int j = (jt << 6) + lane;
  int Kq = K >> 2;
  int k0 = s * Kq;
  float a0 = 0.f, a1 = 0.f, a2 = 0.f, a3 = 0.f;
  for (int k = 0; k < Kq; k += 4) {
    int kk = k0 + k;
    a0 = fmaf(sin_[kk + 0], w[(kk + 0) * J + j], a0);
    a1 = fmaf(sin_[kk + 1], w[(kk + 1) * J + j], a1);
    a2 = fmaf(sin_[kk + 2], w[(kk + 2) * J + j], a2);
    a3 = fmaf(sin_[kk + 3], w[(kk + 3) * J + j], a3);
  }
  part[s][lane] = (a0 + a1) + (a2 + a3);
  __syncthreads();
  if (tid < 64)
    out[bb * J + (jt << 6) + tid] =
        part[0][tid] + part[1][tid] + part[2][tid] + part[3][tid] + bias[(jt << 6) + tid];
}

__global__ __launch_bounds__(256) void k_bn(const float* __restrict__ z, const float* __restrict__ g,
                                            const float* __restrict__ bt, float* __restrict__ out, int J) {
  __shared__ float tile[64][64];
  __shared__ float red[4][64];
  __shared__ float sc[64], sh[64];
  int tid = threadIdx.x, s = tid >> 6, lane = tid & 63;
  int j0 = blockIdx.x << 6;
  float psum = 0.f;
#pragma unroll
  for (int r = 0; r < 16; ++r) {
    int row = s * 16 + r;
    float v = z[row * J + j0 + lane];
    tile[row][lane] = v;
    psum += v;
  }
  red[s][lane] = psum;
  __syncthreads();
  if (tid < 64) sc[tid] = (red[0][tid] + red[1][tid] + red[2][tid] + red[3][tid]) * (1.f / 64.f);
  __syncthreads();
  float mean = sc[lane];
  float pv = 0.f;
#pragma unroll
  for (int r = 0; r < 16; ++r) {
    float d = tile[s * 16 + r][lane] - mean;
    pv = fmaf(d, d, pv);
  }
  red[s][lane] = pv;
  __syncthreads();
  if (tid < 64) {
    float var = (red[0][tid] + red[1][tid] + red[2][tid] + red[3][tid]) * (1.f / 64.f);
    float scale = g[j0 + tid] / sqrtf(var + 1e-5f);
    sh[tid] = bt[j0 + tid] - sc[tid] * scale;
    sc[tid] = scale;
  }
  __syncthreads();
  float scale = sc[lane], shift = sh[lane];
#pragma unroll
  for (int r = 0; r < 16; ++r) {
    int row = s * 16 + r;
    out[row * J + j0 + lane] = fmaxf(fmaf(tile[row][lane], scale, shift), 0.f);
  }
}

__global__ __launch_bounds__(256) void k_head(const float* __restrict__ z, const float* __restrict__ w,
                                              const float* __restrict__ b, float* __restrict__ out) {
  __shared__ float sz[256];
  __shared__ float part[4][64];
  int bb = blockIdx.x, tid = threadIdx.x;
  sz[tid] = z[bb * 256 + tid];
  __syncthreads();
  int s = tid >> 6, j = tid & 63;
  float acc = 0.f;
  if (j < 40) {
#pragma unroll
    for (int k = 0; k < 64; k += 4) {
      int kk = s * 64 + k;
      acc = fmaf(sz[kk + 0], w[(kk + 0) * 40 + j], acc);
      acc = fmaf(sz[kk + 1], w[(kk + 1) * 40 + j], acc);
      acc = fmaf(sz[kk + 2], w[(kk + 2) * 40 + j], acc);
      acc = fmaf(sz[kk + 3], w[(kk + 3) * 40 + j], acc);
    }
  }
  part[s][j] = acc;
  __syncthreads();
  if (tid < 64) {
    float v = (j < 40) ? part[0][j] + part[1][j] + part[2][j] + part[3][j] + b[j] : -INFINITY;
    float m = v;
    for (int d = 32; d > 0; d >>= 1) m = fmaxf(m, __shfl_xor(m, d));
    float e = (j < 40) ? expf(v - m) : 0.f;
    for (int d = 32; d > 0; d >>= 1) e += __shfl_xor(e, d);
    if (j < 40) out[bb * 40 + j] = v - m - logf(e);
  }
}

extern "C" void kernel_launch(void* const* d_in, const int* in_sizes, int n_in,
                              void* d_out, int out_size, void* d_ws, size_t ws_size,
                              hipStream_t stream) {
  (void)in_sizes; (void)n_in; (void)out_size; (void)ws_size;
  const float* x    = (const float*)d_in[0];
  const int*   esrc = (const int*)d_in[1];
  const int*   edst = (const int*)d_in[2];
  const float* ev   = (const float*)d_in[3];
  const float* gc1w = (const float*)d_in[5];
  const float* gc1b = (const float*)d_in[6];
  const float* gc2w = (const float*)d_in[7];
  const float* gc2b = (const float*)d_in[8];
  const float* gc3w = (const float*)d_in[9];
  const float* gc3b = (const float*)d_in[10];
  const float* fc1w = (const float*)d_in[11];
  const float* fc1b = (const float*)d_in[12];
  const float* bn1g = (const float*)d_in[13];
  const float* bn1b = (const float*)d_in[14];
  const float* fc2w = (const float*)d_in[15];
  const float* fc2b = (const float*)d_in[16];
  const float* bn2g = (const float*)d_in[17];
  const float* bn2b = (const float*)d_in[18];
  const float* fc3w = (const float*)d_in[19];
  const float* fc3b = (const float*)d_in[20];

  char* ws = (char*)d_ws;
  size_t o = 0;
  auto alloc = [&](size_t bytes) -> void* {
    void* p = ws + o;
    o += (bytes + 255) & ~(size_t)255;
    return p;
  };
  int*   off  = (int*)alloc((size_t)(NN + 1) * 4);
  int*   gcur = (int*)alloc(64 * 4);
  int2*  pack = (int2*)alloc((size_t)NE * 8);
  float* aggx = (float*)alloc((size_t)NN * 3 * 4);
  float4* x4  = (float4*)alloc((size_t)NN * 16);
  float* bufA = (float*)alloc((size_t)NN * 64 * 4);  // ebin head; h1/h2 bf16
  float* bufB = (float*)alloc((size_t)NN * 64 * 4);  // ebin tail; agg2 f32; Ahi/Alo
  int4*  ebin = (int4*)bufA;                         // 64*CAP*16 = 17.8 MB, dead before gemm1
  unsigned short* h1_16 = (unsigned short*)bufA;            // 8 MB
  unsigned short* h2_16 = (unsigned short*)bufA;            // 8 MB (h1 dead by then)
  unsigned short* Ahi = (unsigned short*)bufB;              // 8 MB
  unsigned short* Alo = (unsigned short*)(bufB + NN * 32);  // 8 MB
  unsigned short* Bfrag = (unsigned short*)alloc(4 * 1024 * 32 * 2);  // 256 KB
  float* gf   = (float*)alloc(64 * 1024 * 4);
  float* z1   = (float*)alloc(64 * 512 * 4);
  float* z1n  = (float*)alloc(64 * 512 * 4);
  float* z2   = (float*)alloc(64 * 256 * 4);
  float* z2n  = (float*)alloc(64 * 256 * 4);

  hipMemsetAsync(gcur, 0, 64 * 4, stream);
  hipMemsetAsync(gf, 0, 64 * 1024 * 4, stream);

  // CSR build: 2-pass shape-bucketed (no global-scatter line fragmentation)
  k_bin<<<NE / 4096, 256, 0, stream>>>(esrc, edst, ev, gcur, ebin);
  k_csr<<<64, 256, 0, stream>>>(gcur, ebin, off, pack);
  k_prepw<<<512, 256, 0, stream>>>(gc3w, Bfrag);
  k_packx<<<NN / 256, 256, 0, stream>>>(x, x4);

  // layer 1
  k_aggx<<<NN / 256, 256, 0, stream>>>(off, pack, x4, aggx);
  k_gemm1<<<(NN * 64) / 256, 256, 0, stream>>>(aggx, gc1w, gc1b, h1_16);

  // layer 2
  k_agg64<<<NN / 4, 256, 0, stream>>>(off, pack, h1_16, bufB);
  k_gemm2<<<NN / 32, 256, 0, stream>>>(bufB, gc2w, gc2b, h2_16);

  // layer 3: aggregate bf16 h2 -> split-bf16 planes, then MFMA GEMM + maxpool
  k_agg64_split<<<NN / 4, 256, 0, stream>>>(off, pack, h2_16, Ahi, Alo);
  k_gemm3max<<<512, 512, 0, stream>>>(Ahi, Alo, Bfrag, gc3b, (unsigned*)gf);

  // MLP head
  k_fc<<<dim3(8, 64), 256, 0, stream>>>(gf, fc1w, fc1b, z1, 1024, 512);
  k_bn<<<8, 256, 0, stream>>>(z1, bn1g, bn1b, z1n, 512);
  k_fc<<<dim3(4, 64), 256, 0, stream>>>(z1n, fc2w, fc2b, z2, 512, 256);
  k_bn<<<4, 256, 0, stream>>>(z2, bn2g, bn2b, z2n, 256);
  k_head<<<64, 256, 0, stream>>>(z2n, fc3w, fc3b, (float*)d_out);
}

// Round 6
// 283.519 us; speedup vs baseline: 2.7220x; 1.1415x over previous
//
#include <hip/hip_runtime.h>
#include <math.h>

#define NN 65536
#define NE 1048576
#define CAP 17408  // per-bucket capacity: mean 16384, sd ~127, 8-sigma slack

typedef __attribute__((ext_vector_type(8))) short short8;
typedef __attribute__((ext_vector_type(4))) float f32x4;

__device__ inline unsigned short f2bf(float f) {
  unsigned u = __float_as_uint(f);
  unsigned r = u + 0x7fff + ((u >> 16) & 1);  // RNE
  return (unsigned short)(r >> 16);
}
__device__ inline float bf2f(unsigned short h) { return __uint_as_float(((unsigned)h) << 16); }

// ---------------- CSR build, pass 1: bin edges by shape (dst>>10) ----------------
__global__ __launch_bounds__(256) void k_bin(const int* __restrict__ src, const int* __restrict__ dst,
                                             const float* __restrict__ val, int* __restrict__ gcur,
                                             int4* __restrict__ ebin) {
  __shared__ int cnt[64], base[64];
  int tid = threadIdx.x;
  if (tid < 64) cnt[tid] = 0;
  __syncthreads();
  int e0 = blockIdx.x * 4096;
  int rsrc[16], rdst[16], rrank[16];
  float rval[16];
#pragma unroll
  for (int i = 0; i < 16; ++i) {
    int e = e0 + i * 256 + tid;
    rsrc[i] = src[e];
    rdst[i] = dst[e];
    rval[i] = val[e];
    rrank[i] = atomicAdd(&cnt[rdst[i] >> 10], 1);
  }
  __syncthreads();
  if (tid < 64) base[tid] = atomicAdd(&gcur[tid], cnt[tid]);
  __syncthreads();
#pragma unroll
  for (int i = 0; i < 16; ++i) {
    int b = rdst[i] >> 10;
    ebin[b * CAP + base[b] + rrank[i]] = make_int4(rsrc[i], rdst[i] & 1023, __float_as_int(rval[i]), 0);
  }
}

// ---------------- CSR build, pass 2: per-bucket local CSR (one block per shape) ----------------
__global__ __launch_bounds__(256) void k_csr(const int* __restrict__ gcnt, const int4* __restrict__ ebin,
                                             int* __restrict__ off, int2* __restrict__ pack) {
  __shared__ int lcnt[1024], lcur[1024], part[256];
  int b = blockIdx.x, tid = threadIdx.x;
  int count = gcnt[b];
  int gbase = 0;
  for (int i = 0; i < 64; ++i) gbase += (i < b) ? gcnt[i] : 0;
  for (int i = tid; i < 1024; i += 256) lcnt[i] = 0;
  __syncthreads();
  for (int i = tid; i < count; i += 256) atomicAdd(&lcnt[ebin[b * CAP + i].y], 1);
  __syncthreads();
  int s0 = lcnt[4 * tid], s1 = lcnt[4 * tid + 1], s2 = lcnt[4 * tid + 2], s3 = lcnt[4 * tid + 3];
  int tsum = s0 + s1 + s2 + s3;
  part[tid] = tsum;
  __syncthreads();
  for (int d = 1; d < 256; d <<= 1) {
    int v = (tid >= d) ? part[tid - d] : 0;
    __syncthreads();
    part[tid] += v;
    __syncthreads();
  }
  int tbase = part[tid] - tsum;  // exclusive
  int o0 = tbase, o1 = tbase + s0, o2 = o1 + s1, o3 = o2 + s2;
  lcur[4 * tid] = o0; lcur[4 * tid + 1] = o1; lcur[4 * tid + 2] = o2; lcur[4 * tid + 3] = o3;
  off[b * 1024 + 4 * tid] = gbase + o0;
  off[b * 1024 + 4 * tid + 1] = gbase + o1;
  off[b * 1024 + 4 * tid + 2] = gbase + o2;
  off[b * 1024 + 4 * tid + 3] = gbase + o3;
  if (b == 63 && tid == 255) off[NN] = gbase + count;
  __syncthreads();
  for (int i = tid; i < count; i += 256) {
    int4 e = ebin[b * CAP + i];
    int p = atomicAdd(&lcur[e.y], 1);
    pack[gbase + p] = make_int2(e.x, e.z);
  }
}

// ---------------- GCN layer 1 ----------------
__global__ __launch_bounds__(256) void k_packx(const float* __restrict__ x, float4* __restrict__ x4) {
  int n = blockIdx.x * 256 + threadIdx.x;
  x4[n] = make_float4(x[3 * n], x[3 * n + 1], x[3 * n + 2], 0.f);
}

__global__ __launch_bounds__(256) void k_aggx(const int* __restrict__ off, const int2* __restrict__ pack,
                                              const float4* __restrict__ x4, float* __restrict__ aggx) {
  int n = blockIdx.x * 256 + threadIdx.x;
  int i = off[n], e = off[n + 1];
  float a0 = 0.f, a1 = 0.f, a2 = 0.f;
  float b0 = 0.f, b1 = 0.f, b2 = 0.f;
  for (; i + 2 <= e; i += 2) {
    int2 e0 = pack[i], e1 = pack[i + 1];
    float v0 = __int_as_float(e0.y), v1 = __int_as_float(e1.y);
    float4 q0 = x4[e0.x];
    float4 q1 = x4[e1.x];
    a0 = fmaf(v0, q0.x, a0);
    a1 = fmaf(v0, q0.y, a1);
    a2 = fmaf(v0, q0.z, a2);
    b0 = fmaf(v1, q1.x, b0);
    b1 = fmaf(v1, q1.y, b1);
    b2 = fmaf(v1, q1.z, b2);
  }
  if (i < e) {
    int2 e0 = pack[i];
    float v0 = __int_as_float(e0.y);
    float4 q0 = x4[e0.x];
    a0 = fmaf(v0, q0.x, a0);
    a1 = fmaf(v0, q0.y, a1);
    a2 = fmaf(v0, q0.z, a2);
  }
  aggx[n * 3 + 0] = a0 + b0;
  aggx[n * 3 + 1] = a1 + b1;
  aggx[n * 3 + 2] = a2 + b2;
}

__global__ __launch_bounds__(256) void k_gemm1(const float* __restrict__ aggx, const float* __restrict__ w,
                                               const float* __restrict__ b, unsigned short* __restrict__ out) {
  __shared__ float sw[256];
  int t = threadIdx.x;
  sw[t] = (t < 192) ? w[t] : b[t - 192];
  __syncthreads();
  int g = blockIdx.x * 256 + t;
  int n = g >> 6, j = g & 63;
  float a0 = aggx[n * 3], a1 = aggx[n * 3 + 1], a2 = aggx[n * 3 + 2];
  float r = sw[192 + j];
  r = fmaf(a0, sw[j], r);
  r = fmaf(a1, sw[64 + j], r);
  r = fmaf(a2, sw[128 + j], r);
  out[g] = f2bf(fmaxf(r, 0.f));
}

// ---------------- fused layer-2: agg(h1) -> @W2+b2, relu -> h2 bf16 ----------------
// wave per node; lane = feature. After the gather-reduce, the row bounces through
// 256B of LDS (same-wave write -> broadcast read) and multiplies reg-resident W2.
__global__ __launch_bounds__(256) void k_agg64g2(const int* __restrict__ off, const int2* __restrict__ pack,
                                                 const unsigned short* __restrict__ h,
                                                 const float* __restrict__ w2, const float* __restrict__ b2,
                                                 unsigned short* __restrict__ out) {
  __shared__ float rows[4][64];
  int lane = threadIdx.x & 63, wv = threadIdx.x >> 6;
  float w[64];
#pragma unroll
  for (int k = 0; k < 64; ++k) w[k] = w2[k * 64 + lane];
  float bb = b2[lane];
  int n = blockIdx.x * 4 + wv;
  int i = off[n], e = off[n + 1];
  float a0 = 0.f, a1 = 0.f, a2 = 0.f, a3 = 0.f;
  for (; i + 4 <= e; i += 4) {
    int2 e0 = pack[i], e1 = pack[i + 1], e2 = pack[i + 2], e3 = pack[i + 3];
    a0 = fmaf(__int_as_float(e0.y), bf2f(h[(size_t)e0.x * 64 + lane]), a0);
    a1 = fmaf(__int_as_float(e1.y), bf2f(h[(size_t)e1.x * 64 + lane]), a1);
    a2 = fmaf(__int_as_float(e2.y), bf2f(h[(size_t)e2.x * 64 + lane]), a2);
    a3 = fmaf(__int_as_float(e3.y), bf2f(h[(size_t)e3.x * 64 + lane]), a3);
  }
  for (; i < e; ++i) {
    int2 ed = pack[i];
    a0 = fmaf(__int_as_float(ed.y), bf2f(h[(size_t)ed.x * 64 + lane]), a0);
  }
  rows[wv][lane] = (a0 + a1) + (a2 + a3);
  // same-wave LDS write->read: compiler orders via lgkmcnt on the dependence
  float acc = bb;
  const float4* rv = (const float4*)rows[wv];
#pragma unroll
  for (int kk = 0; kk < 16; ++kk) {
    float4 q = rv[kk];  // broadcast
    acc = fmaf(q.x, w[4 * kk + 0], acc);
    acc = fmaf(q.y, w[4 * kk + 1], acc);
    acc = fmaf(q.z, w[4 * kk + 2], acc);
    acc = fmaf(q.w, w[4 * kk + 3], acc);
  }
  out[(size_t)n * 64 + lane] = f2bf(fmaxf(acc, 0.f));
}

// 64-feature aggregation from bf16 h, emitting split-bf16 planes for the MFMA GEMM
__global__ __launch_bounds__(256) void k_agg64_split(const int* __restrict__ off, const int2* __restrict__ pack,
                                                     const unsigned short* __restrict__ h,
                                                     unsigned short* __restrict__ hi,
                                                     unsigned short* __restrict__ lo) {
  int lane = threadIdx.x & 63;
  int n = blockIdx.x * 4 + (threadIdx.x >> 6);
  int i = off[n], e = off[n + 1];
  float a0 = 0.f, a1 = 0.f, a2 = 0.f, a3 = 0.f;
  for (; i + 4 <= e; i += 4) {
    int2 e0 = pack[i], e1 = pack[i + 1], e2 = pack[i + 2], e3 = pack[i + 3];
    a0 = fmaf(__int_as_float(e0.y), bf2f(h[(size_t)e0.x * 64 + lane]), a0);
    a1 = fmaf(__int_as_float(e1.y), bf2f(h[(size_t)e1.x * 64 + lane]), a1);
    a2 = fmaf(__int_as_float(e2.y), bf2f(h[(size_t)e2.x * 64 + lane]), a2);
    a3 = fmaf(__int_as_float(e3.y), bf2f(h[(size_t)e3.x * 64 + lane]), a3);
  }
  for (; i < e; ++i) {
    int2 ed = pack[i];
    a0 = fmaf(__int_as_float(ed.y), bf2f(h[(size_t)ed.x * 64 + lane]), a0);
  }
  float acc = (a0 + a1) + (a2 + a3);
  unsigned short h16 = f2bf(acc);
  unsigned short l16 = f2bf(acc - bf2f(h16));
  size_t idx = (size_t)n * 64 + lane;
  hi[idx] = h16;
  lo[idx] = l16;
}

// ---------------- W3 prep: split-bf16, MFMA-fragment order ----------------
__global__ __launch_bounds__(256) void k_prepw(const float* __restrict__ w3, unsigned short* __restrict__ bfrag) {
  int t = blockIdx.x * 256 + threadIdx.x;  // 131072 total
  int e = t & 7, g = (t >> 3) & 3, col = (t >> 5) & 1023, q = t >> 15;
  int k = (q & 1) * 32 + g * 8 + e;
  float v = w3[k * 1024 + col];
  unsigned short hv = f2bf(v);
  bfrag[t] = (q < 2) ? hv : f2bf(v - bf2f(hv));
}

// ---------------- GCN layer 3 GEMM + maxpool via MFMA (split-bf16) ----------------
__global__ __launch_bounds__(512) void k_gemm3max(const unsigned short* __restrict__ Ahi,
                                                  const unsigned short* __restrict__ Alo,
                                                  const unsigned short* __restrict__ Bfrag,
                                                  const float* __restrict__ b3,
                                                  unsigned* __restrict__ gf) {
  int b = blockIdx.x;
  int colhalf = b & 1, rowchunk = b >> 1;  // rowchunk 0..255 (256 rows each)
  int shape = rowchunk >> 2;
  int tid = threadIdx.x;
  int wv = tid >> 6, l = tid & 63;
  int g = l >> 4, lr = l & 15;

  const short8* bf = (const short8*)Bfrag;
  int c0 = colhalf * 512 + wv * 64 + lr;
  short8 B0[4], B1[4], B2[4], B3[4];
#pragma unroll
  for (int ct = 0; ct < 4; ++ct) {
    int col = c0 + ct * 16;
    B0[ct] = bf[(0 * 1024 + col) * 4 + g];
    B1[ct] = bf[(1 * 1024 + col) * 4 + g];
    B2[ct] = bf[(2 * 1024 + col) * 4 + g];
    B3[ct] = bf[(3 * 1024 + col) * 4 + g];
  }

  float m[4] = {-1e30f, -1e30f, -1e30f, -1e30f};
  size_t abase = ((size_t)rowchunk * 256 + lr) * 64 + g * 8;
  for (int t = 0; t < 16; ++t) {
    size_t o = abase + (size_t)t * 16 * 64;
    short8 ah0 = *(const short8*)(Ahi + o);
    short8 ah1 = *(const short8*)(Ahi + o + 32);
    short8 al0 = *(const short8*)(Alo + o);
    short8 al1 = *(const short8*)(Alo + o + 32);
#pragma unroll
    for (int ct = 0; ct < 4; ++ct) {
      f32x4 acc = {0.f, 0.f, 0.f, 0.f};
      acc = __builtin_amdgcn_mfma_f32_16x16x32_bf16(ah0, B0[ct], acc, 0, 0, 0);
      acc = __builtin_amdgcn_mfma_f32_16x16x32_bf16(ah1, B1[ct], acc, 0, 0, 0);
      acc = __builtin_amdgcn_mfma_f32_16x16x32_bf16(ah0, B2[ct], acc, 0, 0, 0);
      acc = __builtin_amdgcn_mfma_f32_16x16x32_bf16(ah1, B3[ct], acc, 0, 0, 0);
      acc = __builtin_amdgcn_mfma_f32_16x16x32_bf16(al0, B0[ct], acc, 0, 0, 0);
      acc = __builtin_amdgcn_mfma_f32_16x16x32_bf16(al1, B1[ct], acc, 0, 0, 0);
      m[ct] = fmaxf(m[ct], fmaxf(fmaxf(acc[0], acc[1]), fmaxf(acc[2], acc[3])));
    }
  }
#pragma unroll
  for (int ct = 0; ct < 4; ++ct) {
    float mm = m[ct];
    mm = fmaxf(mm, __shfl_xor(mm, 16));
    mm = fmaxf(mm, __shfl_xor(mm, 32));
    if (g == 0) {
      int col = c0 + ct * 16;
      float v = fmaxf(mm + b3[col], 0.f);
      atomicMax(&gf[shape * 1024 + col], __float_as_uint(v));
    }
  }
}

// ---------------- MLP head ----------------
// grid (J/64, 64): 512 thr = 8 waves; wave s covers K/8; 16-deep load bursts.
__global__ __launch_bounds__(512) void k_fc(const float* __restrict__ in, const float* __restrict__ w,
                                            const float* __restrict__ bias, float* __restrict__ out,
                                            int K, int J) {
  __shared__ float sin_[1024];
  __shared__ float part[8][64];
  int jt = blockIdx.x, bb = blockIdx.y;
  int tid = threadIdx.x, s = tid >> 6, lane = tid & 63;
  for (int i = tid; i < K; i += 512) sin_[i] = in[bb * K + i];
  __syncthreads();
  int j = (jt << 6) + lane;
  int Ks = K >> 3;
  int k0 = s * Ks;
  float acc = 0.f;
  for (int k = 0; k < Ks; k += 16) {
    float wv[16];
#pragma unroll
    for (int u = 0; u < 16; ++u) wv[u] = w[(k0 + k + u) * J + j];
#pragma unroll
    for (int u = 0; u < 16; ++u) acc = fmaf(sin_[k0 + k + u], wv[u], acc);
  }
  part[s][lane] = acc;
  __syncthreads();
  if (tid < 64) {
    float r = bias[(jt << 6) + tid];
#pragma unroll
    for (int u = 0; u < 8; ++u) r += part[u][tid];
    out[bb * J + (jt << 6) + tid] = r;
  }
}

__global__ __launch_bounds__(256) void k_bn(const float* __restrict__ z, const float* __restrict__ g,
                                            const float* __restrict__ bt, float* __restrict__ out, int J) {
  __shared__ float tile[64][64];
  __shared__ float red[4][64];
  __shared__ float sc[64], sh[64];
  int tid = threadIdx.x, s = tid >> 6, lane = tid & 63;
  int j0 = blockIdx.x << 6;
  float psum = 0.f;
#pragma unroll
  for (int r = 0; r < 16; ++r) {
    int row = s * 16 + r;
    float v = z[row * J + j0 + lane];
    tile[row][lane] = v;
    psum += v;
  }
  red[s][lane] = psum;
  __syncthreads();
  if (tid < 64) sc[tid] = (red[0][tid] + red[1][tid] + red[2][tid] + red[3][tid]) * (1.f / 64.f);
  __syncthreads();
  float mean = sc[lane];
  float pv = 0.f;
#pragma unroll
  for (int r = 0; r < 16; ++r) {
    float d = tile[s * 16 + r][lane] - mean;
    pv = fmaf(d, d, pv);
  }
  red[s][lane] = pv;
  __syncthreads();
  if (tid < 64) {
    float var = (red[0][tid] + red[1][tid] + red[2][tid] + red[3][tid]) * (1.f / 64.f);
    float scale = g[j0 + tid] / sqrtf(var + 1e-5f);
    sh[tid] = bt[j0 + tid] - sc[tid] * scale;
    sc[tid] = scale;
  }
  __syncthreads();
  float scale = sc[lane], shift = sh[lane];
#pragma unroll
  for (int r = 0; r < 16; ++r) {
    int row = s * 16 + r;
    out[row * J + j0 + lane] = fmaxf(fmaf(tile[row][lane], scale, shift), 0.f);
  }
}

__global__ __launch_bounds__(256) void k_head(const float* __restrict__ z, const float* __restrict__ w,
                                              const float* __restrict__ b, float* __restrict__ out) {
  __shared__ float sz[256];
  __shared__ float part[4][64];
  int bb = blockIdx.x, tid = threadIdx.x;
  sz[tid] = z[bb * 256 + tid];
  __syncthreads();
  int s = tid >> 6, j = tid & 63;
  float acc = 0.f;
  if (j < 40) {
#pragma unroll
    for (int k = 0; k < 64; k += 4) {
      int kk = s * 64 + k;
      acc = fmaf(sz[kk + 0], w[(kk + 0) * 40 + j], acc);
      acc = fmaf(sz[kk + 1], w[(kk + 1) * 40 + j], acc);
      acc = fmaf(sz[kk + 2], w[(kk + 2) * 40 + j], acc);
      acc = fmaf(sz[kk + 3], w[(kk + 3) * 40 + j], acc);
    }
  }
  part[s][j] = acc;
  __syncthreads();
  if (tid < 64) {
    float v = (j < 40) ? part[0][j] + part[1][j] + part[2][j] + part[3][j] + b[j] : -INFINITY;
    float m = v;
    for (int d = 32; d > 0; d >>= 1) m = fmaxf(m, __shfl_xor(m, d));
    float e = (j < 40) ? expf(v - m) : 0.f;
    for (int d = 32; d > 0; d >>= 1) e += __shfl_xor(e, d);
    if (j < 40) out[bb * 40 + j] = v - m - logf(e);
  }
}

extern "C" void kernel_launch(void* const* d_in, const int* in_sizes, int n_in,
                              void* d_out, int out_size, void* d_ws, size_t ws_size,
                              hipStream_t stream) {
  (void)in_sizes; (void)n_in; (void)out_size; (void)ws_size;
  const float* x    = (const float*)d_in[0];
  const int*   esrc = (const int*)d_in[1];
  const int*   edst = (const int*)d_in[2];
  const float* ev   = (const float*)d_in[3];
  const float* gc1w = (const float*)d_in[5];
  const float* gc1b = (const float*)d_in[6];
  const float* gc2w = (const float*)d_in[7];
  const float* gc2b = (const float*)d_in[8];
  const float* gc3w = (const float*)d_in[9];
  const float* gc3b = (const float*)d_in[10];
  const float* fc1w = (const float*)d_in[11];
  const float* fc1b = (const float*)d_in[12];
  const float* bn1g = (const float*)d_in[13];
  const float* bn1b = (const float*)d_in[14];
  const float* fc2w = (const float*)d_in[15];
  const float* fc2b = (const float*)d_in[16];
  const float* bn2g = (const float*)d_in[17];
  const float* bn2b = (const float*)d_in[18];
  const float* fc3w = (const float*)d_in[19];
  const float* fc3b = (const float*)d_in[20];

  char* ws = (char*)d_ws;
  size_t o = 0;
  auto alloc = [&](size_t bytes) -> void* {
    void* p = ws + o;
    o += (bytes + 255) & ~(size_t)255;
    return p;
  };
  int*   off  = (int*)alloc((size_t)(NN + 1) * 4);
  int*   gcur = (int*)alloc(64 * 4);
  int2*  pack = (int2*)alloc((size_t)NE * 8);
  float* aggx = (float*)alloc((size_t)NN * 3 * 4);
  float4* x4  = (float4*)alloc((size_t)NN * 16);
  float* bufA = (float*)alloc((size_t)NN * 64 * 4);  // ebin head; h1/h2 bf16
  float* bufB = (float*)alloc((size_t)NN * 64 * 4);  // ebin tail; Ahi/Alo
  int4*  ebin = (int4*)bufA;                         // 64*CAP*16 = 17.8 MB, dead before gemm1
  unsigned short* h1_16 = (unsigned short*)bufA;            // 8 MB
  unsigned short* h2_16 = (unsigned short*)((char*)bufA + NN * 64 * 2);  // 8 MB (second half)
  unsigned short* Ahi = (unsigned short*)bufB;              // 8 MB
  unsigned short* Alo = (unsigned short*)(bufB + NN * 32);  // 8 MB
  unsigned short* Bfrag = (unsigned short*)alloc(4 * 1024 * 32 * 2);  // 256 KB
  float* gf   = (float*)alloc(64 * 1024 * 4);
  float* z1   = (float*)alloc(64 * 512 * 4);
  float* z1n  = (float*)alloc(64 * 512 * 4);
  float* z2   = (float*)alloc(64 * 256 * 4);
  float* z2n  = (float*)alloc(64 * 256 * 4);

  hipMemsetAsync(gcur, 0, 64 * 4, stream);
  hipMemsetAsync(gf, 0, 64 * 1024 * 4, stream);

  // CSR build: 2-pass shape-bucketed
  k_bin<<<NE / 4096, 256, 0, stream>>>(esrc, edst, ev, gcur, ebin);
  k_csr<<<64, 256, 0, stream>>>(gcur, ebin, off, pack);
  k_prepw<<<512, 256, 0, stream>>>(gc3w, Bfrag);
  k_packx<<<NN / 256, 256, 0, stream>>>(x, x4);

  // layer 1  (note: gemm1 writes h1 into bufA after ebin is dead)
  k_aggx<<<NN / 256, 256, 0, stream>>>(off, pack, x4, aggx);
  k_gemm1<<<(NN * 64) / 256, 256, 0, stream>>>(aggx, gc1w, gc1b, h1_16);

  // layer 2 fused: agg(h1) @ W2 + b2, relu -> h2 bf16
  k_agg64g2<<<NN / 4, 256, 0, stream>>>(off, pack, h1_16, gc2w, gc2b, h2_16);

  // layer 3: aggregate bf16 h2 -> split-bf16 planes, then MFMA GEMM + maxpool
  k_agg64_split<<<NN / 4, 256, 0, stream>>>(off, pack, h2_16, Ahi, Alo);
  k_gemm3max<<<512, 512, 0, stream>>>(Ahi, Alo, Bfrag, gc3b, (unsigned*)gf);

  // MLP head
  k_fc<<<dim3(8, 64), 512, 0, stream>>>(gf, fc1w, fc1b, z1, 1024, 512);
  k_bn<<<8, 256, 0, stream>>>(z1, bn1g, bn1b, z1n, 512);
  k_fc<<<dim3(4, 64), 512, 0, stream>>>(z1n, fc2w, fc2b, z2, 512, 256);
  k_bn<<<4, 256, 0, stream>>>(z2, bn2g, bn2b, z2n, 256);
  k_head<<<64, 256, 0, stream>>>(z2n, fc3w, fc3b, (float*)d_out);
}

// Round 7
// 261.554 us; speedup vs baseline: 2.9506x; 1.0840x over previous
//
#include <hip/hip_runtime.h>
#include <math.h>

#define NN 65536
#define NE 1048576
#define CAP 17408  // per-bucket capacity: mean 16384, sd ~127, 8-sigma slack

typedef __attribute__((ext_vector_type(8))) short short8;
typedef __attribute__((ext_vector_type(4))) float f32x4;

__device__ inline unsigned short f2bf(float f) {
  unsigned u = __float_as_uint(f);
  unsigned r = u + 0x7fff + ((u >> 16) & 1);  // RNE
  return (unsigned short)(r >> 16);
}
__device__ inline float bf2f(unsigned short h) { return __uint_as_float(((unsigned)h) << 16); }

// ---------------- CSR build, pass 1: bin edges by shape (dst>>10) ----------------
__global__ __launch_bounds__(256) void k_bin(const int* __restrict__ src, const int* __restrict__ dst,
                                             const float* __restrict__ val, int* __restrict__ gcur,
                                             int4* __restrict__ ebin) {
  __shared__ int cnt[64], base[64];
  int tid = threadIdx.x;
  if (tid < 64) cnt[tid] = 0;
  __syncthreads();
  int e0 = blockIdx.x * 4096;
  int rsrc[16], rdst[16], rrank[16];
  float rval[16];
#pragma unroll
  for (int i = 0; i < 16; ++i) {
    int e = e0 + i * 256 + tid;
    rsrc[i] = src[e];
    rdst[i] = dst[e];
    rval[i] = val[e];
    rrank[i] = atomicAdd(&cnt[rdst[i] >> 10], 1);
  }
  __syncthreads();
  if (tid < 64) base[tid] = atomicAdd(&gcur[tid], cnt[tid]);
  __syncthreads();
#pragma unroll
  for (int i = 0; i < 16; ++i) {
    int b = rdst[i] >> 10;
    ebin[b * CAP + base[b] + rrank[i]] = make_int4(rsrc[i], rdst[i] & 1023, __float_as_int(rval[i]), 0);
  }
}

// ---------------- CSR build, pass 2: per-bucket local CSR (one block per shape) ----------------
__global__ __launch_bounds__(256) void k_csr(const int* __restrict__ gcnt, const int4* __restrict__ ebin,
                                             int* __restrict__ off, int2* __restrict__ pack) {
  __shared__ int lcnt[1024], lcur[1024], part[256];
  int b = blockIdx.x, tid = threadIdx.x;
  int count = gcnt[b];
  int gbase = 0;
  for (int i = 0; i < 64; ++i) gbase += (i < b) ? gcnt[i] : 0;
  for (int i = tid; i < 1024; i += 256) lcnt[i] = 0;
  __syncthreads();
  for (int i = tid; i < count; i += 256) atomicAdd(&lcnt[ebin[b * CAP + i].y], 1);
  __syncthreads();
  int s0 = lcnt[4 * tid], s1 = lcnt[4 * tid + 1], s2 = lcnt[4 * tid + 2], s3 = lcnt[4 * tid + 3];
  int tsum = s0 + s1 + s2 + s3;
  part[tid] = tsum;
  __syncthreads();
  for (int d = 1; d < 256; d <<= 1) {
    int v = (tid >= d) ? part[tid - d] : 0;
    __syncthreads();
    part[tid] += v;
    __syncthreads();
  }
  int tbase = part[tid] - tsum;  // exclusive
  int o0 = tbase, o1 = tbase + s0, o2 = o1 + s1, o3 = o2 + s2;
  lcur[4 * tid] = o0; lcur[4 * tid + 1] = o1; lcur[4 * tid + 2] = o2; lcur[4 * tid + 3] = o3;
  off[b * 1024 + 4 * tid] = gbase + o0;
  off[b * 1024 + 4 * tid + 1] = gbase + o1;
  off[b * 1024 + 4 * tid + 2] = gbase + o2;
  off[b * 1024 + 4 * tid + 3] = gbase + o3;
  if (b == 63 && tid == 255) off[NN] = gbase + count;
  __syncthreads();
  for (int i = tid; i < count; i += 256) {
    int4 e = ebin[b * CAP + i];
    int p = atomicAdd(&lcur[e.y], 1);
    pack[gbase + p] = make_int2(e.x, e.z);
  }
}

// ---------------- GCN layer 1 ----------------
__global__ __launch_bounds__(256) void k_packx(const float* __restrict__ x, float4* __restrict__ x4) {
  int n = blockIdx.x * 256 + threadIdx.x;
  x4[n] = make_float4(x[3 * n], x[3 * n + 1], x[3 * n + 2], 0.f);
}

// thread per node, 8-deep gather pipeline
__global__ __launch_bounds__(256) void k_aggx(const int* __restrict__ off, const int2* __restrict__ pack,
                                              const float4* __restrict__ x4, float* __restrict__ aggx) {
  int n = blockIdx.x * 256 + threadIdx.x;
  int i0 = off[n], e = off[n + 1];
  int deg = e - i0;
  float a0 = 0.f, a1 = 0.f, a2 = 0.f;
  for (int b = 0; b < deg; b += 8) {
    int2 ed[8];
    float4 q[8];
#pragma unroll
    for (int u = 0; u < 8; ++u) ed[u] = pack[min(i0 + b + u, e - 1)];
#pragma unroll
    for (int u = 0; u < 8; ++u) q[u] = x4[ed[u].x];
#pragma unroll
    for (int u = 0; u < 8; ++u) {
      float v = (b + u < deg) ? __int_as_float(ed[u].y) : 0.f;
      a0 = fmaf(v, q[u].x, a0);
      a1 = fmaf(v, q[u].y, a1);
      a2 = fmaf(v, q[u].z, a2);
    }
  }
  aggx[n * 3 + 0] = a0;
  aggx[n * 3 + 1] = a1;
  aggx[n * 3 + 2] = a2;
}

__global__ __launch_bounds__(256) void k_gemm1(const float* __restrict__ aggx, const float* __restrict__ w,
                                               const float* __restrict__ b, unsigned short* __restrict__ out) {
  __shared__ float sw[256];
  int t = threadIdx.x;
  sw[t] = (t < 192) ? w[t] : b[t - 192];
  __syncthreads();
  int g = blockIdx.x * 256 + t;
  int n = g >> 6, j = g & 63;
  float a0 = aggx[n * 3], a1 = aggx[n * 3 + 1], a2 = aggx[n * 3 + 2];
  float r = sw[192 + j];
  r = fmaf(a0, sw[j], r);
  r = fmaf(a1, sw[64 + j], r);
  r = fmaf(a2, sw[128 + j], r);
  out[g] = f2bf(fmaxf(r, 0.f));
}

// ---------------- fused layer-2: agg(h1) -> @W2+b2, relu -> h2 bf16 ----------------
// wave per node; lane = feature; 8-deep gather pipeline; W2 staged in LDS.
__global__ __launch_bounds__(256) void k_agg64g2(const int* __restrict__ off, const int2* __restrict__ pack,
                                                 const unsigned short* __restrict__ h,
                                                 const float* __restrict__ w2, const float* __restrict__ b2,
                                                 unsigned short* __restrict__ out) {
  __shared__ float sw[64][64];   // sw[k][j]
  __shared__ float rows[4][64];
  int tid = threadIdx.x;
  int lane = tid & 63, wv = tid >> 6;
  for (int t = tid; t < 1024; t += 256) ((float4*)sw)[t] = ((const float4*)w2)[t];
  __syncthreads();
  float bb = b2[lane];
  int n = blockIdx.x * 4 + wv;
  int i0 = off[n], e = off[n + 1];
  int deg = e - i0;
  float a0 = 0.f, a1 = 0.f, a2 = 0.f, a3 = 0.f;
  for (int b = 0; b < deg; b += 8) {
    int2 ed[8];
    float hv[8];
#pragma unroll
    for (int u = 0; u < 8; ++u) ed[u] = pack[min(i0 + b + u, e - 1)];
#pragma unroll
    for (int u = 0; u < 8; ++u) hv[u] = bf2f(h[(size_t)ed[u].x * 64 + lane]);
#pragma unroll
    for (int u = 0; u < 8; ++u) {
      float v = (b + u < deg) ? __int_as_float(ed[u].y) : 0.f;
      float& acc = (u & 2) ? ((u & 1) ? a3 : a2) : ((u & 1) ? a1 : a0);
      acc = fmaf(v, hv[u], acc);
    }
  }
  rows[wv][lane] = (a0 + a1) + (a2 + a3);
  // same-wave LDS write->read; compiler orders via lgkmcnt
  float acc = bb;
  const float4* rv = (const float4*)rows[wv];
#pragma unroll
  for (int kk = 0; kk < 16; ++kk) {
    float4 q = rv[kk];  // broadcast
    acc = fmaf(q.x, sw[4 * kk + 0][lane], acc);
    acc = fmaf(q.y, sw[4 * kk + 1][lane], acc);
    acc = fmaf(q.z, sw[4 * kk + 2][lane], acc);
    acc = fmaf(q.w, sw[4 * kk + 3][lane], acc);
  }
  out[(size_t)n * 64 + lane] = f2bf(fmaxf(acc, 0.f));
}

// 64-feature aggregation from bf16 h -> split-bf16 planes; 8-deep gather pipeline
__global__ __launch_bounds__(256) void k_agg64_split(const int* __restrict__ off, const int2* __restrict__ pack,
                                                     const unsigned short* __restrict__ h,
                                                     unsigned short* __restrict__ hi,
                                                     unsigned short* __restrict__ lo) {
  int lane = threadIdx.x & 63;
  int n = blockIdx.x * 4 + (threadIdx.x >> 6);
  int i0 = off[n], e = off[n + 1];
  int deg = e - i0;
  float a0 = 0.f, a1 = 0.f, a2 = 0.f, a3 = 0.f;
  for (int b = 0; b < deg; b += 8) {
    int2 ed[8];
    float hv[8];
#pragma unroll
    for (int u = 0; u < 8; ++u) ed[u] = pack[min(i0 + b + u, e - 1)];
#pragma unroll
    for (int u = 0; u < 8; ++u) hv[u] = bf2f(h[(size_t)ed[u].x * 64 + lane]);
#pragma unroll
    for (int u = 0; u < 8; ++u) {
      float v = (b + u < deg) ? __int_as_float(ed[u].y) : 0.f;
      float& acc = (u & 2) ? ((u & 1) ? a3 : a2) : ((u & 1) ? a1 : a0);
      acc = fmaf(v, hv[u], acc);
    }
  }
  float acc = (a0 + a1) + (a2 + a3);
  unsigned short h16 = f2bf(acc);
  unsigned short l16 = f2bf(acc - bf2f(h16));
  size_t idx = (size_t)n * 64 + lane;
  hi[idx] = h16;
  lo[idx] = l16;
}

// ---------------- W3 prep: split-bf16, MFMA-fragment order ----------------
__global__ __launch_bounds__(256) void k_prepw(const float* __restrict__ w3, unsigned short* __restrict__ bfrag) {
  int t = blockIdx.x * 256 + threadIdx.x;  // 131072 total
  int e = t & 7, g = (t >> 3) & 3, col = (t >> 5) & 1023, q = t >> 15;
  int k = (q & 1) * 32 + g * 8 + e;
  float v = w3[k * 1024 + col];
  unsigned short hv = f2bf(v);
  bfrag[t] = (q < 2) ? hv : f2bf(v - bf2f(hv));
}

// ---------------- GCN layer 3 GEMM + maxpool via MFMA (split-bf16) ----------------
__global__ __launch_bounds__(512) void k_gemm3max(const unsigned short* __restrict__ Ahi,
                                                  const unsigned short* __restrict__ Alo,
                                                  const unsigned short* __restrict__ Bfrag,
                                                  const float* __restrict__ b3,
                                                  unsigned* __restrict__ gf) {
  int b = blockIdx.x;
  int colhalf = b & 1, rowchunk = b >> 1;  // rowchunk 0..255 (256 rows each)
  int shape = rowchunk >> 2;
  int tid = threadIdx.x;
  int wv = tid >> 6, l = tid & 63;
  int g = l >> 4, lr = l & 15;

  const short8* bf = (const short8*)Bfrag;
  int c0 = colhalf * 512 + wv * 64 + lr;
  short8 B0[4], B1[4], B2[4], B3[4];
#pragma unroll
  for (int ct = 0; ct < 4; ++ct) {
    int col = c0 + ct * 16;
    B0[ct] = bf[(0 * 1024 + col) * 4 + g];
    B1[ct] = bf[(1 * 1024 + col) * 4 + g];
    B2[ct] = bf[(2 * 1024 + col) * 4 + g];
    B3[ct] = bf[(3 * 1024 + col) * 4 + g];
  }

  float m[4] = {-1e30f, -1e30f, -1e30f, -1e30f};
  size_t abase = ((size_t)rowchunk * 256 + lr) * 64 + g * 8;
  for (int t = 0; t < 16; ++t) {
    size_t o = abase + (size_t)t * 16 * 64;
    short8 ah0 = *(const short8*)(Ahi + o);
    short8 ah1 = *(const short8*)(Ahi + o + 32);
    short8 al0 = *(const short8*)(Alo + o);
    short8 al1 = *(const short8*)(Alo + o + 32);
#pragma unroll
    for (int ct = 0; ct < 4; ++ct) {
      f32x4 acc = {0.f, 0.f, 0.f, 0.f};
      acc = __builtin_amdgcn_mfma_f32_16x16x32_bf16(ah0, B0[ct], acc, 0, 0, 0);
      acc = __builtin_amdgcn_mfma_f32_16x16x32_bf16(ah1, B1[ct], acc, 0, 0, 0);
      acc = __builtin_amdgcn_mfma_f32_16x16x32_bf16(ah0, B2[ct], acc, 0, 0, 0);
      acc = __builtin_amdgcn_mfma_f32_16x16x32_bf16(ah1, B3[ct], acc, 0, 0, 0);
      acc = __builtin_amdgcn_mfma_f32_16x16x32_bf16(al0, B0[ct], acc, 0, 0, 0);
      acc = __builtin_amdgcn_mfma_f32_16x16x32_bf16(al1, B1[ct], acc, 0, 0, 0);
      m[ct] = fmaxf(m[ct], fmaxf(fmaxf(acc[0], acc[1]), fmaxf(acc[2], acc[3])));
    }
  }
#pragma unroll
  for (int ct = 0; ct < 4; ++ct) {
    float mm = m[ct];
    mm = fmaxf(mm, __shfl_xor(mm, 16));
    mm = fmaxf(mm, __shfl_xor(mm, 32));
    if (g == 0) {
      int col = c0 + ct * 16;
      float v = fmaxf(mm + b3[col], 0.f);
      atomicMax(&gf[shape * 1024 + col], __float_as_uint(v));
    }
  }
}

// ---------------- MLP head ----------------
// grid (J/64, 64): 512 thr = 8 waves; wave s covers K/8; 16-deep load bursts.
__global__ __launch_bounds__(512) void k_fc(const float* __restrict__ in, const float* __restrict__ w,
                                            const float* __restrict__ bias, float* __restrict__ out,
                                            int K, int J) {
  __shared__ float sin_[1024];
  __shared__ float part[8][64];
  int jt = blockIdx.x, bb = blockIdx.y;
  int tid = threadIdx.x, s = tid >> 6, lane = tid & 63;
  for (int i = tid; i < K; i += 512) sin_[i] = in[bb * K + i];
  __syncthreads();
  int j = (jt << 6) + lane;
  int Ks = K >> 3;
  int k0 = s * Ks;
  float acc = 0.f;
  for (int k = 0; k < Ks; k += 16) {
    float wv[16];
#pragma unroll
    for (int u = 0; u < 16; ++u) wv[u] = w[(k0 + k + u) * J + j];
#pragma unroll
    for (int u = 0; u < 16; ++u) acc = fmaf(sin_[k0 + k + u], wv[u], acc);
  }
  part[s][lane] = acc;
  __syncthreads();
  if (tid < 64) {
    float r = bias[(jt << 6) + tid];
#pragma unroll
    for (int u = 0; u < 8; ++u) r += part[u][tid];
    out[bb * J + (jt << 6) + tid] = r;
  }
}

__global__ __launch_bounds__(256) void k_bn(const float* __restrict__ z, const float* __restrict__ g,
                                            const float* __restrict__ bt, float* __restrict__ out, int J) {
  __shared__ float tile[64][64];
  __shared__ float red[4][64];
  __shared__ float sc[64], sh[64];
  int tid = threadIdx.x, s = tid >> 6, lane = tid & 63;
  int j0 = blockIdx.x << 6;
  float psum = 0.f;
#pragma unroll
  for (int r = 0; r < 16; ++r) {
    int row = s * 16 + r;
    float v = z[row * J + j0 + lane];
    tile[row][lane] = v;
    psum += v;
  }
  red[s][lane] = psum;
  __syncthreads();
  if (tid < 64) sc[tid] = (red[0][tid] + red[1][tid] + red[2][tid] + red[3][tid]) * (1.f / 64.f);
  __syncthreads();
  float mean = sc[lane];
  float pv = 0.f;
#pragma unroll
  for (int r = 0; r < 16; ++r) {
    float d = tile[s * 16 + r][lane] - mean;
    pv = fmaf(d, d, pv);
  }
  red[s][lane] = pv;
  __syncthreads();
  if (tid < 64) {
    float var = (red[0][tid] + red[1][tid] + red[2][tid] + red[3][tid]) * (1.f / 64.f);
    float scale = g[j0 + tid] / sqrtf(var + 1e-5f);
    sh[tid] = bt[j0 + tid] - sc[tid] * scale;
    sc[tid] = scale;
  }
  __syncthreads();
  float scale = sc[lane], shift = sh[lane];
#pragma unroll
  for (int r = 0; r < 16; ++r) {
    int row = s * 16 + r;
    out[row * J + j0 + lane] = fmaxf(fmaf(tile[row][lane], scale, shift), 0.f);
  }
}

__global__ __launch_bounds__(256) void k_head(const float* __restrict__ z, const float* __restrict__ w,
                                              const float* __restrict__ b, float* __restrict__ out) {
  __shared__ float sz[256];
  __shared__ float part[4][64];
  int bb = blockIdx.x, tid = threadIdx.x;
  sz[tid] = z[bb * 256 + tid];
  __syncthreads();
  int s = tid >> 6, j = tid & 63;
  float acc = 0.f;
  if (j < 40) {
#pragma unroll
    for (int k = 0; k < 64; k += 4) {
      int kk = s * 64 + k;
      acc = fmaf(sz[kk + 0], w[(kk + 0) * 40 + j], acc);
      acc = fmaf(sz[kk + 1], w[(kk + 1) * 40 + j], acc);
      acc = fmaf(sz[kk + 2], w[(kk + 2) * 40 + j], acc);
      acc = fmaf(sz[kk + 3], w[(kk + 3) * 40 + j], acc);
    }
  }
  part[s][j] = acc;
  __syncthreads();
  if (tid < 64) {
    float v = (j < 40) ? part[0][j] + part[1][j] + part[2][j] + part[3][j] + b[j] : -INFINITY;
    float m = v;
    for (int d = 32; d > 0; d >>= 1) m = fmaxf(m, __shfl_xor(m, d));
    float e = (j < 40) ? expf(v - m) : 0.f;
    for (int d = 32; d > 0; d >>= 1) e += __shfl_xor(e, d);
    if (j < 40) out[bb * 40 + j] = v - m - logf(e);
  }
}

extern "C" void kernel_launch(void* const* d_in, const int* in_sizes, int n_in,
                              void* d_out, int out_size, void* d_ws, size_t ws_size,
                              hipStream_t stream) {
  (void)in_sizes; (void)n_in; (void)out_size; (void)ws_size;
  const float* x    = (const float*)d_in[0];
  const int*   esrc = (const int*)d_in[1];
  const int*   edst = (const int*)d_in[2];
  const float* ev   = (const float*)d_in[3];
  const float* gc1w = (const float*)d_in[5];
  const float* gc1b = (const float*)d_in[6];
  const float* gc2w = (const float*)d_in[7];
  const float* gc2b = (const float*)d_in[8];
  const float* gc3w = (const float*)d_in[9];
  const float* gc3b = (const float*)d_in[10];
  const float* fc1w = (const float*)d_in[11];
  const float* fc1b = (const float*)d_in[12];
  const float* bn1g = (const float*)d_in[13];
  const float* bn1b = (const float*)d_in[14];
  const float* fc2w = (const float*)d_in[15];
  const float* fc2b = (const float*)d_in[16];
  const float* bn2g = (const float*)d_in[17];
  const float* bn2b = (const float*)d_in[18];
  const float* fc3w = (const float*)d_in[19];
  const float* fc3b = (const float*)d_in[20];

  char* ws = (char*)d_ws;
  size_t o = 0;
  auto alloc = [&](size_t bytes) -> void* {
    void* p = ws + o;
    o += (bytes + 255) & ~(size_t)255;
    return p;
  };
  int*   off  = (int*)alloc((size_t)(NN + 1) * 4);
  int*   gcur = (int*)alloc(64 * 4);
  int2*  pack = (int2*)alloc((size_t)NE * 8);
  float* aggx = (float*)alloc((size_t)NN * 3 * 4);
  float4* x4  = (float4*)alloc((size_t)NN * 16);
  float* bufA = (float*)alloc((size_t)NN * 64 * 4);  // ebin head; h1/h2 bf16
  float* bufB = (float*)alloc((size_t)NN * 64 * 4);  // ebin tail; Ahi/Alo
  int4*  ebin = (int4*)bufA;                         // 64*CAP*16 = 17.8 MB, dead before gemm1
  unsigned short* h1_16 = (unsigned short*)bufA;            // 8 MB
  unsigned short* h2_16 = (unsigned short*)((char*)bufA + NN * 64 * 2);  // 8 MB (second half)
  unsigned short* Ahi = (unsigned short*)bufB;              // 8 MB
  unsigned short* Alo = (unsigned short*)(bufB + NN * 32);  // 8 MB
  unsigned short* Bfrag = (unsigned short*)alloc(4 * 1024 * 32 * 2);  // 256 KB
  float* gf   = (float*)alloc(64 * 1024 * 4);
  float* z1   = (float*)alloc(64 * 512 * 4);
  float* z1n  = (float*)alloc(64 * 512 * 4);
  float* z2   = (float*)alloc(64 * 256 * 4);
  float* z2n  = (float*)alloc(64 * 256 * 4);

  hipMemsetAsync(gcur, 0, 64 * 4, stream);
  hipMemsetAsync(gf, 0, 64 * 1024 * 4, stream);

  // CSR build: 2-pass shape-bucketed
  k_bin<<<NE / 4096, 256, 0, stream>>>(esrc, edst, ev, gcur, ebin);
  k_csr<<<64, 256, 0, stream>>>(gcur, ebin, off, pack);
  k_prepw<<<512, 256, 0, stream>>>(gc3w, Bfrag);
  k_packx<<<NN / 256, 256, 0, stream>>>(x, x4);

  // layer 1  (gemm1 writes h1 into bufA after ebin is dead)
  k_aggx<<<NN / 256, 256, 0, stream>>>(off, pack, x4, aggx);
  k_gemm1<<<(NN * 64) / 256, 256, 0, stream>>>(aggx, gc1w, gc1b, h1_16);

  // layer 2 fused: agg(h1) @ W2 + b2, relu -> h2 bf16
  k_agg64g2<<<NN / 4, 256, 0, stream>>>(off, pack, h1_16, gc2w, gc2b, h2_16);

  // layer 3: aggregate bf16 h2 -> split-bf16 planes, then MFMA GEMM + maxpool
  k_agg64_split<<<NN / 4, 256, 0, stream>>>(off, pack, h2_16, Ahi, Alo);
  k_gemm3max<<<512, 512, 0, stream>>>(Ahi, Alo, Bfrag, gc3b, (unsigned*)gf);

  // MLP head
  k_fc<<<dim3(8, 64), 512, 0, stream>>>(gf, fc1w, fc1b, z1, 1024, 512);
  k_bn<<<8, 256, 0, stream>>>(z1, bn1g, bn1b, z1n, 512);
  k_fc<<<dim3(4, 64), 512, 0, stream>>>(z1n, fc2w, fc2b, z2, 512, 256);
  k_bn<<<4, 256, 0, stream>>>(z2, bn2g, bn2b, z2n, 256);
  k_head<<<64, 256, 0, stream>>>(z2n, fc3w, fc3b, (float*)d_out);
}

// Round 8
// 218.662 us; speedup vs baseline: 3.5294x; 1.1962x over previous
//
#include <hip/hip_runtime.h>
#include <math.h>

#define NN 65536
#define NE 1048576
#define CAP 17408  // per-bucket capacity: mean 16384, sd ~127, 8-sigma slack

typedef __attribute__((ext_vector_type(8))) short short8;
typedef __attribute__((ext_vector_type(4))) float f32x4;

__device__ inline unsigned short f2bf(float f) {
  unsigned u = __float_as_uint(f);
  unsigned r = u + 0x7fff + ((u >> 16) & 1);  // RNE
  return (unsigned short)(r >> 16);
}
__device__ inline float bf2f(unsigned short h) { return __uint_as_float(((unsigned)h) << 16); }

// ---------------- CSR build, pass 1: bin edges by shape (dst>>10) ----------------
__global__ __launch_bounds__(256) void k_bin(const int* __restrict__ src, const int* __restrict__ dst,
                                             const float* __restrict__ val, int* __restrict__ gcur,
                                             int4* __restrict__ ebin) {
  __shared__ int cnt[64], base[64];
  int tid = threadIdx.x;
  if (tid < 64) cnt[tid] = 0;
  __syncthreads();
  int e0 = blockIdx.x * 4096;
  int rsrc[16], rdst[16], rrank[16];
  float rval[16];
#pragma unroll
  for (int i = 0; i < 16; ++i) {
    int e = e0 + i * 256 + tid;
    rsrc[i] = src[e];
    rdst[i] = dst[e];
    rval[i] = val[e];
    rrank[i] = atomicAdd(&cnt[rdst[i] >> 10], 1);
  }
  __syncthreads();
  if (tid < 64) base[tid] = atomicAdd(&gcur[tid], cnt[tid]);
  __syncthreads();
#pragma unroll
  for (int i = 0; i < 16; ++i) {
    int b = rdst[i] >> 10;
    ebin[b * CAP + base[b] + rrank[i]] = make_int4(rsrc[i], rdst[i] & 1023, __float_as_int(rval[i]), 0);
  }
}

// ---------------- CSR build, pass 2: per-bucket local CSR (one block per shape) ----------------
__global__ __launch_bounds__(256) void k_csr(const int* __restrict__ gcnt, const int4* __restrict__ ebin,
                                             int* __restrict__ off, int2* __restrict__ pack) {
  __shared__ int lcnt[1024], lcur[1024], part[256];
  int b = blockIdx.x, tid = threadIdx.x;
  int count = gcnt[b];
  int gbase = 0;
  for (int i = 0; i < 64; ++i) gbase += (i < b) ? gcnt[i] : 0;
  for (int i = tid; i < 1024; i += 256) lcnt[i] = 0;
  __syncthreads();
  for (int i = tid; i < count; i += 256) atomicAdd(&lcnt[ebin[b * CAP + i].y], 1);
  __syncthreads();
  int s0 = lcnt[4 * tid], s1 = lcnt[4 * tid + 1], s2 = lcnt[4 * tid + 2], s3 = lcnt[4 * tid + 3];
  int tsum = s0 + s1 + s2 + s3;
  part[tid] = tsum;
  __syncthreads();
  for (int d = 1; d < 256; d <<= 1) {
    int v = (tid >= d) ? part[tid - d] : 0;
    __syncthreads();
    part[tid] += v;
    __syncthreads();
  }
  int tbase = part[tid] - tsum;  // exclusive
  int o0 = tbase, o1 = tbase + s0, o2 = o1 + s1, o3 = o2 + s2;
  lcur[4 * tid] = o0; lcur[4 * tid + 1] = o1; lcur[4 * tid + 2] = o2; lcur[4 * tid + 3] = o3;
  off[b * 1024 + 4 * tid] = gbase + o0;
  off[b * 1024 + 4 * tid + 1] = gbase + o1;
  off[b * 1024 + 4 * tid + 2] = gbase + o2;
  off[b * 1024 + 4 * tid + 3] = gbase + o3;
  if (b == 63 && tid == 255) off[NN] = gbase + count;
  __syncthreads();
  for (int i = tid; i < count; i += 256) {
    int4 e = ebin[b * CAP + i];
    int p = atomicAdd(&lcur[e.y], 1);
    pack[gbase + p] = make_int2(e.x, e.z);
  }
}

// ---------------- GCN layer 1 ----------------
__global__ __launch_bounds__(256) void k_packx(const float* __restrict__ x, float4* __restrict__ x4) {
  int n = blockIdx.x * 256 + threadIdx.x;
  x4[n] = make_float4(x[3 * n], x[3 * n + 1], x[3 * n + 2], 0.f);
}

// thread per node, 8-deep gather pipeline
__global__ __launch_bounds__(256) void k_aggx(const int* __restrict__ off, const int2* __restrict__ pack,
                                              const float4* __restrict__ x4, float* __restrict__ aggx) {
  int n = blockIdx.x * 256 + threadIdx.x;
  int i0 = off[n], e = off[n + 1];
  int deg = e - i0;
  float a0 = 0.f, a1 = 0.f, a2 = 0.f;
  for (int b = 0; b < deg; b += 8) {
    int2 ed[8];
    float4 q[8];
#pragma unroll
    for (int u = 0; u < 8; ++u) ed[u] = pack[min(i0 + b + u, e - 1)];
#pragma unroll
    for (int u = 0; u < 8; ++u) q[u] = x4[ed[u].x];
#pragma unroll
    for (int u = 0; u < 8; ++u) {
      float v = (b + u < deg) ? __int_as_float(ed[u].y) : 0.f;
      a0 = fmaf(v, q[u].x, a0);
      a1 = fmaf(v, q[u].y, a1);
      a2 = fmaf(v, q[u].z, a2);
    }
  }
  aggx[n * 3 + 0] = a0;
  aggx[n * 3 + 1] = a1;
  aggx[n * 3 + 2] = a2;
}

__global__ __launch_bounds__(256) void k_gemm1(const float* __restrict__ aggx, const float* __restrict__ w,
                                               const float* __restrict__ b, unsigned short* __restrict__ out) {
  __shared__ float sw[256];
  int t = threadIdx.x;
  sw[t] = (t < 192) ? w[t] : b[t - 192];
  __syncthreads();
  int g = blockIdx.x * 256 + t;
  int n = g >> 6, j = g & 63;
  float a0 = aggx[n * 3], a1 = aggx[n * 3 + 1], a2 = aggx[n * 3 + 2];
  float r = sw[192 + j];
  r = fmaf(a0, sw[j], r);
  r = fmaf(a1, sw[64 + j], r);
  r = fmaf(a2, sw[128 + j], r);
  out[g] = f2bf(fmaxf(r, 0.f));
}

// ---------------- fused layer-2: agg(h1) -> @W2+b2, relu -> h2 bf16 ----------------
// 2 nodes per wave, 2 features per lane (uint = 2xbf16 per gather); W2 in LDS.
__global__ __launch_bounds__(256) void k_agg64g2(const int* __restrict__ off, const int2* __restrict__ pack,
                                                 const unsigned short* __restrict__ h,
                                                 const float* __restrict__ w2, const float* __restrict__ b2,
                                                 unsigned short* __restrict__ out) {
  __shared__ float sw[64][64];    // sw[k][j]
  __shared__ float rows[8][64];
  int tid = threadIdx.x;
  int lane = tid & 63, wv = tid >> 6;
  for (int t = tid; t < 1024; t += 256) ((float4*)sw)[t] = ((const float4*)w2)[t];
  __syncthreads();
  int half = lane >> 5, fl = lane & 31;
  int n = blockIdx.x * 8 + wv * 2 + half;
  int i0 = off[n], e = off[n + 1];
  int deg = e - i0;
  const unsigned* h32 = (const unsigned*)h;
  float l0 = 0.f, l1 = 0.f, h0 = 0.f, h1 = 0.f;
  for (int b = 0; b < deg; b += 8) {
    int2 ed[8];
    unsigned hv[8];
#pragma unroll
    for (int u = 0; u < 8; ++u) ed[u] = pack[min(i0 + b + u, e - 1)];
#pragma unroll
    for (int u = 0; u < 8; ++u) hv[u] = h32[(size_t)ed[u].x * 32 + fl];
#pragma unroll
    for (int u = 0; u < 8; ++u) {
      float v = (b + u < deg) ? __int_as_float(ed[u].y) : 0.f;
      float flo = __uint_as_float(hv[u] << 16);
      float fhi = __uint_as_float(hv[u] & 0xffff0000u);
      if (u & 1) { l1 = fmaf(v, flo, l1); h1 = fmaf(v, fhi, h1); }
      else       { l0 = fmaf(v, flo, l0); h0 = fmaf(v, fhi, h0); }
    }
  }
  // lane holds feats 2fl, 2fl+1 of its node; write row (same-wave LDS dependence)
  ((float2*)rows[wv * 2 + half])[fl] = make_float2(l0 + l1, h0 + h1);
  int nA = blockIdx.x * 8 + wv * 2;
  float bb = b2[lane];
  float accA = bb, accB = bb;
  const float4* ra = (const float4*)rows[wv * 2];
  const float4* rb = (const float4*)rows[wv * 2 + 1];
#pragma unroll
  for (int kk = 0; kk < 16; ++kk) {
    float4 qa = ra[kk];
    float4 qb = rb[kk];
    accA = fmaf(qa.x, sw[4 * kk + 0][lane], accA);
    accB = fmaf(qb.x, sw[4 * kk + 0][lane], accB);
    accA = fmaf(qa.y, sw[4 * kk + 1][lane], accA);
    accB = fmaf(qb.y, sw[4 * kk + 1][lane], accB);
    accA = fmaf(qa.z, sw[4 * kk + 2][lane], accA);
    accB = fmaf(qb.z, sw[4 * kk + 2][lane], accB);
    accA = fmaf(qa.w, sw[4 * kk + 3][lane], accA);
    accB = fmaf(qb.w, sw[4 * kk + 3][lane], accB);
  }
  out[(size_t)nA * 64 + lane] = f2bf(fmaxf(accA, 0.f));
  out[(size_t)(nA + 1) * 64 + lane] = f2bf(fmaxf(accB, 0.f));
}

// 64-feature aggregation -> split-bf16 planes; 2 nodes/wave, 2 feats/lane
__global__ __launch_bounds__(256) void k_agg64_split(const int* __restrict__ off, const int2* __restrict__ pack,
                                                     const unsigned short* __restrict__ h,
                                                     unsigned short* __restrict__ hi,
                                                     unsigned short* __restrict__ lo) {
  int tid = threadIdx.x;
  int lane = tid & 63, wv = tid >> 6;
  int half = lane >> 5, fl = lane & 31;
  int n = blockIdx.x * 8 + wv * 2 + half;
  int i0 = off[n], e = off[n + 1];
  int deg = e - i0;
  const unsigned* h32 = (const unsigned*)h;
  float l0 = 0.f, l1 = 0.f, h0 = 0.f, h1 = 0.f;
  for (int b = 0; b < deg; b += 8) {
    int2 ed[8];
    unsigned hv[8];
#pragma unroll
    for (int u = 0; u < 8; ++u) ed[u] = pack[min(i0 + b + u, e - 1)];
#pragma unroll
    for (int u = 0; u < 8; ++u) hv[u] = h32[(size_t)ed[u].x * 32 + fl];
#pragma unroll
    for (int u = 0; u < 8; ++u) {
      float v = (b + u < deg) ? __int_as_float(ed[u].y) : 0.f;
      float flo = __uint_as_float(hv[u] << 16);
      float fhi = __uint_as_float(hv[u] & 0xffff0000u);
      if (u & 1) { l1 = fmaf(v, flo, l1); h1 = fmaf(v, fhi, h1); }
      else       { l0 = fmaf(v, flo, l0); h0 = fmaf(v, fhi, h0); }
    }
  }
  float accLo = l0 + l1, accHi = h0 + h1;  // feats 2fl, 2fl+1
  unsigned short hA = f2bf(accLo), hB = f2bf(accHi);
  unsigned short lA = f2bf(accLo - bf2f(hA)), lB = f2bf(accHi - bf2f(hB));
  ((unsigned*)hi)[(size_t)n * 32 + fl] = (unsigned)hA | ((unsigned)hB << 16);
  ((unsigned*)lo)[(size_t)n * 32 + fl] = (unsigned)lA | ((unsigned)lB << 16);
}

// ---------------- W3 prep: split-bf16, MFMA-fragment order ----------------
__global__ __launch_bounds__(256) void k_prepw(const float* __restrict__ w3, unsigned short* __restrict__ bfrag) {
  int t = blockIdx.x * 256 + threadIdx.x;  // 131072 total
  int e = t & 7, g = (t >> 3) & 3, col = (t >> 5) & 1023, q = t >> 15;
  int k = (q & 1) * 32 + g * 8 + e;
  float v = w3[k * 1024 + col];
  unsigned short hv = f2bf(v);
  bfrag[t] = (q < 2) ? hv : f2bf(v - bf2f(hv));
}

// ---------------- GCN layer 3 GEMM + maxpool via MFMA (split-bf16) ----------------
__global__ __launch_bounds__(512) void k_gemm3max(const unsigned short* __restrict__ Ahi,
                                                  const unsigned short* __restrict__ Alo,
                                                  const unsigned short* __restrict__ Bfrag,
                                                  const float* __restrict__ b3,
                                                  unsigned* __restrict__ gf) {
  int b = blockIdx.x;
  int colhalf = b & 1, rowchunk = b >> 1;  // rowchunk 0..255 (256 rows each)
  int shape = rowchunk >> 2;
  int tid = threadIdx.x;
  int wv = tid >> 6, l = tid & 63;
  int g = l >> 4, lr = l & 15;

  const short8* bf = (const short8*)Bfrag;
  int c0 = colhalf * 512 + wv * 64 + lr;
  short8 B0[4], B1[4], B2[4], B3[4];
#pragma unroll
  for (int ct = 0; ct < 4; ++ct) {
    int col = c0 + ct * 16;
    B0[ct] = bf[(0 * 1024 + col) * 4 + g];
    B1[ct] = bf[(1 * 1024 + col) * 4 + g];
    B2[ct] = bf[(2 * 1024 + col) * 4 + g];
    B3[ct] = bf[(3 * 1024 + col) * 4 + g];
  }

  float m[4] = {-1e30f, -1e30f, -1e30f, -1e30f};
  size_t abase = ((size_t)rowchunk * 256 + lr) * 64 + g * 8;
  for (int t = 0; t < 16; ++t) {
    size_t o = abase + (size_t)t * 16 * 64;
    short8 ah0 = *(const short8*)(Ahi + o);
    short8 ah1 = *(const short8*)(Ahi + o + 32);
    short8 al0 = *(const short8*)(Alo + o);
    short8 al1 = *(const short8*)(Alo + o + 32);
#pragma unroll
    for (int ct = 0; ct < 4; ++ct) {
      f32x4 acc = {0.f, 0.f, 0.f, 0.f};
      acc = __builtin_amdgcn_mfma_f32_16x16x32_bf16(ah0, B0[ct], acc, 0, 0, 0);
      acc = __builtin_amdgcn_mfma_f32_16x16x32_bf16(ah1, B1[ct], acc, 0, 0, 0);
      acc = __builtin_amdgcn_mfma_f32_16x16x32_bf16(ah0, B2[ct], acc, 0, 0, 0);
      acc = __builtin_amdgcn_mfma_f32_16x16x32_bf16(ah1, B3[ct], acc, 0, 0, 0);
      acc = __builtin_amdgcn_mfma_f32_16x16x32_bf16(al0, B0[ct], acc, 0, 0, 0);
      acc = __builtin_amdgcn_mfma_f32_16x16x32_bf16(al1, B1[ct], acc, 0, 0, 0);
      m[ct] = fmaxf(m[ct], fmaxf(fmaxf(acc[0], acc[1]), fmaxf(acc[2], acc[3])));
    }
  }
#pragma unroll
  for (int ct = 0; ct < 4; ++ct) {
    float mm = m[ct];
    mm = fmaxf(mm, __shfl_xor(mm, 16));
    mm = fmaxf(mm, __shfl_xor(mm, 32));
    if (g == 0) {
      int col = c0 + ct * 16;
      float v = fmaxf(mm + b3[col], 0.f);
      atomicMax(&gf[shape * 1024 + col], __float_as_uint(v));
    }
  }
}

// ---------------- MLP head ----------------
// grid (J/64, 64): 512 thr = 8 waves; wave s covers K/8; 16-deep load bursts.
__global__ __launch_bounds__(512) void k_fc(const float* __restrict__ in, const float* __restrict__ w,
                                            const float* __restrict__ bias, float* __restrict__ out,
                                            int K, int J) {
  __shared__ float sin_[1024];
  __shared__ float part[8][64];
  int jt = blockIdx.x, bb = blockIdx.y;
  int tid = threadIdx.x, s = tid >> 6, lane = tid & 63;
  for (int i = tid; i < K; i += 512) sin_[i] = in[bb * K + i];
  __syncthreads();
  int j = (jt << 6) + lane;
  int Ks = K >> 3;
  int k0 = s * Ks;
  float acc = 0.f;
  for (int k = 0; k < Ks; k += 16) {
    float wv[16];
#pragma unroll
    for (int u = 0; u < 16; ++u) wv[u] = w[(k0 + k + u) * J + j];
#pragma unroll
    for (int u = 0; u < 16; ++u) acc = fmaf(sin_[k0 + k + u], wv[u], acc);
  }
  part[s][lane] = acc;
  __syncthreads();
  if (tid < 64) {
    float r = bias[(jt << 6) + tid];
#pragma unroll
    for (int u = 0; u < 8; ++u) r += part[u][tid];
    out[bb * J + (jt << 6) + tid] = r;
  }
}

__global__ __launch_bounds__(256) void k_bn(const float* __restrict__ z, const float* __restrict__ g,
                                            const float* __restrict__ bt, float* __restrict__ out, int J) {
  __shared__ float tile[64][64];
  __shared__ float red[4][64];
  __shared__ float sc[64], sh[64];
  int tid = threadIdx.x, s = tid >> 6, lane = tid & 63;
  int j0 = blockIdx.x << 6;
  float psum = 0.f;
#pragma unroll
  for (int r = 0; r < 16; ++r) {
    int row = s * 16 + r;
    float v = z[row * J + j0 + lane];
    tile[row][lane] = v;
    psum += v;
  }
  red[s][lane] = psum;
  __syncthreads();
  if (tid < 64) sc[tid] = (red[0][tid] + red[1][tid] + red[2][tid] + red[3][tid]) * (1.f / 64.f);
  __syncthreads();
  float mean = sc[lane];
  float pv = 0.f;
#pragma unroll
  for (int r = 0; r < 16; ++r) {
    float d = tile[s * 16 + r][lane] - mean;
    pv = fmaf(d, d, pv);
  }
  red[s][lane] = pv;
  __syncthreads();
  if (tid < 64) {
    float var = (red[0][tid] + red[1][tid] + red[2][tid] + red[3][tid]) * (1.f / 64.f);
    float scale = g[j0 + tid] / sqrtf(var + 1e-5f);
    sh[tid] = bt[j0 + tid] - sc[tid] * scale;
    sc[tid] = scale;
  }
  __syncthreads();
  float scale = sc[lane], shift = sh[lane];
#pragma unroll
  for (int r = 0; r < 16; ++r) {
    int row = s * 16 + r;
    out[row * J + j0 + lane] = fmaxf(fmaf(tile[row][lane], scale, shift), 0.f);
  }
}

__global__ __launch_bounds__(256) void k_head(const float* __restrict__ z, const float* __restrict__ w,
                                              const float* __restrict__ b, float* __restrict__ out) {
  __shared__ float sz[256];
  __shared__ float part[4][64];
  int bb = blockIdx.x, tid = threadIdx.x;
  sz[tid] = z[bb * 256 + tid];
  __syncthreads();
  int s = tid >> 6, j = tid & 63;
  float acc = 0.f;
  if (j < 40) {
#pragma unroll
    for (int k = 0; k < 64; k += 4) {
      int kk = s * 64 + k;
      acc = fmaf(sz[kk + 0], w[(kk + 0) * 40 + j], acc);
      acc = fmaf(sz[kk + 1], w[(kk + 1) * 40 + j], acc);
      acc = fmaf(sz[kk + 2], w[(kk + 2) * 40 + j], acc);
      acc = fmaf(sz[kk + 3], w[(kk + 3) * 40 + j], acc);
    }
  }
  part[s][j] = acc;
  __syncthreads();
  if (tid < 64) {
    float v = (j < 40) ? part[0][j] + part[1][j] + part[2][j] + part[3][j] + b[j] : -INFINITY;
    float m = v;
    for (int d = 32; d > 0; d >>= 1) m = fmaxf(m, __shfl_xor(m, d));
    float e = (j < 40) ? expf(v - m) : 0.f;
    for (int d = 32; d > 0; d >>= 1) e += __shfl_xor(e, d);
    if (j < 40) out[bb * 40 + j] = v - m - logf(e);
  }
}

extern "C" void kernel_launch(void* const* d_in, const int* in_sizes, int n_in,
                              void* d_out, int out_size, void* d_ws, size_t ws_size,
                              hipStream_t stream) {
  (void)in_sizes; (void)n_in; (void)out_size; (void)ws_size;
  const float* x    = (const float*)d_in[0];
  const int*   esrc = (const int*)d_in[1];
  const int*   edst = (const int*)d_in[2];
  const float* ev   = (const float*)d_in[3];
  const float* gc1w = (const float*)d_in[5];
  const float* gc1b = (const float*)d_in[6];
  const float* gc2w = (const float*)d_in[7];
  const float* gc2b = (const float*)d_in[8];
  const float* gc3w = (const float*)d_in[9];
  const float* gc3b = (const float*)d_in[10];
  const float* fc1w = (const float*)d_in[11];
  const float* fc1b = (const float*)d_in[12];
  const float* bn1g = (const float*)d_in[13];
  const float* bn1b = (const float*)d_in[14];
  const float* fc2w = (const float*)d_in[15];
  const float* fc2b = (const float*)d_in[16];
  const float* bn2g = (const float*)d_in[17];
  const float* bn2b = (const float*)d_in[18];
  const float* fc3w = (const float*)d_in[19];
  const float* fc3b = (const float*)d_in[20];

  char* ws = (char*)d_ws;
  size_t o = 0;
  auto alloc = [&](size_t bytes) -> void* {
    void* p = ws + o;
    o += (bytes + 255) & ~(size_t)255;
    return p;
  };
  int*   off  = (int*)alloc((size_t)(NN + 1) * 4);
  int*   gcur = (int*)alloc(64 * 4);
  int2*  pack = (int2*)alloc((size_t)NE * 8);
  float* aggx = (float*)alloc((size_t)NN * 3 * 4);
  float4* x4  = (float4*)alloc((size_t)NN * 16);
  float* bufA = (float*)alloc((size_t)NN * 64 * 4);  // ebin head; h1/h2 bf16
  float* bufB = (float*)alloc((size_t)NN * 64 * 4);  // ebin tail; Ahi/Alo
  int4*  ebin = (int4*)bufA;                         // 64*CAP*16 = 17.8 MB, dead before gemm1
  unsigned short* h1_16 = (unsigned short*)bufA;            // 8 MB
  unsigned short* h2_16 = (unsigned short*)((char*)bufA + NN * 64 * 2);  // 8 MB (second half)
  unsigned short* Ahi = (unsigned short*)bufB;              // 8 MB
  unsigned short* Alo = (unsigned short*)(bufB + NN * 32);  // 8 MB
  unsigned short* Bfrag = (unsigned short*)alloc(4 * 1024 * 32 * 2);  // 256 KB
  float* gf   = (float*)alloc(64 * 1024 * 4);
  float* z1   = (float*)alloc(64 * 512 * 4);
  float* z1n  = (float*)alloc(64 * 512 * 4);
  float* z2   = (float*)alloc(64 * 256 * 4);
  float* z2n  = (float*)alloc(64 * 256 * 4);

  hipMemsetAsync(gcur, 0, 64 * 4, stream);
  hipMemsetAsync(gf, 0, 64 * 1024 * 4, stream);

  // CSR build: 2-pass shape-bucketed
  k_bin<<<NE / 4096, 256, 0, stream>>>(esrc, edst, ev, gcur, ebin);
  k_csr<<<64, 256, 0, stream>>>(gcur, ebin, off, pack);
  k_prepw<<<512, 256, 0, stream>>>(gc3w, Bfrag);
  k_packx<<<NN / 256, 256, 0, stream>>>(x, x4);

  // layer 1  (gemm1 writes h1 into bufA after ebin is dead)
  k_aggx<<<NN / 256, 256, 0, stream>>>(off, pack, x4, aggx);
  k_gemm1<<<(NN * 64) / 256, 256, 0, stream>>>(aggx, gc1w, gc1b, h1_16);

  // layer 2 fused: agg(h1) @ W2 + b2, relu -> h2 bf16
  k_agg64g2<<<NN / 8, 256, 0, stream>>>(off, pack, h1_16, gc2w, gc2b, h2_16);

  // layer 3: aggregate bf16 h2 -> split-bf16 planes, then MFMA GEMM + maxpool
  k_agg64_split<<<NN / 8, 256, 0, stream>>>(off, pack, h2_16, Ahi, Alo);
  k_gemm3max<<<512, 512, 0, stream>>>(Ahi, Alo, Bfrag, gc3b, (unsigned*)gf);

  // MLP head
  k_fc<<<dim3(8, 64), 512, 0, stream>>>(gf, fc1w, fc1b, z1, 1024, 512);
  k_bn<<<8, 256, 0, stream>>>(z1, bn1g, bn1b, z1n, 512);
  k_fc<<<dim3(4, 64), 512, 0, stream>>>(z1n, fc2w, fc2b, z2, 512, 256);
  k_bn<<<4, 256, 0, stream>>>(z2, bn2g, bn2b, z2n, 256);
  k_head<<<64, 256, 0, stream>>>(z2n, fc3w, fc3b, (float*)d_out);
}

// Round 9
// 192.667 us; speedup vs baseline: 4.0056x; 1.1349x over previous
//
#include <hip/hip_runtime.h>
#include <math.h>

#define NN 65536
#define NE 1048576
#define CAP 17408  // per-bucket capacity: mean 16384, sd ~127, 8-sigma slack

typedef __attribute__((ext_vector_type(8))) short short8;
typedef __attribute__((ext_vector_type(4))) float f32x4;

__device__ inline unsigned short f2bf(float f) {
  unsigned u = __float_as_uint(f);
  unsigned r = u + 0x7fff + ((u >> 16) & 1);  // RNE
  return (unsigned short)(r >> 16);
}
__device__ inline float bf2f(unsigned short h) { return __uint_as_float(((unsigned)h) << 16); }

// ---------------- CSR build, pass 1: bin edges by shape (dst>>10), 8B records ----------------
__global__ __launch_bounds__(256) void k_bin(const int* __restrict__ src, const int* __restrict__ dst,
                                             const float* __restrict__ val, int* __restrict__ gcur,
                                             uint2* __restrict__ ebin) {
  __shared__ int cnt[64], base[64];
  int tid = threadIdx.x;
  if (tid < 64) cnt[tid] = 0;
  __syncthreads();
  int e0 = blockIdx.x * 4096;
  int rsrc[16], rdst[16], rrank[16];
  float rval[16];
#pragma unroll
  for (int i = 0; i < 16; ++i) {
    int e = e0 + i * 256 + tid;
    rsrc[i] = src[e];
    rdst[i] = dst[e];
    rval[i] = val[e];
    rrank[i] = atomicAdd(&cnt[rdst[i] >> 10], 1);
  }
  __syncthreads();
  if (tid < 64) base[tid] = atomicAdd(&gcur[tid], cnt[tid]);
  __syncthreads();
#pragma unroll
  for (int i = 0; i < 16; ++i) {
    int b = rdst[i] >> 10;
    ebin[b * CAP + base[b] + rrank[i]] =
        make_uint2((unsigned)rsrc[i] | ((unsigned)(rdst[i] & 1023) << 16), (unsigned)__float_as_int(rval[i]));
  }
}

// ---------------- CSR build, pass 2: per-bucket local CSR, 1024 threads/block ----------------
__global__ __launch_bounds__(1024) void k_csr(const int* __restrict__ gcnt, const uint2* __restrict__ ebin,
                                              int* __restrict__ off, int2* __restrict__ pack) {
  __shared__ int lcnt[1024], lcur[1024], part[1024];
  int b = blockIdx.x, tid = threadIdx.x;
  int count = gcnt[b];
  int gbase = 0;
  for (int i = 0; i < b; ++i) gbase += gcnt[i];
  lcnt[tid] = 0;
  __syncthreads();
  const uint2* eb = ebin + (size_t)b * CAP;
  // histogram over local dst, 4-deep batched loads
  for (int i0 = 0; i0 < count; i0 += 4096) {
    unsigned xs[4];
#pragma unroll
    for (int u = 0; u < 4; ++u) {
      int i = i0 + u * 1024 + tid;
      xs[u] = eb[min(i, count - 1)].x;
    }
#pragma unroll
    for (int u = 0; u < 4; ++u) {
      int i = i0 + u * 1024 + tid;
      if (i < count) atomicAdd(&lcnt[(xs[u] >> 16) & 1023], 1);
    }
  }
  __syncthreads();
  int s = lcnt[tid];
  part[tid] = s;
  __syncthreads();
  for (int d = 1; d < 1024; d <<= 1) {
    int v = (tid >= d) ? part[tid - d] : 0;
    __syncthreads();
    part[tid] += v;
    __syncthreads();
  }
  int o0 = part[tid] - s;  // exclusive prefix
  lcur[tid] = o0;
  off[b * 1024 + tid] = gbase + o0;
  if (b == 63 && tid == 1023) off[NN] = gbase + count;
  __syncthreads();
  // placement, 4-deep batched loads
  for (int i0 = 0; i0 < count; i0 += 4096) {
    uint2 es[4];
#pragma unroll
    for (int u = 0; u < 4; ++u) {
      int i = i0 + u * 1024 + tid;
      es[u] = eb[min(i, count - 1)];
    }
#pragma unroll
    for (int u = 0; u < 4; ++u) {
      int i = i0 + u * 1024 + tid;
      if (i < count) {
        int ld = (es[u].x >> 16) & 1023;
        int p = atomicAdd(&lcur[ld], 1);
        pack[gbase + p] = make_int2((int)(es[u].x & 0xffffu), (int)es[u].y);
      }
    }
  }
}

// ---------------- GCN layer 1 ----------------
__global__ __launch_bounds__(256) void k_packx(const float* __restrict__ x, float4* __restrict__ x4) {
  int n = blockIdx.x * 256 + threadIdx.x;
  x4[n] = make_float4(x[3 * n], x[3 * n + 1], x[3 * n + 2], 0.f);
}

// thread per node, 8-deep gather pipeline
__global__ __launch_bounds__(256) void k_aggx(const int* __restrict__ off, const int2* __restrict__ pack,
                                              const float4* __restrict__ x4, float* __restrict__ aggx) {
  int n = blockIdx.x * 256 + threadIdx.x;
  int i0 = off[n], e = off[n + 1];
  int deg = e - i0;
  float a0 = 0.f, a1 = 0.f, a2 = 0.f;
  for (int b = 0; b < deg; b += 8) {
    int2 ed[8];
    float4 q[8];
#pragma unroll
    for (int u = 0; u < 8; ++u) ed[u] = pack[min(i0 + b + u, e - 1)];
#pragma unroll
    for (int u = 0; u < 8; ++u) q[u] = x4[ed[u].x];
#pragma unroll
    for (int u = 0; u < 8; ++u) {
      float v = (b + u < deg) ? __int_as_float(ed[u].y) : 0.f;
      a0 = fmaf(v, q[u].x, a0);
      a1 = fmaf(v, q[u].y, a1);
      a2 = fmaf(v, q[u].z, a2);
    }
  }
  aggx[n * 3 + 0] = a0;
  aggx[n * 3 + 1] = a1;
  aggx[n * 3 + 2] = a2;
}

__global__ __launch_bounds__(256) void k_gemm1(const float* __restrict__ aggx, const float* __restrict__ w,
                                               const float* __restrict__ b, unsigned short* __restrict__ out) {
  __shared__ float sw[256];
  int t = threadIdx.x;
  sw[t] = (t < 192) ? w[t] : b[t - 192];
  __syncthreads();
  int g = blockIdx.x * 256 + t;
  int n = g >> 6, j = g & 63;
  float a0 = aggx[n * 3], a1 = aggx[n * 3 + 1], a2 = aggx[n * 3 + 2];
  float r = sw[192 + j];
  r = fmaf(a0, sw[j], r);
  r = fmaf(a1, sw[64 + j], r);
  r = fmaf(a2, sw[128 + j], r);
  out[g] = f2bf(fmaxf(r, 0.f));
}

// ---------------- fused layer-2: agg(h1) -> @W2+b2, relu -> h2 bf16 ----------------
// 2 nodes per wave, 2 features per lane (uint = 2xbf16 per gather); W2 in LDS.
__global__ __launch_bounds__(256) void k_agg64g2(const int* __restrict__ off, const int2* __restrict__ pack,
                                                 const unsigned short* __restrict__ h,
                                                 const float* __restrict__ w2, const float* __restrict__ b2,
                                                 unsigned short* __restrict__ out) {
  __shared__ float sw[64][64];    // sw[k][j]
  __shared__ float rows[8][64];
  int tid = threadIdx.x;
  int lane = tid & 63, wv = tid >> 6;
  for (int t = tid; t < 1024; t += 256) ((float4*)sw)[t] = ((const float4*)w2)[t];
  __syncthreads();
  int half = lane >> 5, fl = lane & 31;
  int n = blockIdx.x * 8 + wv * 2 + half;
  int i0 = off[n], e = off[n + 1];
  int deg = e - i0;
  const unsigned* h32 = (const unsigned*)h;
  float l0 = 0.f, l1 = 0.f, h0 = 0.f, h1 = 0.f;
  for (int b = 0; b < deg; b += 8) {
    int2 ed[8];
    unsigned hv[8];
#pragma unroll
    for (int u = 0; u < 8; ++u) ed[u] = pack[min(i0 + b + u, e - 1)];
#pragma unroll
    for (int u = 0; u < 8; ++u) hv[u] = h32[(size_t)ed[u].x * 32 + fl];
#pragma unroll
    for (int u = 0; u < 8; ++u) {
      float v = (b + u < deg) ? __int_as_float(ed[u].y) : 0.f;
      float flo = __uint_as_float(hv[u] << 16);
      float fhi = __uint_as_float(hv[u] & 0xffff0000u);
      if (u & 1) { l1 = fmaf(v, flo, l1); h1 = fmaf(v, fhi, h1); }
      else       { l0 = fmaf(v, flo, l0); h0 = fmaf(v, fhi, h0); }
    }
  }
  // lane holds feats 2fl, 2fl+1 of its node; write row (same-wave LDS dependence)
  ((float2*)rows[wv * 2 + half])[fl] = make_float2(l0 + l1, h0 + h1);
  int nA = blockIdx.x * 8 + wv * 2;
  float bb = b2[lane];
  float accA = bb, accB = bb;
  const float4* ra = (const float4*)rows[wv * 2];
  const float4* rb = (const float4*)rows[wv * 2 + 1];
#pragma unroll
  for (int kk = 0; kk < 16; ++kk) {
    float4 qa = ra[kk];
    float4 qb = rb[kk];
    accA = fmaf(qa.x, sw[4 * kk + 0][lane], accA);
    accB = fmaf(qb.x, sw[4 * kk + 0][lane], accB);
    accA = fmaf(qa.y, sw[4 * kk + 1][lane], accA);
    accB = fmaf(qb.y, sw[4 * kk + 1][lane], accB);
    accA = fmaf(qa.z, sw[4 * kk + 2][lane], accA);
    accB = fmaf(qb.z, sw[4 * kk + 2][lane], accB);
    accA = fmaf(qa.w, sw[4 * kk + 3][lane], accA);
    accB = fmaf(qb.w, sw[4 * kk + 3][lane], accB);
  }
  out[(size_t)nA * 64 + lane] = f2bf(fmaxf(accA, 0.f));
  out[(size_t)(nA + 1) * 64 + lane] = f2bf(fmaxf(accB, 0.f));
}

// 64-feature aggregation -> split-bf16 planes; 2 nodes/wave, 2 feats/lane
__global__ __launch_bounds__(256) void k_agg64_split(const int* __restrict__ off, const int2* __restrict__ pack,
                                                     const unsigned short* __restrict__ h,
                                                     unsigned short* __restrict__ hi,
                                                     unsigned short* __restrict__ lo) {
  int tid = threadIdx.x;
  int lane = tid & 63, wv = tid >> 6;
  int half = lane >> 5, fl = lane & 31;
  int n = blockIdx.x * 8 + wv * 2 + half;
  int i0 = off[n], e = off[n + 1];
  int deg = e - i0;
  const unsigned* h32 = (const unsigned*)h;
  float l0 = 0.f, l1 = 0.f, h0 = 0.f, h1 = 0.f;
  for (int b = 0; b < deg; b += 8) {
    int2 ed[8];
    unsigned hv[8];
#pragma unroll
    for (int u = 0; u < 8; ++u) ed[u] = pack[min(i0 + b + u, e - 1)];
#pragma unroll
    for (int u = 0; u < 8; ++u) hv[u] = h32[(size_t)ed[u].x * 32 + fl];
#pragma unroll
    for (int u = 0; u < 8; ++u) {
      float v = (b + u < deg) ? __int_as_float(ed[u].y) : 0.f;
      float flo = __uint_as_float(hv[u] << 16);
      float fhi = __uint_as_float(hv[u] & 0xffff0000u);
      if (u & 1) { l1 = fmaf(v, flo, l1); h1 = fmaf(v, fhi, h1); }
      else       { l0 = fmaf(v, flo, l0); h0 = fmaf(v, fhi, h0); }
    }
  }
  float accLo = l0 + l1, accHi = h0 + h1;  // feats 2fl, 2fl+1
  unsigned short hA = f2bf(accLo), hB = f2bf(accHi);
  unsigned short lA = f2bf(accLo - bf2f(hA)), lB = f2bf(accHi - bf2f(hB));
  ((unsigned*)hi)[(size_t)n * 32 + fl] = (unsigned)hA | ((unsigned)hB << 16);
  ((unsigned*)lo)[(size_t)n * 32 + fl] = (unsigned)lA | ((unsigned)lB << 16);
}

// ---------------- W3 prep: split-bf16, MFMA-fragment order ----------------
__global__ __launch_bounds__(256) void k_prepw(const float* __restrict__ w3, unsigned short* __restrict__ bfrag) {
  int t = blockIdx.x * 256 + threadIdx.x;  // 131072 total
  int e = t & 7, g = (t >> 3) & 3, col = (t >> 5) & 1023, q = t >> 15;
  int k = (q & 1) * 32 + g * 8 + e;
  float v = w3[k * 1024 + col];
  unsigned short hv = f2bf(v);
  bfrag[t] = (q < 2) ? hv : f2bf(v - bf2f(hv));
}

// ---------------- GCN layer 3 GEMM + maxpool via MFMA (split-bf16) ----------------
__global__ __launch_bounds__(512) void k_gemm3max(const unsigned short* __restrict__ Ahi,
                                                  const unsigned short* __restrict__ Alo,
                                                  const unsigned short* __restrict__ Bfrag,
                                                  const float* __restrict__ b3,
                                                  unsigned* __restrict__ gf) {
  int b = blockIdx.x;
  int colhalf = b & 1, rowchunk = b >> 1;  // rowchunk 0..255 (256 rows each)
  int shape = rowchunk >> 2;
  int tid = threadIdx.x;
  int wv = tid >> 6, l = tid & 63;
  int g = l >> 4, lr = l & 15;

  const short8* bf = (const short8*)Bfrag;
  int c0 = colhalf * 512 + wv * 64 + lr;
  short8 B0[4], B1[4], B2[4], B3[4];
#pragma unroll
  for (int ct = 0; ct < 4; ++ct) {
    int col = c0 + ct * 16;
    B0[ct] = bf[(0 * 1024 + col) * 4 + g];
    B1[ct] = bf[(1 * 1024 + col) * 4 + g];
    B2[ct] = bf[(2 * 1024 + col) * 4 + g];
    B3[ct] = bf[(3 * 1024 + col) * 4 + g];
  }

  float m[4] = {-1e30f, -1e30f, -1e30f, -1e30f};
  size_t abase = ((size_t)rowchunk * 256 + lr) * 64 + g * 8;
  for (int t = 0; t < 16; ++t) {
    size_t o = abase + (size_t)t * 16 * 64;
    short8 ah0 = *(const short8*)(Ahi + o);
    short8 ah1 = *(const short8*)(Ahi + o + 32);
    short8 al0 = *(const short8*)(Alo + o);
    short8 al1 = *(const short8*)(Alo + o + 32);
#pragma unroll
    for (int ct = 0; ct < 4; ++ct) {
      f32x4 acc = {0.f, 0.f, 0.f, 0.f};
      acc = __builtin_amdgcn_mfma_f32_16x16x32_bf16(ah0, B0[ct], acc, 0, 0, 0);
      acc = __builtin_amdgcn_mfma_f32_16x16x32_bf16(ah1, B1[ct], acc, 0, 0, 0);
      acc = __builtin_amdgcn_mfma_f32_16x16x32_bf16(ah0, B2[ct], acc, 0, 0, 0);
      acc = __builtin_amdgcn_mfma_f32_16x16x32_bf16(ah1, B3[ct], acc, 0, 0, 0);
      acc = __builtin_amdgcn_mfma_f32_16x16x32_bf16(al0, B0[ct], acc, 0, 0, 0);
      acc = __builtin_amdgcn_mfma_f32_16x16x32_bf16(al1, B1[ct], acc, 0, 0, 0);
      m[ct] = fmaxf(m[ct], fmaxf(fmaxf(acc[0], acc[1]), fmaxf(acc[2], acc[3])));
    }
  }
#pragma unroll
  for (int ct = 0; ct < 4; ++ct) {
    float mm = m[ct];
    mm = fmaxf(mm, __shfl_xor(mm, 16));
    mm = fmaxf(mm, __shfl_xor(mm, 32));
    if (g == 0) {
      int col = c0 + ct * 16;
      float v = fmaxf(mm + b3[col], 0.f);
      atomicMax(&gf[shape * 1024 + col], __float_as_uint(v));
    }
  }
}

// ---------------- MLP head ----------------
// grid (J/64, 64): 512 thr = 8 waves; wave s covers K/8; 16-deep load bursts.
__global__ __launch_bounds__(512) void k_fc(const float* __restrict__ in, const float* __restrict__ w,
                                            const float* __restrict__ bias, float* __restrict__ out,
                                            int K, int J) {
  __shared__ float sin_[1024];
  __shared__ float part[8][64];
  int jt = blockIdx.x, bb = blockIdx.y;
  int tid = threadIdx.x, s = tid >> 6, lane = tid & 63;
  for (int i = tid; i < K; i += 512) sin_[i] = in[bb * K + i];
  __syncthreads();
  int j = (jt << 6) + lane;
  int Ks = K >> 3;
  int k0 = s * Ks;
  float acc = 0.f;
  for (int k = 0; k < Ks; k += 16) {
    float wv[16];
#pragma unroll
    for (int u = 0; u < 16; ++u) wv[u] = w[(k0 + k + u) * J + j];
#pragma unroll
    for (int u = 0; u < 16; ++u) acc = fmaf(sin_[k0 + k + u], wv[u], acc);
  }
  part[s][lane] = acc;
  __syncthreads();
  if (tid < 64) {
    float r = bias[(jt << 6) + tid];
#pragma unroll
    for (int u = 0; u < 8; ++u) r += part[u][tid];
    out[bb * J + (jt << 6) + tid] = r;
  }
}

__global__ __launch_bounds__(256) void k_bn(const float* __restrict__ z, const float* __restrict__ g,
                                            const float* __restrict__ bt, float* __restrict__ out, int J) {
  __shared__ float tile[64][64];
  __shared__ float red[4][64];
  __shared__ float sc[64], sh[64];
  int tid = threadIdx.x, s = tid >> 6, lane = tid & 63;
  int j0 = blockIdx.x << 6;
  float psum = 0.f;
#pragma unroll
  for (int r = 0; r < 16; ++r) {
    int row = s * 16 + r;
    float v = z[row * J + j0 + lane];
    tile[row][lane] = v;
    psum += v;
  }
  red[s][lane] = psum;
  __syncthreads();
  if (tid < 64) sc[tid] = (red[0][tid] + red[1][tid] + red[2][tid] + red[3][tid]) * (1.f / 64.f);
  __syncthreads();
  float mean = sc[lane];
  float pv = 0.f;
#pragma unroll
  for (int r = 0; r < 16; ++r) {
    float d = tile[s * 16 + r][lane] - mean;
    pv = fmaf(d, d, pv);
  }
  red[s][lane] = pv;
  __syncthreads();
  if (tid < 64) {
    float var = (red[0][tid] + red[1][tid] + red[2][tid] + red[3][tid]) * (1.f / 64.f);
    float scale = g[j0 + tid] / sqrtf(var + 1e-5f);
    sh[tid] = bt[j0 + tid] - sc[tid] * scale;
    sc[tid] = scale;
  }
  __syncthreads();
  float scale = sc[lane], shift = sh[lane];
#pragma unroll
  for (int r = 0; r < 16; ++r) {
    int row = s * 16 + r;
    out[row * J + j0 + lane] = fmaxf(fmaf(tile[row][lane], scale, shift), 0.f);
  }
}

__global__ __launch_bounds__(256) void k_head(const float* __restrict__ z, const float* __restrict__ w,
                                              const float* __restrict__ b, float* __restrict__ out) {
  __shared__ float sz[256];
  __shared__ float part[4][64];
  int bb = blockIdx.x, tid = threadIdx.x;
  sz[tid] = z[bb * 256 + tid];
  __syncthreads();
  int s = tid >> 6, j = tid & 63;
  float acc = 0.f;
  if (j < 40) {
#pragma unroll
    for (int k = 0; k < 64; k += 4) {
      int kk = s * 64 + k;
      acc = fmaf(sz[kk + 0], w[(kk + 0) * 40 + j], acc);
      acc = fmaf(sz[kk + 1], w[(kk + 1) * 40 + j], acc);
      acc = fmaf(sz[kk + 2], w[(kk + 2) * 40 + j], acc);
      acc = fmaf(sz[kk + 3], w[(kk + 3) * 40 + j], acc);
    }
  }
  part[s][j] = acc;
  __syncthreads();
  if (tid < 64) {
    float v = (j < 40) ? part[0][j] + part[1][j] + part[2][j] + part[3][j] + b[j] : -INFINITY;
    float m = v;
    for (int d = 32; d > 0; d >>= 1) m = fmaxf(m, __shfl_xor(m, d));
    float e = (j < 40) ? expf(v - m) : 0.f;
    for (int d = 32; d > 0; d >>= 1) e += __shfl_xor(e, d);
    if (j < 40) out[bb * 40 + j] = v - m - logf(e);
  }
}

extern "C" void kernel_launch(void* const* d_in, const int* in_sizes, int n_in,
                              void* d_out, int out_size, void* d_ws, size_t ws_size,
                              hipStream_t stream) {
  (void)in_sizes; (void)n_in; (void)out_size; (void)ws_size;
  const float* x    = (const float*)d_in[0];
  const int*   esrc = (const int*)d_in[1];
  const int*   edst = (const int*)d_in[2];
  const float* ev   = (const float*)d_in[3];
  const float* gc1w = (const float*)d_in[5];
  const float* gc1b = (const float*)d_in[6];
  const float* gc2w = (const float*)d_in[7];
  const float* gc2b = (const float*)d_in[8];
  const float* gc3w = (const float*)d_in[9];
  const float* gc3b = (const float*)d_in[10];
  const float* fc1w = (const float*)d_in[11];
  const float* fc1b = (const float*)d_in[12];
  const float* bn1g = (const float*)d_in[13];
  const float* bn1b = (const float*)d_in[14];
  const float* fc2w = (const float*)d_in[15];
  const float* fc2b = (const float*)d_in[16];
  const float* bn2g = (const float*)d_in[17];
  const float* bn2b = (const float*)d_in[18];
  const float* fc3w = (const float*)d_in[19];
  const float* fc3b = (const float*)d_in[20];

  char* ws = (char*)d_ws;
  size_t o = 0;
  auto alloc = [&](size_t bytes) -> void* {
    void* p = ws + o;
    o += (bytes + 255) & ~(size_t)255;
    return p;
  };
  int*   off  = (int*)alloc((size_t)(NN + 1) * 4);
  int*   gcur = (int*)alloc(64 * 4);
  int2*  pack = (int2*)alloc((size_t)NE * 8);
  float* aggx = (float*)alloc((size_t)NN * 3 * 4);
  float4* x4  = (float4*)alloc((size_t)NN * 16);
  float* bufA = (float*)alloc((size_t)NN * 64 * 4);  // ebin; later h1/h2 bf16
  float* bufB = (float*)alloc((size_t)NN * 64 * 4);  // Ahi/Alo
  uint2* ebin = (uint2*)bufA;                        // 64*CAP*8 = 8.9 MB, dead before gemm1
  unsigned short* h1_16 = (unsigned short*)bufA;            // 8 MB
  unsigned short* h2_16 = (unsigned short*)((char*)bufA + NN * 64 * 2);  // 8 MB (second half)
  unsigned short* Ahi = (unsigned short*)bufB;              // 8 MB
  unsigned short* Alo = (unsigned short*)(bufB + NN * 32);  // 8 MB
  unsigned short* Bfrag = (unsigned short*)alloc(4 * 1024 * 32 * 2);  // 256 KB
  float* gf   = (float*)alloc(64 * 1024 * 4);
  float* z1   = (float*)alloc(64 * 512 * 4);
  float* z1n  = (float*)alloc(64 * 512 * 4);
  float* z2   = (float*)alloc(64 * 256 * 4);
  float* z2n  = (float*)alloc(64 * 256 * 4);

  hipMemsetAsync(gcur, 0, 64 * 4, stream);
  hipMemsetAsync(gf, 0, 64 * 1024 * 4, stream);

  // CSR build: 2-pass shape-bucketed
  k_bin<<<NE / 4096, 256, 0, stream>>>(esrc, edst, ev, gcur, ebin);
  k_csr<<<64, 1024, 0, stream>>>(gcur, ebin, off, pack);
  k_prepw<<<512, 256, 0, stream>>>(gc3w, Bfrag);
  k_packx<<<NN / 256, 256, 0, stream>>>(x, x4);

  // layer 1  (gemm1 writes h1 into bufA after ebin is dead)
  k_aggx<<<NN / 256, 256, 0, stream>>>(off, pack, x4, aggx);
  k_gemm1<<<(NN * 64) / 256, 256, 0, stream>>>(aggx, gc1w, gc1b, h1_16);

  // layer 2 fused: agg(h1) @ W2 + b2, relu -> h2 bf16
  k_agg64g2<<<NN / 8, 256, 0, stream>>>(off, pack, h1_16, gc2w, gc2b, h2_16);

  // layer 3: aggregate bf16 h2 -> split-bf16 planes, then MFMA GEMM + maxpool
  k_agg64_split<<<NN / 8, 256, 0, stream>>>(off, pack, h2_16, Ahi, Alo);
  k_gemm3max<<<512, 512, 0, stream>>>(Ahi, Alo, Bfrag, gc3b, (unsigned*)gf);

  // MLP head
  k_fc<<<dim3(8, 64), 512, 0, stream>>>(gf, fc1w, fc1b, z1, 1024, 512);
  k_bn<<<8, 256, 0, stream>>>(z1, bn1g, bn1b, z1n, 512);
  k_fc<<<dim3(4, 64), 512, 0, stream>>>(z1n, fc2w, fc2b, z2, 512, 256);
  k_bn<<<4, 256, 0, stream>>>(z2, bn2g, bn2b, z2n, 256);
  k_head<<<64, 256, 0, stream>>>(z2n, fc3w, fc3b, (float*)d_out);
}

// Round 10
// 175.412 us; speedup vs baseline: 4.3996x; 1.0984x over previous
//
#include <hip/hip_runtime.h>
#include <math.h>

#define NN 65536
#define NE 1048576
#define CAP 17408   // per-bucket ebin capacity (mean 16384 + 8-sigma)
#define PCAP 24576  // per-bucket padded pack capacity (CAP + 7*1024 padding)

typedef __attribute__((ext_vector_type(8))) short short8;
typedef __attribute__((ext_vector_type(4))) float f32x4;

__device__ inline unsigned short f2bf(float f) {
  unsigned u = __float_as_uint(f);
  unsigned r = u + 0x7fff + ((u >> 16) & 1);  // RNE
  return (unsigned short)(r >> 16);
}
__device__ inline float bf2f(unsigned short h) { return __uint_as_float(((unsigned)h) << 16); }

// ---------------- CSR build, pass 1: bin edges by shape (dst>>10), 8B records ----------------
__global__ __launch_bounds__(256) void k_bin(const int* __restrict__ src, const int* __restrict__ dst,
                                             const float* __restrict__ val, int* __restrict__ gcur,
                                             uint2* __restrict__ ebin) {
  __shared__ int cnt[64], base[64];
  int tid = threadIdx.x;
  if (tid < 64) cnt[tid] = 0;
  __syncthreads();
  int e0 = blockIdx.x * 4096;
  int rsrc[16], rdst[16], rrank[16];
  float rval[16];
#pragma unroll
  for (int i = 0; i < 16; ++i) {
    int e = e0 + i * 256 + tid;
    rsrc[i] = src[e];
    rdst[i] = dst[e];
    rval[i] = val[e];
    rrank[i] = atomicAdd(&cnt[rdst[i] >> 10], 1);
  }
  __syncthreads();
  if (tid < 64) base[tid] = atomicAdd(&gcur[tid], cnt[tid]);
  __syncthreads();
#pragma unroll
  for (int i = 0; i < 16; ++i) {
    int b = rdst[i] >> 10;
    ebin[b * CAP + base[b] + rrank[i]] =
        make_uint2((unsigned)rsrc[i] | ((unsigned)(rdst[i] & 1023) << 16), (unsigned)__float_as_int(rval[i]));
  }
}

// ---------------- CSR build, pass 2: per-bucket padded CSR, 1024 threads/block ----------------
// pack entries: (src<<7 = h-row byte offset, val bits); per-node lists padded to x8 with (0,0).
__global__ __launch_bounds__(1024) void k_csr(const int* __restrict__ gcnt, const uint2* __restrict__ ebin,
                                              int2* __restrict__ offdeg, int2* __restrict__ pack) {
  __shared__ int lcnt[1024], lcur[1024], part[1024];
  int b = blockIdx.x, tid = threadIdx.x;
  int count = gcnt[b];
  int gbase = b * PCAP;
  lcnt[tid] = 0;
  __syncthreads();
  const uint2* eb = ebin + (size_t)b * CAP;
  // histogram over local dst, 4-deep batched loads
  for (int i0 = 0; i0 < count; i0 += 4096) {
    unsigned xs[4];
#pragma unroll
    for (int u = 0; u < 4; ++u) {
      int i = i0 + u * 1024 + tid;
      xs[u] = eb[min(i, count - 1)].x;
    }
#pragma unroll
    for (int u = 0; u < 4; ++u) {
      int i = i0 + u * 1024 + tid;
      if (i < count) atomicAdd(&lcnt[(xs[u] >> 16) & 1023], 1);
    }
  }
  __syncthreads();
  int deg = lcnt[tid];
  int pdeg = (deg + 7) & ~7;
  part[tid] = pdeg;
  __syncthreads();
  for (int d = 1; d < 1024; d <<= 1) {
    int v = (tid >= d) ? part[tid - d] : 0;
    __syncthreads();
    part[tid] += v;
    __syncthreads();
  }
  int o0 = part[tid] - pdeg;  // exclusive prefix (padded)
  lcur[tid] = o0;
  offdeg[b * 1024 + tid] = make_int2(gbase + o0, pdeg);
  __syncthreads();
  // placement, 4-deep batched loads
  for (int i0 = 0; i0 < count; i0 += 4096) {
    uint2 es[4];
#pragma unroll
    for (int u = 0; u < 4; ++u) {
      int i = i0 + u * 1024 + tid;
      es[u] = eb[min(i, count - 1)];
    }
#pragma unroll
    for (int u = 0; u < 4; ++u) {
      int i = i0 + u * 1024 + tid;
      if (i < count) {
        int ld = (es[u].x >> 16) & 1023;
        int p = atomicAdd(&lcur[ld], 1);
        pack[gbase + p] = make_int2((int)((es[u].x & 0xffffu) << 7), (int)es[u].y);
      }
    }
  }
  // zero-fill own node's padding (disjoint from placement range)
  int pend = o0 + pdeg;
  for (int p = o0 + deg; p < pend; ++p) pack[gbase + p] = make_int2(0, 0);
}

// ---------------- GCN layer 1 ----------------
__global__ __launch_bounds__(256) void k_packx(const float* __restrict__ x, float4* __restrict__ x4) {
  int n = blockIdx.x * 256 + threadIdx.x;
  x4[n] = make_float4(x[3 * n], x[3 * n + 1], x[3 * n + 2], 0.f);
}

// thread per node, 8-deep gather pipeline, padded edge lists (no clamps)
__global__ __launch_bounds__(256) void k_aggx(const int2* __restrict__ offdeg, const int2* __restrict__ pack,
                                              const float4* __restrict__ x4, float* __restrict__ aggx) {
  int n = blockIdx.x * 256 + threadIdx.x;
  int2 od = offdeg[n];
  int i0 = od.x, pdeg = od.y;
  float a0 = 0.f, a1 = 0.f, a2 = 0.f;
  for (int b = 0; b < pdeg; b += 8) {
    int2 ed[8];
    float4 q[8];
#pragma unroll
    for (int u = 0; u < 8; ++u) ed[u] = pack[i0 + b + u];
#pragma unroll
    for (int u = 0; u < 8; ++u) q[u] = x4[(unsigned)ed[u].x >> 7];
#pragma unroll
    for (int u = 0; u < 8; ++u) {
      float v = __int_as_float(ed[u].y);
      a0 = fmaf(v, q[u].x, a0);
      a1 = fmaf(v, q[u].y, a1);
      a2 = fmaf(v, q[u].z, a2);
    }
  }
  aggx[n * 3 + 0] = a0;
  aggx[n * 3 + 1] = a1;
  aggx[n * 3 + 2] = a2;
}

__global__ __launch_bounds__(256) void k_gemm1(const float* __restrict__ aggx, const float* __restrict__ w,
                                               const float* __restrict__ b, unsigned short* __restrict__ out) {
  __shared__ float sw[256];
  int t = threadIdx.x;
  sw[t] = (t < 192) ? w[t] : b[t - 192];
  __syncthreads();
  int g = blockIdx.x * 256 + t;
  int n = g >> 6, j = g & 63;
  float a0 = aggx[n * 3], a1 = aggx[n * 3 + 1], a2 = aggx[n * 3 + 2];
  float r = sw[192 + j];
  r = fmaf(a0, sw[j], r);
  r = fmaf(a1, sw[64 + j], r);
  r = fmaf(a2, sw[128 + j], r);
  out[g] = f2bf(fmaxf(r, 0.f));
}

// ---------------- fused layer-2: agg(h1) -> @W2+b2, relu -> h2 bf16 ----------------
// 4 nodes/wave, 4 feats/lane (dwordx2 gather); padded lists; W2 in LDS.
__global__ __launch_bounds__(256) void k_agg64g2(const int2* __restrict__ offdeg, const int2* __restrict__ pack,
                                                 const unsigned short* __restrict__ h,
                                                 const float* __restrict__ w2, const float* __restrict__ b2,
                                                 unsigned short* __restrict__ out) {
  __shared__ float sw[64][64];    // sw[k][j]
  __shared__ float rows[16][64];
  int tid = threadIdx.x;
  int lane = tid & 63, wv = tid >> 6;
  for (int t = tid; t < 1024; t += 256) ((float4*)sw)[t] = ((const float4*)w2)[t];
  __syncthreads();
  int q = lane >> 4, fl = lane & 15;  // node quarter, feat group (feats 4fl..4fl+3)
  int n = blockIdx.x * 16 + wv * 4 + q;
  int2 od = offdeg[n];
  int i0 = od.x, pdeg = od.y;
  const char* hb = (const char*)h;
  unsigned fo = (unsigned)(fl << 3);
  float c0 = 0.f, c1 = 0.f, c2 = 0.f, c3 = 0.f;
  for (int b = 0; b < pdeg; b += 8) {
    int2 ed[8];
    uint2 hv[8];
#pragma unroll
    for (int u = 0; u < 8; ++u) ed[u] = pack[i0 + b + u];
#pragma unroll
    for (int u = 0; u < 8; ++u) hv[u] = *(const uint2*)(hb + ((unsigned)ed[u].x + fo));
#pragma unroll
    for (int u = 0; u < 8; ++u) {
      float v = __int_as_float(ed[u].y);
      c0 = fmaf(v, __uint_as_float(hv[u].x << 16), c0);
      c1 = fmaf(v, __uint_as_float(hv[u].x & 0xffff0000u), c1);
      c2 = fmaf(v, __uint_as_float(hv[u].y << 16), c2);
      c3 = fmaf(v, __uint_as_float(hv[u].y & 0xffff0000u), c3);
    }
  }
  ((float4*)rows[wv * 4 + q])[fl] = make_float4(c0, c1, c2, c3);
  // tail GEMM: wave computes its 4 nodes x 64 outputs (same-wave LDS dependence)
  int nA = blockIdx.x * 16 + wv * 4;
  float bb = b2[lane];
  float aA = bb, aB = bb, aC = bb, aD = bb;
  const float4* rA = (const float4*)rows[wv * 4 + 0];
  const float4* rB = (const float4*)rows[wv * 4 + 1];
  const float4* rC = (const float4*)rows[wv * 4 + 2];
  const float4* rD = (const float4*)rows[wv * 4 + 3];
#pragma unroll
  for (int kk = 0; kk < 16; ++kk) {
    float4 qa = rA[kk], qb = rB[kk], qc = rC[kk], qd = rD[kk];
    float w0 = sw[4 * kk + 0][lane], w1 = sw[4 * kk + 1][lane];
    float w2v = sw[4 * kk + 2][lane], w3v = sw[4 * kk + 3][lane];
    aA = fmaf(qa.x, w0, aA); aB = fmaf(qb.x, w0, aB); aC = fmaf(qc.x, w0, aC); aD = fmaf(qd.x, w0, aD);
    aA = fmaf(qa.y, w1, aA); aB = fmaf(qb.y, w1, aB); aC = fmaf(qc.y, w1, aC); aD = fmaf(qd.y, w1, aD);
    aA = fmaf(qa.z, w2v, aA); aB = fmaf(qb.z, w2v, aB); aC = fmaf(qc.z, w2v, aC); aD = fmaf(qd.z, w2v, aD);
    aA = fmaf(qa.w, w3v, aA); aB = fmaf(qb.w, w3v, aB); aC = fmaf(qc.w, w3v, aC); aD = fmaf(qd.w, w3v, aD);
  }
  out[(size_t)(nA + 0) * 64 + lane] = f2bf(fmaxf(aA, 0.f));
  out[(size_t)(nA + 1) * 64 + lane] = f2bf(fmaxf(aB, 0.f));
  out[(size_t)(nA + 2) * 64 + lane] = f2bf(fmaxf(aC, 0.f));
  out[(size_t)(nA + 3) * 64 + lane] = f2bf(fmaxf(aD, 0.f));
}

// 64-feature aggregation -> split-bf16 planes; 4 nodes/wave, 4 feats/lane, padded
__global__ __launch_bounds__(256) void k_agg64_split(const int2* __restrict__ offdeg, const int2* __restrict__ pack,
                                                     const unsigned short* __restrict__ h,
                                                     unsigned short* __restrict__ hi,
                                                     unsigned short* __restrict__ lo) {
  int tid = threadIdx.x;
  int lane = tid & 63, wv = tid >> 6;
  int q = lane >> 4, fl = lane & 15;
  int n = blockIdx.x * 16 + wv * 4 + q;
  int2 od = offdeg[n];
  int i0 = od.x, pdeg = od.y;
  const char* hb = (const char*)h;
  unsigned fo = (unsigned)(fl << 3);
  float c0 = 0.f, c1 = 0.f, c2 = 0.f, c3 = 0.f;
  for (int b = 0; b < pdeg; b += 8) {
    int2 ed[8];
    uint2 hv[8];
#pragma unroll
    for (int u = 0; u < 8; ++u) ed[u] = pack[i0 + b + u];
#pragma unroll
    for (int u = 0; u < 8; ++u) hv[u] = *(const uint2*)(hb + ((unsigned)ed[u].x + fo));
#pragma unroll
    for (int u = 0; u < 8; ++u) {
      float v = __int_as_float(ed[u].y);
      c0 = fmaf(v, __uint_as_float(hv[u].x << 16), c0);
      c1 = fmaf(v, __uint_as_float(hv[u].x & 0xffff0000u), c1);
      c2 = fmaf(v, __uint_as_float(hv[u].y << 16), c2);
      c3 = fmaf(v, __uint_as_float(hv[u].y & 0xffff0000u), c3);
    }
  }
  unsigned short h0 = f2bf(c0), h1 = f2bf(c1), h2 = f2bf(c2), h3 = f2bf(c3);
  unsigned short l0 = f2bf(c0 - bf2f(h0)), l1 = f2bf(c1 - bf2f(h1));
  unsigned short l2 = f2bf(c2 - bf2f(h2)), l3 = f2bf(c3 - bf2f(h3));
  ((uint2*)hi)[(size_t)n * 16 + fl] = make_uint2((unsigned)h0 | ((unsigned)h1 << 16), (unsigned)h2 | ((unsigned)h3 << 16));
  ((uint2*)lo)[(size_t)n * 16 + fl] = make_uint2((unsigned)l0 | ((unsigned)l1 << 16), (unsigned)l2 | ((unsigned)l3 << 16));
}

// ---------------- W3 prep: split-bf16, MFMA-fragment order ----------------
__global__ __launch_bounds__(256) void k_prepw(const float* __restrict__ w3, unsigned short* __restrict__ bfrag) {
  int t = blockIdx.x * 256 + threadIdx.x;  // 131072 total
  int e = t & 7, g = (t >> 3) & 3, col = (t >> 5) & 1023, q = t >> 15;
  int k = (q & 1) * 32 + g * 8 + e;
  float v = w3[k * 1024 + col];
  unsigned short hv = f2bf(v);
  bfrag[t] = (q < 2) ? hv : f2bf(v - bf2f(hv));
}

// ---------------- GCN layer 3 GEMM + maxpool via MFMA (split-bf16) ----------------
__global__ __launch_bounds__(512) void k_gemm3max(const unsigned short* __restrict__ Ahi,
                                                  const unsigned short* __restrict__ Alo,
                                                  const unsigned short* __restrict__ Bfrag,
                                                  const float* __restrict__ b3,
                                                  unsigned* __restrict__ gf) {
  int b = blockIdx.x;
  int colhalf = b & 1, rowchunk = b >> 1;  // rowchunk 0..255 (256 rows each)
  int shape = rowchunk >> 2;
  int tid = threadIdx.x;
  int wv = tid >> 6, l = tid & 63;
  int g = l >> 4, lr = l & 15;

  const short8* bf = (const short8*)Bfrag;
  int c0 = colhalf * 512 + wv * 64 + lr;
  short8 B0[4], B1[4], B2[4], B3[4];
#pragma unroll
  for (int ct = 0; ct < 4; ++ct) {
    int col = c0 + ct * 16;
    B0[ct] = bf[(0 * 1024 + col) * 4 + g];
    B1[ct] = bf[(1 * 1024 + col) * 4 + g];
    B2[ct] = bf[(2 * 1024 + col) * 4 + g];
    B3[ct] = bf[(3 * 1024 + col) * 4 + g];
  }

  float m[4] = {-1e30f, -1e30f, -1e30f, -1e30f};
  size_t abase = ((size_t)rowchunk * 256 + lr) * 64 + g * 8;
  for (int t = 0; t < 16; ++t) {
    size_t o = abase + (size_t)t * 16 * 64;
    short8 ah0 = *(const short8*)(Ahi + o);
    short8 ah1 = *(const short8*)(Ahi + o + 32);
    short8 al0 = *(const short8*)(Alo + o);
    short8 al1 = *(const short8*)(Alo + o + 32);
#pragma unroll
    for (int ct = 0; ct < 4; ++ct) {
      f32x4 acc = {0.f, 0.f, 0.f, 0.f};
      acc = __builtin_amdgcn_mfma_f32_16x16x32_bf16(ah0, B0[ct], acc, 0, 0, 0);
      acc = __builtin_amdgcn_mfma_f32_16x16x32_bf16(ah1, B1[ct], acc, 0, 0, 0);
      acc = __builtin_amdgcn_mfma_f32_16x16x32_bf16(ah0, B2[ct], acc, 0, 0, 0);
      acc = __builtin_amdgcn_mfma_f32_16x16x32_bf16(ah1, B3[ct], acc, 0, 0, 0);
      acc = __builtin_amdgcn_mfma_f32_16x16x32_bf16(al0, B0[ct], acc, 0, 0, 0);
      acc = __builtin_amdgcn_mfma_f32_16x16x32_bf16(al1, B1[ct], acc, 0, 0, 0);
      m[ct] = fmaxf(m[ct], fmaxf(fmaxf(acc[0], acc[1]), fmaxf(acc[2], acc[3])));
    }
  }
#pragma unroll
  for (int ct = 0; ct < 4; ++ct) {
    float mm = m[ct];
    mm = fmaxf(mm, __shfl_xor(mm, 16));
    mm = fmaxf(mm, __shfl_xor(mm, 32));
    if (g == 0) {
      int col = c0 + ct * 16;
      float v = fmaxf(mm + b3[col], 0.f);
      atomicMax(&gf[shape * 1024 + col], __float_as_uint(v));
    }
  }
}

// ---------------- MLP head ----------------
__global__ __launch_bounds__(512) void k_fc(const float* __restrict__ in, const float* __restrict__ w,
                                            const float* __restrict__ bias, float* __restrict__ out,
                                            int K, int J) {
  __shared__ float sin_[1024];
  __shared__ float part[8][64];
  int jt = blockIdx.x, bb = blockIdx.y;
  int tid = threadIdx.x, s = tid >> 6, lane = tid & 63;
  for (int i = tid; i < K; i += 512) sin_[i] = in[bb * K + i];
  __syncthreads();
  int j = (jt << 6) + lane;
  int Ks = K >> 3;
  int k0 = s * Ks;
  float acc = 0.f;
  for (int k = 0; k < Ks; k += 16) {
    float wv[16];
#pragma unroll
    for (int u = 0; u < 16; ++u) wv[u] = w[(k0 + k + u) * J + j];
#pragma unroll
    for (int u = 0; u < 16; ++u) acc = fmaf(sin_[k0 + k + u], wv[u], acc);
  }
  part[s][lane] = acc;
  __syncthreads();
  if (tid < 64) {
    float r = bias[(jt << 6) + tid];
#pragma unroll
    for (int u = 0; u < 8; ++u) r += part[u][tid];
    out[bb * J + (jt << 6) + tid] = r;
  }
}

__global__ __launch_bounds__(256) void k_bn(const float* __restrict__ z, const float* __restrict__ g,
                                            const float* __restrict__ bt, float* __restrict__ out, int J) {
  __shared__ float tile[64][64];
  __shared__ float red[4][64];
  __shared__ float sc[64], sh[64];
  int tid = threadIdx.x, s = tid >> 6, lane = tid & 63;
  int j0 = blockIdx.x << 6;
  float psum = 0.f;
#pragma unroll
  for (int r = 0; r < 16; ++r) {
    int row = s * 16 + r;
    float v = z[row * J + j0 + lane];
    tile[row][lane] = v;
    psum += v;
  }
  red[s][lane] = psum;
  __syncthreads();
  if (tid < 64) sc[tid] = (red[0][tid] + red[1][tid] + red[2][tid] + red[3][tid]) * (1.f / 64.f);
  __syncthreads();
  float mean = sc[lane];
  float pv = 0.f;
#pragma unroll
  for (int r = 0; r < 16; ++r) {
    float d = tile[s * 16 + r][lane] - mean;
    pv = fmaf(d, d, pv);
  }
  red[s][lane] = pv;
  __syncthreads();
  if (tid < 64) {
    float var = (red[0][tid] + red[1][tid] + red[2][tid] + red[3][tid]) * (1.f / 64.f);
    float scale = g[j0 + tid] / sqrtf(var + 1e-5f);
    sh[tid] = bt[j0 + tid] - sc[tid] * scale;
    sc[tid] = scale;
  }
  __syncthreads();
  float scale = sc[lane], shift = sh[lane];
#pragma unroll
  for (int r = 0; r < 16; ++r) {
    int row = s * 16 + r;
    out[row * J + j0 + lane] = fmaxf(fmaf(tile[row][lane], scale, shift), 0.f);
  }
}

__global__ __launch_bounds__(256) void k_head(const float* __restrict__ z, const float* __restrict__ w,
                                              const float* __restrict__ b, float* __restrict__ out) {
  __shared__ float sz[256];
  __shared__ float part[4][64];
  int bb = blockIdx.x, tid = threadIdx.x;
  sz[tid] = z[bb * 256 + tid];
  __syncthreads();
  int s = tid >> 6, j = tid & 63;
  float acc = 0.f;
  if (j < 40) {
#pragma unroll
    for (int k = 0; k < 64; k += 4) {
      int kk = s * 64 + k;
      acc = fmaf(sz[kk + 0], w[(kk + 0) * 40 + j], acc);
      acc = fmaf(sz[kk + 1], w[(kk + 1) * 40 + j], acc);
      acc = fmaf(sz[kk + 2], w[(kk + 2) * 40 + j], acc);
      acc = fmaf(sz[kk + 3], w[(kk + 3) * 40 + j], acc);
    }
  }
  part[s][j] = acc;
  __syncthreads();
  if (tid < 64) {
    float v = (j < 40) ? part[0][j] + part[1][j] + part[2][j] + part[3][j] + b[j] : -INFINITY;
    float m = v;
    for (int d = 32; d > 0; d >>= 1) m = fmaxf(m, __shfl_xor(m, d));
    float e = (j < 40) ? expf(v - m) : 0.f;
    for (int d = 32; d > 0; d >>= 1) e += __shfl_xor(e, d);
    if (j < 40) out[bb * 40 + j] = v - m - logf(e);
  }
}

extern "C" void kernel_launch(void* const* d_in, const int* in_sizes, int n_in,
                              void* d_out, int out_size, void* d_ws, size_t ws_size,
                              hipStream_t stream) {
  (void)in_sizes; (void)n_in; (void)out_size; (void)ws_size;
  const float* x    = (const float*)d_in[0];
  const int*   esrc = (const int*)d_in[1];
  const int*   edst = (const int*)d_in[2];
  const float* ev   = (const float*)d_in[3];
  const float* gc1w = (const float*)d_in[5];
  const float* gc1b = (const float*)d_in[6];
  const float* gc2w = (const float*)d_in[7];
  const float* gc2b = (const float*)d_in[8];
  const float* gc3w = (const float*)d_in[9];
  const float* gc3b = (const float*)d_in[10];
  const float* fc1w = (const float*)d_in[11];
  const float* fc1b = (const float*)d_in[12];
  const float* bn1g = (const float*)d_in[13];
  const float* bn1b = (const float*)d_in[14];
  const float* fc2w = (const float*)d_in[15];
  const float* fc2b = (const float*)d_in[16];
  const float* bn2g = (const float*)d_in[17];
  const float* bn2b = (const float*)d_in[18];
  const float* fc3w = (const float*)d_in[19];
  const float* fc3b = (const float*)d_in[20];

  char* ws = (char*)d_ws;
  size_t o = 0;
  auto alloc = [&](size_t bytes) -> void* {
    void* p = ws + o;
    o += (bytes + 255) & ~(size_t)255;
    return p;
  };
  int2*  offdeg = (int2*)alloc((size_t)NN * 8);
  int*   gcur = (int*)alloc(64 * 4);
  int2*  pack = (int2*)alloc((size_t)64 * PCAP * 8);  // 12.6 MB padded
  float* aggx = (float*)alloc((size_t)NN * 3 * 4);
  float4* x4  = (float4*)alloc((size_t)NN * 16);
  float* bufA = (float*)alloc((size_t)NN * 64 * 4);  // ebin; later h1/h2 bf16
  float* bufB = (float*)alloc((size_t)NN * 64 * 4);  // Ahi/Alo
  uint2* ebin = (uint2*)bufA;                        // 64*CAP*8 = 8.9 MB, dead before gemm1
  unsigned short* h1_16 = (unsigned short*)bufA;            // 8 MB
  unsigned short* h2_16 = (unsigned short*)((char*)bufA + NN * 64 * 2);  // 8 MB (second half)
  unsigned short* Ahi = (unsigned short*)bufB;              // 8 MB
  unsigned short* Alo = (unsigned short*)(bufB + NN * 32);  // 8 MB
  unsigned short* Bfrag = (unsigned short*)alloc(4 * 1024 * 32 * 2);  // 256 KB
  float* gf   = (float*)alloc(64 * 1024 * 4);
  float* z1   = (float*)alloc(64 * 512 * 4);
  float* z1n  = (float*)alloc(64 * 512 * 4);
  float* z2   = (float*)alloc(64 * 256 * 4);
  float* z2n  = (float*)alloc(64 * 256 * 4);

  hipMemsetAsync(gcur, 0, 64 * 4, stream);
  hipMemsetAsync(gf, 0, 64 * 1024 * 4, stream);

  // CSR build: 2-pass shape-bucketed, padded to x8 per node
  k_bin<<<NE / 4096, 256, 0, stream>>>(esrc, edst, ev, gcur, ebin);
  k_csr<<<64, 1024, 0, stream>>>(gcur, ebin, offdeg, pack);
  k_prepw<<<512, 256, 0, stream>>>(gc3w, Bfrag);
  k_packx<<<NN / 256, 256, 0, stream>>>(x, x4);

  // layer 1  (gemm1 writes h1 into bufA after ebin is dead)
  k_aggx<<<NN / 256, 256, 0, stream>>>(offdeg, pack, x4, aggx);
  k_gemm1<<<(NN * 64) / 256, 256, 0, stream>>>(aggx, gc1w, gc1b, h1_16);

  // layer 2 fused: agg(h1) @ W2 + b2, relu -> h2 bf16
  k_agg64g2<<<NN / 16, 256, 0, stream>>>(offdeg, pack, h1_16, gc2w, gc2b, h2_16);

  // layer 3: aggregate bf16 h2 -> split-bf16 planes, then MFMA GEMM + maxpool
  k_agg64_split<<<NN / 16, 256, 0, stream>>>(offdeg, pack, h2_16, Ahi, Alo);
  k_gemm3max<<<512, 512, 0, stream>>>(Ahi, Alo, Bfrag, gc3b, (unsigned*)gf);

  // MLP head
  k_fc<<<dim3(8, 64), 512, 0, stream>>>(gf, fc1w, fc1b, z1, 1024, 512);
  k_bn<<<8, 256, 0, stream>>>(z1, bn1g, bn1b, z1n, 512);
  k_fc<<<dim3(4, 64), 512, 0, stream>>>(z1n, fc2w, fc2b, z2, 512, 256);
  k_bn<<<4, 256, 0, stream>>>(z2, bn2g, bn2b, z2n, 256);
  k_head<<<64, 256, 0, stream>>>(z2n, fc3w, fc3b, (float*)d_out);
}

// Round 11
// 171.933 us; speedup vs baseline: 4.4886x; 1.0202x over previous
//
#include <hip/hip_runtime.h>
#include <math.h>

#define NN 65536
#define NE 1048576
#define CAP 17408   // per-bucket ebin capacity (mean 16384 + 8-sigma)
#define PCAP 24576  // per-bucket padded pack capacity (CAP + 7*1024 padding)

typedef __attribute__((ext_vector_type(8))) short short8;
typedef __attribute__((ext_vector_type(4))) float f32x4;

__device__ inline unsigned short f2bf(float f) {
  unsigned u = __float_as_uint(f);
  unsigned r = u + 0x7fff + ((u >> 16) & 1);  // RNE
  return (unsigned short)(r >> 16);
}
__device__ inline float bf2f(unsigned short h) { return __uint_as_float(((unsigned)h) << 16); }

// ---------------- x packing + gcur zero-init (runs FIRST; same-stream ordering) ----------------
__global__ __launch_bounds__(256) void k_packx(const float* __restrict__ x, float4* __restrict__ x4,
                                               int* __restrict__ gcur) {
  int n = blockIdx.x * 256 + threadIdx.x;
  if (blockIdx.x == 0 && threadIdx.x < 64) gcur[threadIdx.x] = 0;
  x4[n] = make_float4(x[3 * n], x[3 * n + 1], x[3 * n + 2], 0.f);
}

// ---------------- CSR build, pass 1: bin edges by shape (dst>>10), 8B records ----------------
__global__ __launch_bounds__(256) void k_bin(const int* __restrict__ src, const int* __restrict__ dst,
                                             const float* __restrict__ val, int* __restrict__ gcur,
                                             uint2* __restrict__ ebin) {
  __shared__ int cnt[64], base[64];
  int tid = threadIdx.x;
  if (tid < 64) cnt[tid] = 0;
  __syncthreads();
  int e0 = blockIdx.x * 4096;
  int rsrc[16], rdst[16], rrank[16];
  float rval[16];
#pragma unroll
  for (int i = 0; i < 16; ++i) {
    int e = e0 + i * 256 + tid;
    rsrc[i] = src[e];
    rdst[i] = dst[e];
    rval[i] = val[e];
    rrank[i] = atomicAdd(&cnt[rdst[i] >> 10], 1);
  }
  __syncthreads();
  if (tid < 64) base[tid] = atomicAdd(&gcur[tid], cnt[tid]);
  __syncthreads();
#pragma unroll
  for (int i = 0; i < 16; ++i) {
    int b = rdst[i] >> 10;
    ebin[b * CAP + base[b] + rrank[i]] =
        make_uint2((unsigned)rsrc[i] | ((unsigned)(rdst[i] & 1023) << 16), (unsigned)__float_as_int(rval[i]));
  }
}

// ---------------- CSR build, pass 2: per-bucket padded CSR, 1024 threads/block ----------------
// pack entries: (src<<7 = h-row byte offset, val bits); per-node lists padded to x8 with (0,0).
__global__ __launch_bounds__(1024) void k_csr(const int* __restrict__ gcnt, const uint2* __restrict__ ebin,
                                              int2* __restrict__ offdeg, int2* __restrict__ pack) {
  __shared__ int lcnt[1024], lcur[1024], part[1024];
  int b = blockIdx.x, tid = threadIdx.x;
  int count = gcnt[b];
  int gbase = b * PCAP;
  lcnt[tid] = 0;
  __syncthreads();
  const uint2* eb = ebin + (size_t)b * CAP;
  // histogram over local dst, 4-deep batched loads
  for (int i0 = 0; i0 < count; i0 += 4096) {
    unsigned xs[4];
#pragma unroll
    for (int u = 0; u < 4; ++u) {
      int i = i0 + u * 1024 + tid;
      xs[u] = eb[min(i, count - 1)].x;
    }
#pragma unroll
    for (int u = 0; u < 4; ++u) {
      int i = i0 + u * 1024 + tid;
      if (i < count) atomicAdd(&lcnt[(xs[u] >> 16) & 1023], 1);
    }
  }
  __syncthreads();
  int deg = lcnt[tid];
  int pdeg = (deg + 7) & ~7;
  part[tid] = pdeg;
  __syncthreads();
  for (int d = 1; d < 1024; d <<= 1) {
    int v = (tid >= d) ? part[tid - d] : 0;
    __syncthreads();
    part[tid] += v;
    __syncthreads();
  }
  int o0 = part[tid] - pdeg;  // exclusive prefix (padded)
  lcur[tid] = o0;
  offdeg[b * 1024 + tid] = make_int2(gbase + o0, pdeg);
  __syncthreads();
  // placement, 4-deep batched loads
  for (int i0 = 0; i0 < count; i0 += 4096) {
    uint2 es[4];
#pragma unroll
    for (int u = 0; u < 4; ++u) {
      int i = i0 + u * 1024 + tid;
      es[u] = eb[min(i, count - 1)];
    }
#pragma unroll
    for (int u = 0; u < 4; ++u) {
      int i = i0 + u * 1024 + tid;
      if (i < count) {
        int ld = (es[u].x >> 16) & 1023;
        int p = atomicAdd(&lcur[ld], 1);
        pack[gbase + p] = make_int2((int)((es[u].x & 0xffffu) << 7), (int)es[u].y);
      }
    }
  }
  // zero-fill own node's padding (disjoint from placement range)
  int pend = o0 + pdeg;
  for (int p = o0 + deg; p < pend; ++p) pack[gbase + p] = make_int2(0, 0);
}

// thread per node, 8-deep gather pipeline, padded edge lists (no clamps)
__global__ __launch_bounds__(256) void k_aggx(const int2* __restrict__ offdeg, const int2* __restrict__ pack,
                                              const float4* __restrict__ x4, float* __restrict__ aggx) {
  int n = blockIdx.x * 256 + threadIdx.x;
  int2 od = offdeg[n];
  int i0 = od.x, pdeg = od.y;
  float a0 = 0.f, a1 = 0.f, a2 = 0.f;
  for (int b = 0; b < pdeg; b += 8) {
    int2 ed[8];
    float4 q[8];
#pragma unroll
    for (int u = 0; u < 8; ++u) ed[u] = pack[i0 + b + u];
#pragma unroll
    for (int u = 0; u < 8; ++u) q[u] = x4[(unsigned)ed[u].x >> 7];
#pragma unroll
    for (int u = 0; u < 8; ++u) {
      float v = __int_as_float(ed[u].y);
      a0 = fmaf(v, q[u].x, a0);
      a1 = fmaf(v, q[u].y, a1);
      a2 = fmaf(v, q[u].z, a2);
    }
  }
  aggx[n * 3 + 0] = a0;
  aggx[n * 3 + 1] = a1;
  aggx[n * 3 + 2] = a2;
}

__global__ __launch_bounds__(256) void k_gemm1(const float* __restrict__ aggx, const float* __restrict__ w,
                                               const float* __restrict__ b, unsigned short* __restrict__ out) {
  __shared__ float sw[256];
  int t = threadIdx.x;
  sw[t] = (t < 192) ? w[t] : b[t - 192];
  __syncthreads();
  int g = blockIdx.x * 256 + t;
  int n = g >> 6, j = g & 63;
  float a0 = aggx[n * 3], a1 = aggx[n * 3 + 1], a2 = aggx[n * 3 + 2];
  float r = sw[192 + j];
  r = fmaf(a0, sw[j], r);
  r = fmaf(a1, sw[64 + j], r);
  r = fmaf(a2, sw[128 + j], r);
  out[g] = f2bf(fmaxf(r, 0.f));
}

// ---------------- fused layer-2: agg(h1) -> @W2+b2, relu -> h2 bf16 ----------------
// 4 nodes/wave, 4 feats/lane (dwordx2 gather); padded lists; W2 in LDS.
__global__ __launch_bounds__(256) void k_agg64g2(const int2* __restrict__ offdeg, const int2* __restrict__ pack,
                                                 const unsigned short* __restrict__ h,
                                                 const float* __restrict__ w2, const float* __restrict__ b2,
                                                 unsigned short* __restrict__ out) {
  __shared__ float sw[64][64];    // sw[k][j]
  __shared__ float rows[16][64];
  int tid = threadIdx.x;
  int lane = tid & 63, wv = tid >> 6;
  for (int t = tid; t < 1024; t += 256) ((float4*)sw)[t] = ((const float4*)w2)[t];
  __syncthreads();
  int q = lane >> 4, fl = lane & 15;  // node quarter, feat group (feats 4fl..4fl+3)
  int n = blockIdx.x * 16 + wv * 4 + q;
  int2 od = offdeg[n];
  int i0 = od.x, pdeg = od.y;
  const char* hb = (const char*)h;
  unsigned fo = (unsigned)(fl << 3);
  float c0 = 0.f, c1 = 0.f, c2 = 0.f, c3 = 0.f;
  for (int b = 0; b < pdeg; b += 8) {
    int2 ed[8];
    uint2 hv[8];
#pragma unroll
    for (int u = 0; u < 8; ++u) ed[u] = pack[i0 + b + u];
#pragma unroll
    for (int u = 0; u < 8; ++u) hv[u] = *(const uint2*)(hb + ((unsigned)ed[u].x + fo));
#pragma unroll
    for (int u = 0; u < 8; ++u) {
      float v = __int_as_float(ed[u].y);
      c0 = fmaf(v, __uint_as_float(hv[u].x << 16), c0);
      c1 = fmaf(v, __uint_as_float(hv[u].x & 0xffff0000u), c1);
      c2 = fmaf(v, __uint_as_float(hv[u].y << 16), c2);
      c3 = fmaf(v, __uint_as_float(hv[u].y & 0xffff0000u), c3);
    }
  }
  ((float4*)rows[wv * 4 + q])[fl] = make_float4(c0, c1, c2, c3);
  // tail GEMM: wave computes its 4 nodes x 64 outputs (same-wave LDS dependence)
  int nA = blockIdx.x * 16 + wv * 4;
  float bb = b2[lane];
  float aA = bb, aB = bb, aC = bb, aD = bb;
  const float4* rA = (const float4*)rows[wv * 4 + 0];
  const float4* rB = (const float4*)rows[wv * 4 + 1];
  const float4* rC = (const float4*)rows[wv * 4 + 2];
  const float4* rD = (const float4*)rows[wv * 4 + 3];
#pragma unroll
  for (int kk = 0; kk < 16; ++kk) {
    float4 qa = rA[kk], qb = rB[kk], qc = rC[kk], qd = rD[kk];
    float w0 = sw[4 * kk + 0][lane], w1 = sw[4 * kk + 1][lane];
    float w2v = sw[4 * kk + 2][lane], w3v = sw[4 * kk + 3][lane];
    aA = fmaf(qa.x, w0, aA); aB = fmaf(qb.x, w0, aB); aC = fmaf(qc.x, w0, aC); aD = fmaf(qd.x, w0, aD);
    aA = fmaf(qa.y, w1, aA); aB = fmaf(qb.y, w1, aB); aC = fmaf(qc.y, w1, aC); aD = fmaf(qd.y, w1, aD);
    aA = fmaf(qa.z, w2v, aA); aB = fmaf(qb.z, w2v, aB); aC = fmaf(qc.z, w2v, aC); aD = fmaf(qd.z, w2v, aD);
    aA = fmaf(qa.w, w3v, aA); aB = fmaf(qb.w, w3v, aB); aC = fmaf(qc.w, w3v, aC); aD = fmaf(qd.w, w3v, aD);
  }
  out[(size_t)(nA + 0) * 64 + lane] = f2bf(fmaxf(aA, 0.f));
  out[(size_t)(nA + 1) * 64 + lane] = f2bf(fmaxf(aB, 0.f));
  out[(size_t)(nA + 2) * 64 + lane] = f2bf(fmaxf(aC, 0.f));
  out[(size_t)(nA + 3) * 64 + lane] = f2bf(fmaxf(aD, 0.f));
}

// 64-feature aggregation -> split-bf16 planes; 4 nodes/wave, 4 feats/lane, padded
__global__ __launch_bounds__(256) void k_agg64_split(const int2* __restrict__ offdeg, const int2* __restrict__ pack,
                                                     const unsigned short* __restrict__ h,
                                                     unsigned short* __restrict__ hi,
                                                     unsigned short* __restrict__ lo) {
  int tid = threadIdx.x;
  int lane = tid & 63, wv = tid >> 6;
  int q = lane >> 4, fl = lane & 15;
  int n = blockIdx.x * 16 + wv * 4 + q;
  int2 od = offdeg[n];
  int i0 = od.x, pdeg = od.y;
  const char* hb = (const char*)h;
  unsigned fo = (unsigned)(fl << 3);
  float c0 = 0.f, c1 = 0.f, c2 = 0.f, c3 = 0.f;
  for (int b = 0; b < pdeg; b += 8) {
    int2 ed[8];
    uint2 hv[8];
#pragma unroll
    for (int u = 0; u < 8; ++u) ed[u] = pack[i0 + b + u];
#pragma unroll
    for (int u = 0; u < 8; ++u) hv[u] = *(const uint2*)(hb + ((unsigned)ed[u].x + fo));
#pragma unroll
    for (int u = 0; u < 8; ++u) {
      float v = __int_as_float(ed[u].y);
      c0 = fmaf(v, __uint_as_float(hv[u].x << 16), c0);
      c1 = fmaf(v, __uint_as_float(hv[u].x & 0xffff0000u), c1);
      c2 = fmaf(v, __uint_as_float(hv[u].y << 16), c2);
      c3 = fmaf(v, __uint_as_float(hv[u].y & 0xffff0000u), c3);
    }
  }
  unsigned short h0 = f2bf(c0), h1 = f2bf(c1), h2 = f2bf(c2), h3 = f2bf(c3);
  unsigned short l0 = f2bf(c0 - bf2f(h0)), l1 = f2bf(c1 - bf2f(h1));
  unsigned short l2 = f2bf(c2 - bf2f(h2)), l3 = f2bf(c3 - bf2f(h3));
  ((uint2*)hi)[(size_t)n * 16 + fl] = make_uint2((unsigned)h0 | ((unsigned)h1 << 16), (unsigned)h2 | ((unsigned)h3 << 16));
  ((uint2*)lo)[(size_t)n * 16 + fl] = make_uint2((unsigned)l0 | ((unsigned)l1 << 16), (unsigned)l2 | ((unsigned)l3 << 16));
}

// ---------------- W3 prep (split-bf16, MFMA-fragment order) + gf zero-init ----------------
__global__ __launch_bounds__(256) void k_prepw(const float* __restrict__ w3, unsigned short* __restrict__ bfrag,
                                               unsigned* __restrict__ gf) {
  int t = blockIdx.x * 256 + threadIdx.x;  // 131072 total
  if (t < 65536) gf[t] = 0u;
  int e = t & 7, g = (t >> 3) & 3, col = (t >> 5) & 1023, q = t >> 15;
  int k = (q & 1) * 32 + g * 8 + e;
  float v = w3[k * 1024 + col];
  unsigned short hv = f2bf(v);
  bfrag[t] = (q < 2) ? hv : f2bf(v - bf2f(hv));
}

// ---------------- GCN layer 3 GEMM + maxpool via MFMA (split-bf16) ----------------
__global__ __launch_bounds__(512) void k_gemm3max(const unsigned short* __restrict__ Ahi,
                                                  const unsigned short* __restrict__ Alo,
                                                  const unsigned short* __restrict__ Bfrag,
                                                  const float* __restrict__ b3,
                                                  unsigned* __restrict__ gf) {
  int b = blockIdx.x;
  int colhalf = b & 1, rowchunk = b >> 1;  // rowchunk 0..255 (256 rows each)
  int shape = rowchunk >> 2;
  int tid = threadIdx.x;
  int wv = tid >> 6, l = tid & 63;
  int g = l >> 4, lr = l & 15;

  const short8* bf = (const short8*)Bfrag;
  int c0 = colhalf * 512 + wv * 64 + lr;
  short8 B0[4], B1[4], B2[4], B3[4];
#pragma unroll
  for (int ct = 0; ct < 4; ++ct) {
    int col = c0 + ct * 16;
    B0[ct] = bf[(0 * 1024 + col) * 4 + g];
    B1[ct] = bf[(1 * 1024 + col) * 4 + g];
    B2[ct] = bf[(2 * 1024 + col) * 4 + g];
    B3[ct] = bf[(3 * 1024 + col) * 4 + g];
  }

  float m[4] = {-1e30f, -1e30f, -1e30f, -1e30f};
  size_t abase = ((size_t)rowchunk * 256 + lr) * 64 + g * 8;
  for (int t = 0; t < 16; ++t) {
    size_t o = abase + (size_t)t * 16 * 64;
    short8 ah0 = *(const short8*)(Ahi + o);
    short8 ah1 = *(const short8*)(Ahi + o + 32);
    short8 al0 = *(const short8*)(Alo + o);
    short8 al1 = *(const short8*)(Alo + o + 32);
#pragma unroll
    for (int ct = 0; ct < 4; ++ct) {
      f32x4 acc = {0.f, 0.f, 0.f, 0.f};
      acc = __builtin_amdgcn_mfma_f32_16x16x32_bf16(ah0, B0[ct], acc, 0, 0, 0);
      acc = __builtin_amdgcn_mfma_f32_16x16x32_bf16(ah1, B1[ct], acc, 0, 0, 0);
      acc = __builtin_amdgcn_mfma_f32_16x16x32_bf16(ah0, B2[ct], acc, 0, 0, 0);
      acc = __builtin_amdgcn_mfma_f32_16x16x32_bf16(ah1, B3[ct], acc, 0, 0, 0);
      acc = __builtin_amdgcn_mfma_f32_16x16x32_bf16(al0, B0[ct], acc, 0, 0, 0);
      acc = __builtin_amdgcn_mfma_f32_16x16x32_bf16(al1, B1[ct], acc, 0, 0, 0);
      m[ct] = fmaxf(m[ct], fmaxf(fmaxf(acc[0], acc[1]), fmaxf(acc[2], acc[3])));
    }
  }
#pragma unroll
  for (int ct = 0; ct < 4; ++ct) {
    float mm = m[ct];
    mm = fmaxf(mm, __shfl_xor(mm, 16));
    mm = fmaxf(mm, __shfl_xor(mm, 32));
    if (g == 0) {
      int col = c0 + ct * 16;
      float v = fmaxf(mm + b3[col], 0.f);
      atomicMax(&gf[shape * 1024 + col], __float_as_uint(v));
    }
  }
}

// ---------------- MLP head ----------------
__global__ __launch_bounds__(512) void k_fc(const float* __restrict__ in, const float* __restrict__ w,
                                            const float* __restrict__ bias, float* __restrict__ out,
                                            int K, int J) {
  __shared__ float sin_[1024];
  __shared__ float part[8][64];
  int jt = blockIdx.x, bb = blockIdx.y;
  int tid = threadIdx.x, s = tid >> 6, lane = tid & 63;
  for (int i = tid; i < K; i += 512) sin_[i] = in[bb * K + i];
  __syncthreads();
  int j = (jt << 6) + lane;
  int Ks = K >> 3;
  int k0 = s * Ks;
  float acc = 0.f;
  for (int k = 0; k < Ks; k += 16) {
    float wv[16];
#pragma unroll
    for (int u = 0; u < 16; ++u) wv[u] = w[(k0 + k + u) * J + j];
#pragma unroll
    for (int u = 0; u < 16; ++u) acc = fmaf(sin_[k0 + k + u], wv[u], acc);
  }
  part[s][lane] = acc;
  __syncthreads();
  if (tid < 64) {
    float r = bias[(jt << 6) + tid];
#pragma unroll
    for (int u = 0; u < 8; ++u) r += part[u][tid];
    out[bb * J + (jt << 6) + tid] = r;
  }
}

__global__ __launch_bounds__(256) void k_bn(const float* __restrict__ z, const float* __restrict__ g,
                                            const float* __restrict__ bt, float* __restrict__ out, int J) {
  __shared__ float tile[64][64];
  __shared__ float red[4][64];
  __shared__ float sc[64], sh[64];
  int tid = threadIdx.x, s = tid >> 6, lane = tid & 63;
  int j0 = blockIdx.x << 6;
  float psum = 0.f;
#pragma unroll
  for (int r = 0; r < 16; ++r) {
    int row = s * 16 + r;
    float v = z[row * J + j0 + lane];
    tile[row][lane] = v;
    psum += v;
  }
  red[s][lane] = psum;
  __syncthreads();
  if (tid < 64) sc[tid] = (red[0][tid] + red[1][tid] + red[2][tid] + red[3][tid]) * (1.f / 64.f);
  __syncthreads();
  float mean = sc[lane];
  float pv = 0.f;
#pragma unroll
  for (int r = 0; r < 16; ++r) {
    float d = tile[s * 16 + r][lane] - mean;
    pv = fmaf(d, d, pv);
  }
  red[s][lane] = pv;
  __syncthreads();
  if (tid < 64) {
    float var = (red[0][tid] + red[1][tid] + red[2][tid] + red[3][tid]) * (1.f / 64.f);
    float scale = g[j0 + tid] / sqrtf(var + 1e-5f);
    sh[tid] = bt[j0 + tid] - sc[tid] * scale;
    sc[tid] = scale;
  }
  __syncthreads();
  float scale = sc[lane], shift = sh[lane];
#pragma unroll
  for (int r = 0; r < 16; ++r) {
    int row = s * 16 + r;
    out[row * J + j0 + lane] = fmaxf(fmaf(tile[row][lane], scale, shift), 0.f);
  }
}

__global__ __launch_bounds__(256) void k_head(const float* __restrict__ z, const float* __restrict__ w,
                                              const float* __restrict__ b, float* __restrict__ out) {
  __shared__ float sz[256];
  __shared__ float part[4][64];
  int bb = blockIdx.x, tid = threadIdx.x;
  sz[tid] = z[bb * 256 + tid];
  __syncthreads();
  int s = tid >> 6, j = tid & 63;
  float acc = 0.f;
  if (j < 40) {
#pragma unroll
    for (int k = 0; k < 64; k += 4) {
      int kk = s * 64 + k;
      acc = fmaf(sz[kk + 0], w[(kk + 0) * 40 + j], acc);
      acc = fmaf(sz[kk + 1], w[(kk + 1) * 40 + j], acc);
      acc = fmaf(sz[kk + 2], w[(kk + 2) * 40 + j], acc);
      acc = fmaf(sz[kk + 3], w[(kk + 3) * 40 + j], acc);
    }
  }
  part[s][j] = acc;
  __syncthreads();
  if (tid < 64) {
    float v = (j < 40) ? part[0][j] + part[1][j] + part[2][j] + part[3][j] + b[j] : -INFINITY;
    float m = v;
    for (int d = 32; d > 0; d >>= 1) m = fmaxf(m, __shfl_xor(m, d));
    float e = (j < 40) ? expf(v - m) : 0.f;
    for (int d = 32; d > 0; d >>= 1) e += __shfl_xor(e, d);
    if (j < 40) out[bb * 40 + j] = v - m - logf(e);
  }
}

extern "C" void kernel_launch(void* const* d_in, const int* in_sizes, int n_in,
                              void* d_out, int out_size, void* d_ws, size_t ws_size,
                              hipStream_t stream) {
  (void)in_sizes; (void)n_in; (void)out_size; (void)ws_size;
  const float* x    = (const float*)d_in[0];
  const int*   esrc = (const int*)d_in[1];
  const int*   edst = (const int*)d_in[2];
  const float* ev   = (const float*)d_in[3];
  const float* gc1w = (const float*)d_in[5];
  const float* gc1b = (const float*)d_in[6];
  const float* gc2w = (const float*)d_in[7];
  const float* gc2b = (const float*)d_in[8];
  const float* gc3w = (const float*)d_in[9];
  const float* gc3b = (const float*)d_in[10];
  const float* fc1w = (const float*)d_in[11];
  const float* fc1b = (const float*)d_in[12];
  const float* bn1g = (const float*)d_in[13];
  const float* bn1b = (const float*)d_in[14];
  const float* fc2w = (const float*)d_in[15];
  const float* fc2b = (const float*)d_in[16];
  const float* bn2g = (const float*)d_in[17];
  const float* bn2b = (const float*)d_in[18];
  const float* fc3w = (const float*)d_in[19];
  const float* fc3b = (const float*)d_in[20];

  char* ws = (char*)d_ws;
  size_t o = 0;
  auto alloc = [&](size_t bytes) -> void* {
    void* p = ws + o;
    o += (bytes + 255) & ~(size_t)255;
    return p;
  };
  int2*  offdeg = (int2*)alloc((size_t)NN * 8);
  int*   gcur = (int*)alloc(64 * 4);
  int2*  pack = (int2*)alloc((size_t)64 * PCAP * 8);  // 12.6 MB padded
  float* aggx = (float*)alloc((size_t)NN * 3 * 4);
  float4* x4  = (float4*)alloc((size_t)NN * 16);
  float* bufA = (float*)alloc((size_t)NN * 64 * 4);  // ebin; later h1/h2 bf16
  float* bufB = (float*)alloc((size_t)NN * 64 * 4);  // Ahi/Alo
  uint2* ebin = (uint2*)bufA;                        // 64*CAP*8 = 8.9 MB, dead before gemm1
  unsigned short* h1_16 = (unsigned short*)bufA;            // 8 MB
  unsigned short* h2_16 = (unsigned short*)((char*)bufA + NN * 64 * 2);  // 8 MB (second half)
  unsigned short* Ahi = (unsigned short*)bufB;              // 8 MB
  unsigned short* Alo = (unsigned short*)(bufB + NN * 32);  // 8 MB
  unsigned short* Bfrag = (unsigned short*)alloc(4 * 1024 * 32 * 2);  // 256 KB
  float* gf   = (float*)alloc(64 * 1024 * 4);
  float* z1   = (float*)alloc(64 * 512 * 4);
  float* z1n  = (float*)alloc(64 * 512 * 4);
  float* z2   = (float*)alloc(64 * 256 * 4);
  float* z2n  = (float*)alloc(64 * 256 * 4);

  // zero-inits folded into k_packx (gcur) and k_prepw (gf) — no hipMemsetAsync
  k_packx<<<NN / 256, 256, 0, stream>>>(x, x4, gcur);
  k_prepw<<<512, 256, 0, stream>>>(gc3w, Bfrag, (unsigned*)gf);

  // CSR build: 2-pass shape-bucketed, padded to x8 per node
  k_bin<<<NE / 4096, 256, 0, stream>>>(esrc, edst, ev, gcur, ebin);
  k_csr<<<64, 1024, 0, stream>>>(gcur, ebin, offdeg, pack);

  // layer 1  (gemm1 writes h1 into bufA after ebin is dead)
  k_aggx<<<NN / 256, 256, 0, stream>>>(offdeg, pack, x4, aggx);
  k_gemm1<<<(NN * 64) / 256, 256, 0, stream>>>(aggx, gc1w, gc1b, h1_16);

  // layer 2 fused: agg(h1) @ W2 + b2, relu -> h2 bf16
  k_agg64g2<<<NN / 16, 256, 0, stream>>>(offdeg, pack, h1_16, gc2w, gc2b, h2_16);

  // layer 3: aggregate bf16 h2 -> split-bf16 planes, then MFMA GEMM + maxpool
  k_agg64_split<<<NN / 16, 256, 0, stream>>>(offdeg, pack, h2_16, Ahi, Alo);
  k_gemm3max<<<512, 512, 0, stream>>>(Ahi, Alo, Bfrag, gc3b, (unsigned*)gf);

  // MLP head
  k_fc<<<dim3(8, 64), 512, 0, stream>>>(gf, fc1w, fc1b, z1, 1024, 512);
  k_bn<<<8, 256, 0, stream>>>(z1, bn1g, bn1b, z1n, 512);
  k_fc<<<dim3(4, 64), 512, 0, stream>>>(z1n, fc2w, fc2b, z2, 512, 256);
  k_bn<<<4, 256, 0, stream>>>(z2, bn2g, bn2b, z2n, 256);
  k_head<<<64, 256, 0, stream>>>(z2n, fc3w, fc3b, (float*)d_out);
}

// Round 12
// 167.198 us; speedup vs baseline: 4.6158x; 1.0283x over previous
//
#include <hip/hip_runtime.h>
#include <math.h>

#define NN 65536
#define NE 1048576
#define CAP 17408   // per-bucket ebin capacity (mean 16384 + 8-sigma)
#define PCAP 24576  // per-bucket padded pack capacity (CAP + 7*1024 padding)

typedef __attribute__((ext_vector_type(8))) short short8;
typedef __attribute__((ext_vector_type(4))) float f32x4;

__device__ inline unsigned short f2bf(float f) {
  unsigned u = __float_as_uint(f);
  unsigned r = u + 0x7fff + ((u >> 16) & 1);  // RNE
  return (unsigned short)(r >> 16);
}
__device__ inline float bf2f(unsigned short h) { return __uint_as_float(((unsigned)h) << 16); }

// ---------------- merged prep: x packing + gcur zero + W3 split-bf16 frags + gf zero ----------
__global__ __launch_bounds__(256) void k_prep(const float* __restrict__ x, float4* __restrict__ x4,
                                              int* __restrict__ gcur, const float* __restrict__ w3,
                                              unsigned short* __restrict__ bfrag, unsigned* __restrict__ gf) {
  int bid = blockIdx.x, tid = threadIdx.x;
  if (bid < 256) {
    if (bid == 0 && tid < 64) gcur[tid] = 0;
    int n = bid * 256 + tid;
    x4[n] = make_float4(x[3 * n], x[3 * n + 1], x[3 * n + 2], 0.f);
  } else {
    int t = (bid - 256) * 256 + tid;  // 0..131071
    if (t < 65536) gf[t] = 0u;
    int e = t & 7, g = (t >> 3) & 3, col = (t >> 5) & 1023, q = t >> 15;
    int k = (q & 1) * 32 + g * 8 + e;
    float v = w3[k * 1024 + col];
    unsigned short hv = f2bf(v);
    bfrag[t] = (q < 2) ? hv : f2bf(v - bf2f(hv));
  }
}

// ---------------- CSR build, pass 1: bin edges by shape (dst>>10), 8B records ----------------
__global__ __launch_bounds__(256) void k_bin(const int* __restrict__ src, const int* __restrict__ dst,
                                             const float* __restrict__ val, int* __restrict__ gcur,
                                             uint2* __restrict__ ebin) {
  __shared__ int cnt[64], base[64];
  int tid = threadIdx.x;
  if (tid < 64) cnt[tid] = 0;
  __syncthreads();
  int e0 = blockIdx.x * 4096;
  int rsrc[16], rdst[16], rrank[16];
  float rval[16];
#pragma unroll
  for (int i = 0; i < 16; ++i) {
    int e = e0 + i * 256 + tid;
    rsrc[i] = src[e];
    rdst[i] = dst[e];
    rval[i] = val[e];
    rrank[i] = atomicAdd(&cnt[rdst[i] >> 10], 1);
  }
  __syncthreads();
  if (tid < 64) base[tid] = atomicAdd(&gcur[tid], cnt[tid]);
  __syncthreads();
#pragma unroll
  for (int i = 0; i < 16; ++i) {
    int b = rdst[i] >> 10;
    ebin[b * CAP + base[b] + rrank[i]] =
        make_uint2((unsigned)rsrc[i] | ((unsigned)(rdst[i] & 1023) << 16), (unsigned)__float_as_int(rval[i]));
  }
}

// ---------------- CSR build, pass 2: per-bucket padded CSR, 1024 threads/block ----------------
// pack entries: (src<<7 = h-row byte offset, val bits); per-node lists padded to x8 with (0,0).
__global__ __launch_bounds__(1024) void k_csr(const int* __restrict__ gcnt, const uint2* __restrict__ ebin,
                                              int2* __restrict__ offdeg, int2* __restrict__ pack) {
  __shared__ int lcnt[1024], lcur[1024], part[1024];
  int b = blockIdx.x, tid = threadIdx.x;
  int count = gcnt[b];
  int gbase = b * PCAP;
  lcnt[tid] = 0;
  __syncthreads();
  const uint2* eb = ebin + (size_t)b * CAP;
  for (int i0 = 0; i0 < count; i0 += 4096) {
    unsigned xs[4];
#pragma unroll
    for (int u = 0; u < 4; ++u) {
      int i = i0 + u * 1024 + tid;
      xs[u] = eb[min(i, count - 1)].x;
    }
#pragma unroll
    for (int u = 0; u < 4; ++u) {
      int i = i0 + u * 1024 + tid;
      if (i < count) atomicAdd(&lcnt[(xs[u] >> 16) & 1023], 1);
    }
  }
  __syncthreads();
  int deg = lcnt[tid];
  int pdeg = (deg + 7) & ~7;
  part[tid] = pdeg;
  __syncthreads();
  for (int d = 1; d < 1024; d <<= 1) {
    int v = (tid >= d) ? part[tid - d] : 0;
    __syncthreads();
    part[tid] += v;
    __syncthreads();
  }
  int o0 = part[tid] - pdeg;  // exclusive prefix (padded)
  lcur[tid] = o0;
  offdeg[b * 1024 + tid] = make_int2(gbase + o0, pdeg);
  __syncthreads();
  for (int i0 = 0; i0 < count; i0 += 4096) {
    uint2 es[4];
#pragma unroll
    for (int u = 0; u < 4; ++u) {
      int i = i0 + u * 1024 + tid;
      es[u] = eb[min(i, count - 1)];
    }
#pragma unroll
    for (int u = 0; u < 4; ++u) {
      int i = i0 + u * 1024 + tid;
      if (i < count) {
        int ld = (es[u].x >> 16) & 1023;
        int p = atomicAdd(&lcur[ld], 1);
        pack[gbase + p] = make_int2((int)((es[u].x & 0xffffu) << 7), (int)es[u].y);
      }
    }
  }
  int pend = o0 + pdeg;
  for (int p = o0 + deg; p < pend; ++p) pack[gbase + p] = make_int2(0, 0);
}

// thread per node, 8-deep gather pipeline, padded edge lists (no clamps)
__global__ __launch_bounds__(256) void k_aggx(const int2* __restrict__ offdeg, const int2* __restrict__ pack,
                                              const float4* __restrict__ x4, float* __restrict__ aggx) {
  int n = blockIdx.x * 256 + threadIdx.x;
  int2 od = offdeg[n];
  int i0 = od.x, pdeg = od.y;
  float a0 = 0.f, a1 = 0.f, a2 = 0.f;
  for (int b = 0; b < pdeg; b += 8) {
    int2 ed[8];
    float4 q[8];
#pragma unroll
    for (int u = 0; u < 8; ++u) ed[u] = pack[i0 + b + u];
#pragma unroll
    for (int u = 0; u < 8; ++u) q[u] = x4[(unsigned)ed[u].x >> 7];
#pragma unroll
    for (int u = 0; u < 8; ++u) {
      float v = __int_as_float(ed[u].y);
      a0 = fmaf(v, q[u].x, a0);
      a1 = fmaf(v, q[u].y, a1);
      a2 = fmaf(v, q[u].z, a2);
    }
  }
  aggx[n * 3 + 0] = a0;
  aggx[n * 3 + 1] = a1;
  aggx[n * 3 + 2] = a2;
}

__global__ __launch_bounds__(256) void k_gemm1(const float* __restrict__ aggx, const float* __restrict__ w,
                                               const float* __restrict__ b, unsigned short* __restrict__ out) {
  __shared__ float sw[256];
  int t = threadIdx.x;
  sw[t] = (t < 192) ? w[t] : b[t - 192];
  __syncthreads();
  int g = blockIdx.x * 256 + t;
  int n = g >> 6, j = g & 63;
  float a0 = aggx[n * 3], a1 = aggx[n * 3 + 1], a2 = aggx[n * 3 + 2];
  float r = sw[192 + j];
  r = fmaf(a0, sw[j], r);
  r = fmaf(a1, sw[64 + j], r);
  r = fmaf(a2, sw[128 + j], r);
  out[g] = f2bf(fmaxf(r, 0.f));
}

// ---------------- fused layer-2: agg(h1) -> @W2+b2, relu -> h2 bf16 ----------------
// 8 nodes/wave, 8 feats/lane (dwordx4 gather); padded lists; W2 in LDS.
__global__ __launch_bounds__(256) void k_agg64g2(const int2* __restrict__ offdeg, const int2* __restrict__ pack,
                                                 const unsigned short* __restrict__ h,
                                                 const float* __restrict__ w2, const float* __restrict__ b2,
                                                 unsigned short* __restrict__ out) {
  __shared__ float sw[64][64];    // sw[k][j]
  __shared__ float rows[32][64];
  int tid = threadIdx.x;
  int lane = tid & 63, wv = tid >> 6;
  for (int t = tid; t < 1024; t += 256) ((float4*)sw)[t] = ((const float4*)w2)[t];
  __syncthreads();
  int o = lane >> 3, fl = lane & 7;  // node octant, feat group (feats 8fl..8fl+7)
  int n = blockIdx.x * 32 + wv * 8 + o;
  int2 od = offdeg[n];
  int i0 = od.x, pdeg = od.y;
  const char* hb = (const char*)h;
  unsigned fo = (unsigned)(fl << 4);
  float c0 = 0.f, c1 = 0.f, c2 = 0.f, c3 = 0.f, c4 = 0.f, c5 = 0.f, c6 = 0.f, c7 = 0.f;
  for (int b = 0; b < pdeg; b += 8) {
    int2 ed[8];
    uint4 hv[8];
#pragma unroll
    for (int u = 0; u < 8; ++u) ed[u] = pack[i0 + b + u];
#pragma unroll
    for (int u = 0; u < 8; ++u) hv[u] = *(const uint4*)(hb + ((unsigned)ed[u].x + fo));
#pragma unroll
    for (int u = 0; u < 8; ++u) {
      float v = __int_as_float(ed[u].y);
      c0 = fmaf(v, __uint_as_float(hv[u].x << 16), c0);
      c1 = fmaf(v, __uint_as_float(hv[u].x & 0xffff0000u), c1);
      c2 = fmaf(v, __uint_as_float(hv[u].y << 16), c2);
      c3 = fmaf(v, __uint_as_float(hv[u].y & 0xffff0000u), c3);
      c4 = fmaf(v, __uint_as_float(hv[u].z << 16), c4);
      c5 = fmaf(v, __uint_as_float(hv[u].z & 0xffff0000u), c5);
      c6 = fmaf(v, __uint_as_float(hv[u].w << 16), c6);
      c7 = fmaf(v, __uint_as_float(hv[u].w & 0xffff0000u), c7);
    }
  }
  ((float4*)rows[wv * 8 + o])[fl * 2 + 0] = make_float4(c0, c1, c2, c3);
  ((float4*)rows[wv * 8 + o])[fl * 2 + 1] = make_float4(c4, c5, c6, c7);
  // tail GEMM: wave computes its 8 nodes x 64 outputs (same-wave LDS dependence)
  int nA = blockIdx.x * 32 + wv * 8;
  float bb = b2[lane];
  float acc[8];
#pragma unroll
  for (int r = 0; r < 8; ++r) acc[r] = bb;
#pragma unroll
  for (int kk = 0; kk < 16; ++kk) {
    float w0 = sw[4 * kk + 0][lane], w1 = sw[4 * kk + 1][lane];
    float w2v = sw[4 * kk + 2][lane], w3v = sw[4 * kk + 3][lane];
#pragma unroll
    for (int r = 0; r < 8; ++r) {
      float4 qr = ((const float4*)rows[wv * 8 + r])[kk];
      acc[r] = fmaf(qr.x, w0, acc[r]);
      acc[r] = fmaf(qr.y, w1, acc[r]);
      acc[r] = fmaf(qr.z, w2v, acc[r]);
      acc[r] = fmaf(qr.w, w3v, acc[r]);
    }
  }
#pragma unroll
  for (int r = 0; r < 8; ++r)
    out[(size_t)(nA + r) * 64 + lane] = f2bf(fmaxf(acc[r], 0.f));
}

// 64-feature aggregation -> split-bf16 planes; 8 nodes/wave, 8 feats/lane, padded
__global__ __launch_bounds__(256) void k_agg64_split(const int2* __restrict__ offdeg, const int2* __restrict__ pack,
                                                     const unsigned short* __restrict__ h,
                                                     unsigned short* __restrict__ hi,
                                                     unsigned short* __restrict__ lo) {
  int tid = threadIdx.x;
  int lane = tid & 63, wv = tid >> 6;
  int o = lane >> 3, fl = lane & 7;
  int n = blockIdx.x * 32 + wv * 8 + o;
  int2 od = offdeg[n];
  int i0 = od.x, pdeg = od.y;
  const char* hb = (const char*)h;
  unsigned fo = (unsigned)(fl << 4);
  float c0 = 0.f, c1 = 0.f, c2 = 0.f, c3 = 0.f, c4 = 0.f, c5 = 0.f, c6 = 0.f, c7 = 0.f;
  for (int b = 0; b < pdeg; b += 8) {
    int2 ed[8];
    uint4 hv[8];
#pragma unroll
    for (int u = 0; u < 8; ++u) ed[u] = pack[i0 + b + u];
#pragma unroll
    for (int u = 0; u < 8; ++u) hv[u] = *(const uint4*)(hb + ((unsigned)ed[u].x + fo));
#pragma unroll
    for (int u = 0; u < 8; ++u) {
      float v = __int_as_float(ed[u].y);
      c0 = fmaf(v, __uint_as_float(hv[u].x << 16), c0);
      c1 = fmaf(v, __uint_as_float(hv[u].x & 0xffff0000u), c1);
      c2 = fmaf(v, __uint_as_float(hv[u].y << 16), c2);
      c3 = fmaf(v, __uint_as_float(hv[u].y & 0xffff0000u), c3);
      c4 = fmaf(v, __uint_as_float(hv[u].z << 16), c4);
      c5 = fmaf(v, __uint_as_float(hv[u].z & 0xffff0000u), c5);
      c6 = fmaf(v, __uint_as_float(hv[u].w << 16), c6);
      c7 = fmaf(v, __uint_as_float(hv[u].w & 0xffff0000u), c7);
    }
  }
  unsigned short h0 = f2bf(c0), h1 = f2bf(c1), h2 = f2bf(c2), h3 = f2bf(c3);
  unsigned short h4 = f2bf(c4), h5 = f2bf(c5), h6 = f2bf(c6), h7 = f2bf(c7);
  uint4 hiw = make_uint4((unsigned)h0 | ((unsigned)h1 << 16), (unsigned)h2 | ((unsigned)h3 << 16),
                         (unsigned)h4 | ((unsigned)h5 << 16), (unsigned)h6 | ((unsigned)h7 << 16));
  unsigned short l0 = f2bf(c0 - bf2f(h0)), l1 = f2bf(c1 - bf2f(h1));
  unsigned short l2 = f2bf(c2 - bf2f(h2)), l3 = f2bf(c3 - bf2f(h3));
  unsigned short l4 = f2bf(c4 - bf2f(h4)), l5 = f2bf(c5 - bf2f(h5));
  unsigned short l6 = f2bf(c6 - bf2f(h6)), l7 = f2bf(c7 - bf2f(h7));
  uint4 low = make_uint4((unsigned)l0 | ((unsigned)l1 << 16), (unsigned)l2 | ((unsigned)l3 << 16),
                         (unsigned)l4 | ((unsigned)l5 << 16), (unsigned)l6 | ((unsigned)l7 << 16));
  ((uint4*)hi)[(size_t)n * 8 + fl] = hiw;
  ((uint4*)lo)[(size_t)n * 8 + fl] = low;
}

// ---------------- GCN layer 3 GEMM + maxpool via MFMA (split-bf16) ----------------
__global__ __launch_bounds__(512) void k_gemm3max(const unsigned short* __restrict__ Ahi,
                                                  const unsigned short* __restrict__ Alo,
                                                  const unsigned short* __restrict__ Bfrag,
                                                  const float* __restrict__ b3,
                                                  unsigned* __restrict__ gf) {
  int b = blockIdx.x;
  int colhalf = b & 1, rowchunk = b >> 1;  // rowchunk 0..255 (256 rows each)
  int shape = rowchunk >> 2;
  int tid = threadIdx.x;
  int wv = tid >> 6, l = tid & 63;
  int g = l >> 4, lr = l & 15;

  const short8* bf = (const short8*)Bfrag;
  int c0 = colhalf * 512 + wv * 64 + lr;
  short8 B0[4], B1[4], B2[4], B3[4];
#pragma unroll
  for (int ct = 0; ct < 4; ++ct) {
    int col = c0 + ct * 16;
    B0[ct] = bf[(0 * 1024 + col) * 4 + g];
    B1[ct] = bf[(1 * 1024 + col) * 4 + g];
    B2[ct] = bf[(2 * 1024 + col) * 4 + g];
    B3[ct] = bf[(3 * 1024 + col) * 4 + g];
  }

  float m[4] = {-1e30f, -1e30f, -1e30f, -1e30f};
  size_t abase = ((size_t)rowchunk * 256 + lr) * 64 + g * 8;
  for (int t = 0; t < 16; ++t) {
    size_t o = abase + (size_t)t * 16 * 64;
    short8 ah0 = *(const short8*)(Ahi + o);
    short8 ah1 = *(const short8*)(Ahi + o + 32);
    short8 al0 = *(const short8*)(Alo + o);
    short8 al1 = *(const short8*)(Alo + o + 32);
#pragma unroll
    for (int ct = 0; ct < 4; ++ct) {
      f32x4 acc = {0.f, 0.f, 0.f, 0.f};
      acc = __builtin_amdgcn_mfma_f32_16x16x32_bf16(ah0, B0[ct], acc, 0, 0, 0);
      acc = __builtin_amdgcn_mfma_f32_16x16x32_bf16(ah1, B1[ct], acc, 0, 0, 0);
      acc = __builtin_amdgcn_mfma_f32_16x16x32_bf16(ah0, B2[ct], acc, 0, 0, 0);
      acc = __builtin_amdgcn_mfma_f32_16x16x32_bf16(ah1, B3[ct], acc, 0, 0, 0);
      acc = __builtin_amdgcn_mfma_f32_16x16x32_bf16(al0, B0[ct], acc, 0, 0, 0);
      acc = __builtin_amdgcn_mfma_f32_16x16x32_bf16(al1, B1[ct], acc, 0, 0, 0);
      m[ct] = fmaxf(m[ct], fmaxf(fmaxf(acc[0], acc[1]), fmaxf(acc[2], acc[3])));
    }
  }
#pragma unroll
  for (int ct = 0; ct < 4; ++ct) {
    float mm = m[ct];
    mm = fmaxf(mm, __shfl_xor(mm, 16));
    mm = fmaxf(mm, __shfl_xor(mm, 32));
    if (g == 0) {
      int col = c0 + ct * 16;
      float v = fmaxf(mm + b3[col], 0.f);
      atomicMax(&gf[shape * 1024 + col], __float_as_uint(v));
    }
  }
}

// ---------------- MLP head ----------------
__global__ __launch_bounds__(512) void k_fc(const float* __restrict__ in, const float* __restrict__ w,
                                            const float* __restrict__ bias, float* __restrict__ out,
                                            int K, int J) {
  __shared__ float sin_[1024];
  __shared__ float part[8][64];
  int jt = blockIdx.x, bb = blockIdx.y;
  int tid = threadIdx.x, s = tid >> 6, lane = tid & 63;
  for (int i = tid; i < K; i += 512) sin_[i] = in[bb * K + i];
  __syncthreads();
  int j = (jt << 6) + lane;
  int Ks = K >> 3;
  int k0 = s * Ks;
  float acc = 0.f;
  for (int k = 0; k < Ks; k += 16) {
    float wv[16];
#pragma unroll
    for (int u = 0; u < 16; ++u) wv[u] = w[(k0 + k + u) * J + j];
#pragma unroll
    for (int u = 0; u < 16; ++u) acc = fmaf(sin_[k0 + k + u], wv[u], acc);
  }
  part[s][lane] = acc;
  __syncthreads();
  if (tid < 64) {
    float r = bias[(jt << 6) + tid];
#pragma unroll
    for (int u = 0; u < 8; ++u) r += part[u][tid];
    out[bb * J + (jt << 6) + tid] = r;
  }
}

__global__ __launch_bounds__(256) void k_bn(const float* __restrict__ z, const float* __restrict__ g,
                                            const float* __restrict__ bt, float* __restrict__ out, int J) {
  __shared__ float tile[64][64];
  __shared__ float red[4][64];
  __shared__ float sc[64], sh[64];
  int tid = threadIdx.x, s = tid >> 6, lane = tid & 63;
  int j0 = blockIdx.x << 6;
  float psum = 0.f;
#pragma unroll
  for (int r = 0; r < 16; ++r) {
    int row = s * 16 + r;
    float v = z[row * J + j0 + lane];
    tile[row][lane] = v;
    psum += v;
  }
  red[s][lane] = psum;
  __syncthreads();
  if (tid < 64) sc[tid] = (red[0][tid] + red[1][tid] + red[2][tid] + red[3][tid]) * (1.f / 64.f);
  __syncthreads();
  float mean = sc[lane];
  float pv = 0.f;
#pragma unroll
  for (int r = 0; r < 16; ++r) {
    float d = tile[s * 16 + r][lane] - mean;
    pv = fmaf(d, d, pv);
  }
  red[s][lane] = pv;
  __syncthreads();
  if (tid < 64) {
    float var = (red[0][tid] + red[1][tid] + red[2][tid] + red[3][tid]) * (1.f / 64.f);
    float scale = g[j0 + tid] / sqrtf(var + 1e-5f);
    sh[tid] = bt[j0 + tid] - sc[tid] * scale;
    sc[tid] = scale;
  }
  __syncthreads();
  float scale = sc[lane], shift = sh[lane];
#pragma unroll
  for (int r = 0; r < 16; ++r) {
    int row = s * 16 + r;
    out[row * J + j0 + lane] = fmaxf(fmaf(tile[row][lane], scale, shift), 0.f);
  }
}

// fused BN2 + relu + fc3 + log_softmax: grid 64 (one block per batch row)
__global__ __launch_bounds__(256) void k_head2(const float* __restrict__ z2, const float* __restrict__ g,
                                               const float* __restrict__ bt, const float* __restrict__ w,
                                               const float* __restrict__ b, float* __restrict__ out) {
  __shared__ float sz[256];
  __shared__ float part[4][64];
  int bb = blockIdx.x, j = threadIdx.x;
  // column-j BN stats (two-pass, matches reference biased var)
  float s = 0.f;
#pragma unroll 8
  for (int r = 0; r < 64; ++r) s += z2[r * 256 + j];
  float mean = s * (1.f / 64.f);
  float v = 0.f;
#pragma unroll 8
  for (int r = 0; r < 64; ++r) {
    float d = z2[r * 256 + j] - mean;
    v = fmaf(d, d, v);
  }
  float scale = g[j] / sqrtf(v * (1.f / 64.f) + 1e-5f);
  float shift = bt[j] - mean * scale;
  sz[j] = fmaxf(fmaf(z2[bb * 256 + j], scale, shift), 0.f);
  __syncthreads();
  int sgrp = j >> 6, lane = j & 63;
  float acc = 0.f;
  if (lane < 40) {
#pragma unroll
    for (int k = 0; k < 64; k += 4) {
      int kk = sgrp * 64 + k;
      acc = fmaf(sz[kk + 0], w[(kk + 0) * 40 + lane], acc);
      acc = fmaf(sz[kk + 1], w[(kk + 1) * 40 + lane], acc);
      acc = fmaf(sz[kk + 2], w[(kk + 2) * 40 + lane], acc);
      acc = fmaf(sz[kk + 3], w[(kk + 3) * 40 + lane], acc);
    }
  }
  part[sgrp][lane] = acc;
  __syncthreads();
  if (j < 64) {
    float lv = (j < 40) ? part[0][j] + part[1][j] + part[2][j] + part[3][j] + b[j] : -INFINITY;
    float m = lv;
    for (int d = 32; d > 0; d >>= 1) m = fmaxf(m, __shfl_xor(m, d));
    float e = (j < 40) ? expf(lv - m) : 0.f;
    for (int d = 32; d > 0; d >>= 1) e += __shfl_xor(e, d);
    if (j < 40) out[bb * 40 + j] = lv - m - logf(e);
  }
}

extern "C" void kernel_launch(void* const* d_in, const int* in_sizes, int n_in,
                              void* d_out, int out_size, void* d_ws, size_t ws_size,
                              hipStream_t stream) {
  (void)in_sizes; (void)n_in; (void)out_size; (void)ws_size;
  const float* x    = (const float*)d_in[0];
  const int*   esrc = (const int*)d_in[1];
  const int*   edst = (const int*)d_in[2];
  const float* ev   = (const float*)d_in[3];
  const float* gc1w = (const float*)d_in[5];
  const float* gc1b = (const float*)d_in[6];
  const float* gc2w = (const float*)d_in[7];
  const float* gc2b = (const float*)d_in[8];
  const float* gc3w = (const float*)d_in[9];
  const float* gc3b = (const float*)d_in[10];
  const float* fc1w = (const float*)d_in[11];
  const float* fc1b = (const float*)d_in[12];
  const float* bn1g = (const float*)d_in[13];
  const float* bn1b = (const float*)d_in[14];
  const float* fc2w = (const float*)d_in[15];
  const float* fc2b = (const float*)d_in[16];
  const float* bn2g = (const float*)d_in[17];
  const float* bn2b = (const float*)d_in[18];
  const float* fc3w = (const float*)d_in[19];
  const float* fc3b = (const float*)d_in[20];

  char* ws = (char*)d_ws;
  size_t o = 0;
  auto alloc = [&](size_t bytes) -> void* {
    void* p = ws + o;
    o += (bytes + 255) & ~(size_t)255;
    return p;
  };
  int2*  offdeg = (int2*)alloc((size_t)NN * 8);
  int*   gcur = (int*)alloc(64 * 4);
  int2*  pack = (int2*)alloc((size_t)64 * PCAP * 8);  // 12.6 MB padded
  float* aggx = (float*)alloc((size_t)NN * 3 * 4);
  float4* x4  = (float4*)alloc((size_t)NN * 16);
  float* bufA = (float*)alloc((size_t)NN * 64 * 4);  // ebin; later h1/h2 bf16
  float* bufB = (float*)alloc((size_t)NN * 64 * 4);  // Ahi/Alo
  uint2* ebin = (uint2*)bufA;                        // 64*CAP*8 = 8.9 MB, dead before gemm1
  unsigned short* h1_16 = (unsigned short*)bufA;            // 8 MB
  unsigned short* h2_16 = (unsigned short*)((char*)bufA + NN * 64 * 2);  // 8 MB (second half)
  unsigned short* Ahi = (unsigned short*)bufB;              // 8 MB
  unsigned short* Alo = (unsigned short*)(bufB + NN * 32);  // 8 MB
  unsigned short* Bfrag = (unsigned short*)alloc(4 * 1024 * 32 * 2);  // 256 KB
  float* gf   = (float*)alloc(64 * 1024 * 4);
  float* z1   = (float*)alloc(64 * 512 * 4);
  float* z1n  = (float*)alloc(64 * 512 * 4);
  float* z2   = (float*)alloc(64 * 256 * 4);

  // prep: x4 pack + gcur zero + W3 frags + gf zero (one dispatch)
  k_prep<<<768, 256, 0, stream>>>(x, x4, gcur, gc3w, Bfrag, (unsigned*)gf);

  // CSR build: 2-pass shape-bucketed, padded to x8 per node
  k_bin<<<NE / 4096, 256, 0, stream>>>(esrc, edst, ev, gcur, ebin);
  k_csr<<<64, 1024, 0, stream>>>(gcur, ebin, offdeg, pack);

  // layer 1  (gemm1 writes h1 into bufA after ebin is dead)
  k_aggx<<<NN / 256, 256, 0, stream>>>(offdeg, pack, x4, aggx);
  k_gemm1<<<(NN * 64) / 256, 256, 0, stream>>>(aggx, gc1w, gc1b, h1_16);

  // layer 2 fused: agg(h1) @ W2 + b2, relu -> h2 bf16
  k_agg64g2<<<NN / 32, 256, 0, stream>>>(offdeg, pack, h1_16, gc2w, gc2b, h2_16);

  // layer 3: aggregate bf16 h2 -> split-bf16 planes, then MFMA GEMM + maxpool
  k_agg64_split<<<NN / 32, 256, 0, stream>>>(offdeg, pack, h2_16, Ahi, Alo);
  k_gemm3max<<<512, 512, 0, stream>>>(Ahi, Alo, Bfrag, gc3b, (unsigned*)gf);

  // MLP head
  k_fc<<<dim3(8, 64), 512, 0, stream>>>(gf, fc1w, fc1b, z1, 1024, 512);
  k_bn<<<8, 256, 0, stream>>>(z1, bn1g, bn1b, z1n, 512);
  k_fc<<<dim3(4, 64), 512, 0, stream>>>(z1n, fc2w, fc2b, z2, 512, 256);
  k_head2<<<64, 256, 0, stream>>>(z2, bn2g, bn2b, fc3w, fc3b, (float*)d_out);
}